// Round 6
// baseline (3605.252 us; speedup 1.0000x reference)
//
#include <hip/hip_runtime.h>
#include <hip/hip_bf16.h>

typedef __hip_bfloat16 bf16;
typedef unsigned short u16;
typedef unsigned int u32;

#define D1c 48
#define H1c 40
#define W1c 48
#define NHALF 92160L
#define D2c 96
#define H2c 80
#define W2c 96
#define NFULL 737280L
#define S1 368
#define S2 128
#define RG 512

#define NX1 (NHALF * S1)
#define NX2 (NFULL * S2)
#define NCTX16 (NHALF * 16)
#define N3H (NHALF * 3)
#define N3F (NFULL * 3)
#define GUARD 1024

typedef __attribute__((ext_vector_type(8))) short s8v;
typedef __attribute__((ext_vector_type(4))) float f4v;

__device__ __forceinline__ float bf2f(bf16 v){ return __bfloat162float(v); }
__device__ __forceinline__ float sf(float v){ return (v == v && fabsf(v) < 1e30f) ? v : 0.f; }
__device__ __forceinline__ bf16 f2bf(float v){ return __float2bfloat16(sf(v)); }
__device__ __forceinline__ long cl(long i, long n){ i = i < 0 ? 0 : i; return i >= n ? n - 1 : i; }
// mode-dispatched input load: 0 = bf16, 1 = f32
__device__ __forceinline__ float gld(const void* p, long i, int mode){
    return mode ? sf(((const float*)p)[i]) : sf(bf2f(((const bf16*)p)[i]));
}

// ---------------- dtype detection: one block per input ---------------------
__global__ void k_detect(const void* p, long nelem, int* flag) {
    long N = nelem < 4096 ? nelem : 4096;
    int tid = threadIdx.x;
    int nb = 0, nf = 0;
    for (long i = tid; i < N; i += 256) {
        float v = bf2f(((const bf16*)p)[i]);
        if (v == v && fabsf(v) <= 1e4f) nb++;
    }
    long M = N / 2;
    for (long i = tid; i < M; i += 256) {
        float v = ((const float*)p)[i];
        if (v == v && fabsf(v) <= 1e4f) nf += 2;
    }
    __shared__ int sb[256], sq[256];
    sb[tid] = nb; sq[tid] = nf;
    __syncthreads();
    for (int t = 128; t; t >>= 1) {
        if (tid < t) { sb[tid] += sb[tid + t]; sq[tid] += sq[tid + t]; }
        __syncthreads();
    }
    if (tid == 0) *flag = (sb[0] >= sq[0]) ? 0 : 1;
}

// ---------------- fills -----------------------------------------------------
__global__ void k_fill(u16* __restrict__ p, long n, u16 val) {
    long i = (long)blockIdx.x * 256 + threadIdx.x;
    long stride = (long)gridDim.x * 256;
    for (; i < n; i += stride) p[i] = val;
}
__global__ void k_fill_tail(void* out, long vf, long out_n, const int* __restrict__ modep) {
    int mode = *modep;
    long n = out_n - vf;
    if (n <= 0) return;
    long i = (long)blockIdx.x * 256 + threadIdx.x;
    long stride = (long)gridDim.x * 256;
    if (mode) { float* p = (float*)out + vf; for (; i < n; i += stride) p[i] = 0.f; }
    else      { u16*   p = (u16*)out + vf;   for (; i < n; i += stride) p[i] = 0; }
}

// ------- weight transpose: (co,ci,tap) -> (tap,ci,co) f32 (small convs) ----
__global__ void k_wt(const void* __restrict__ w, float* __restrict__ wt,
                     int Cin, int Cout, const int* __restrict__ modep) {
    int mode = *modep;
    long n = (long)Cin * Cout * 27;
    long i = (long)blockIdx.x * 256 + threadIdx.x;
    if (i >= n) return;
    int tap = (int)(i % 27); long r = i / 27;
    int ci = (int)(r % Cin); int co = (int)(r / Cin);
    wt[cl(((long)tap * Cin + ci) * Cout + co, n)] = gld(w, cl(i, n), mode);
}

// ------- MFMA weight repack: (co,ci,tap) -> [tap][chunk][co][32] bf16 ------
// zero-padded for ci >= Cin (Cin tails)
__global__ void k_wtb(const void* __restrict__ w, bf16* __restrict__ wtb,
                      int Cin, int Cout, int nchunk, const int* __restrict__ modep) {
    int mode = *modep;
    long n = 27L * nchunk * Cout * 32;
    long i = (long)blockIdx.x * 256 + threadIdx.x;
    if (i >= n) return;
    int kk = (int)(i & 31);
    long r = i >> 5;
    int co = (int)(r % Cout); r /= Cout;
    int ch = (int)(r % nchunk); int tap = (int)(r / nchunk);
    int ci = ch * 32 + kk;
    float v = (ci < Cin) ? gld(w, ((long)co * Cin + ci) * 27 + tap, mode) : 0.f;
    wtb[i] = f2bf(v);
}

// ------- channel-first [C][N] -> channel-last columns ----------------------
__global__ void k_tcl(const void* __restrict__ in, long nin,
                      bf16* __restrict__ out, long nout, int col0,
                      int C, long N, int stride, const int* __restrict__ modep) {
    int mode = *modep;
    long n = (long)blockIdx.x * 256 + threadIdx.x;
    if (n >= N) return;
    for (int c = 0; c < C; ++c)
        out[cl(n * stride + col0 + c, nout)] = f2bf(gld(in, cl((long)c * N + n, nin), mode));
}

// ------- antialiased x0.5 downsample taps ----------------------------------
__device__ __forceinline__ void down_taps(int i, int n_in, int j[4], float w[4]) {
    float s = 0.f;
    for (int k = 0; k < 4; ++k) {
        int jj = 2 * i - 1 + k;
        bool valid = (jj >= 0 && jj < n_in);
        j[k] = valid ? jj : 0;
        float b = (k == 0 || k == 3) ? 1.f : 3.f;
        w[k] = valid ? b : 0.f;
        s += w[k];
    }
    float inv = 1.f / fmaxf(s, 1e-6f);
    for (int k = 0; k < 4; ++k) w[k] *= inv;
}

// disp = resize(disp_up,0.5)*0.5 -> disph f32 + xin1 cols 221..223
__global__ void k_down(const void* __restrict__ dispup, float* __restrict__ disph,
                       bf16* __restrict__ xin1, const int* __restrict__ modep) {
    int mode = *modep;
    long p = (long)blockIdx.x * 256 + threadIdx.x;
    if (p >= NHALF) return;
    int x = (int)(p % W1c), y = (int)((p / W1c) % H1c), z = (int)(p / (W1c * H1c));
    int jz[4], jy[4], jx[4]; float wz[4], wy[4], wx[4];
    down_taps(z, D2c, jz, wz); down_taps(y, H2c, jy, wy); down_taps(x, W2c, jx, wx);
    for (int c = 0; c < 3; ++c) {
        float acc = 0.f;
        for (int a = 0; a < 4; ++a) {
            if (wz[a] == 0.f) continue;
            for (int b = 0; b < 4; ++b) {
                if (wy[b] == 0.f) continue;
                float wzy = wz[a] * wy[b];
                long base = (long)c * NFULL + ((long)jz[a] * H2c + jy[b]) * W2c;
                for (int d = 0; d < 4; ++d) {
                    if (wx[d] == 0.f) continue;
                    acc += wzy * wx[d] * gld(dispup, cl(base + jx[d], 3 * NFULL), mode);
                }
            }
        }
        acc = sf(acc * 0.5f);
        disph[cl(p * 3 + c, N3H)] = acc;
        xin1[cl(p * (long)S1 + 221 + c, NX1)] = f2bf(acc);
    }
}

// ------- trilinear warp, channel-first INPUT volume, zero pad --------------
template<int C>
__global__ void k_warp_cf(const void* __restrict__ vol, long nvol,
                          const float* __restrict__ coords, long ncoords,
                          bf16* __restrict__ dst, long ndst, int dstride, int col0,
                          int D, int H, int W, const int* __restrict__ modep) {
    int mode = *modep;
    const long N = (long)D * H * W;
    long p = (long)blockIdx.x * 256 + threadIdx.x;
    if (p >= N) return;
    int x = (int)(p % W), y = (int)((p / W) % H), z = (int)(p / ((long)W * H));
    float cz = z + sf(coords[cl(p * 3, ncoords)]);
    float cy = y + sf(coords[cl(p * 3 + 1, ncoords)]);
    float cx = x + sf(coords[cl(p * 3 + 2, ncoords)]);
    float acc[C];
    for (int c = 0; c < C; ++c) acc[c] = 0.f;
    float z0f = floorf(cz), y0f = floorf(cy), x0f = floorf(cx);
    int z0 = (int)z0f, y0 = (int)y0f, x0 = (int)x0f;
    float fz = cz - z0f, fy = cy - y0f, fx = cx - x0f;
    for (int dz = 0; dz < 2; ++dz) {
        int zi = z0 + dz; if (zi < 0 || zi >= D) continue;
        float wz = dz ? fz : 1.f - fz;
        for (int dy = 0; dy < 2; ++dy) {
            int yi = y0 + dy; if (yi < 0 || yi >= H) continue;
            float wzy = wz * (dy ? fy : 1.f - fy);
            for (int dx = 0; dx < 2; ++dx) {
                int xi = x0 + dx; if (xi < 0 || xi >= W) continue;
                float w = wzy * (dx ? fx : 1.f - fx);
                long idx = (long)(zi * H + yi) * W + xi;
                for (int c = 0; c < C; ++c) acc[c] += w * gld(vol, cl((long)c * N + idx, nvol), mode);
            }
        }
    }
    for (int c = 0; c < C; ++c) dst[cl(p * (long)dstride + col0 + c, ndst)] = f2bf(acc[c]);
}

// ------- two-stage deterministic reduction (sum, sumsq) --------------------
__global__ void k_reduce_cl(const void* __restrict__ base, long nbase, long rows,
                            int stride, int col0, int cn, double* __restrict__ part,
                            const int* __restrict__ modep) {
    int mode = *modep;
    long total = rows * cn;
    double s = 0.0, q = 0.0;
    long i = (long)blockIdx.x * 256 + threadIdx.x;
    long gs = (long)gridDim.x * 256;
    for (; i < total; i += gs) {
        long r = i / cn; int c = (int)(i - r * cn);
        float f = gld(base, cl(r * (long)stride + col0 + c, nbase), mode);
        s += f; q += (double)f * f;
    }
    __shared__ double ls[256], lq[256];
    ls[threadIdx.x] = s; lq[threadIdx.x] = q;
    __syncthreads();
    for (int t = 128; t; t >>= 1) {
        if (threadIdx.x < t) { ls[threadIdx.x] += ls[threadIdx.x + t]; lq[threadIdx.x] += lq[threadIdx.x + t]; }
        __syncthreads();
    }
    if (threadIdx.x == 0) { part[cl(blockIdx.x * 2, RG * 2)] = ls[0]; part[cl(blockIdx.x * 2 + 1, RG * 2)] = lq[0]; }
}

__global__ void k_stats2(const double* __restrict__ pa, const double* __restrict__ pb,
                         double n, double C, double* __restrict__ outm) {
    __shared__ double ls[256], lq[256];
    double s = 0.0, q = 0.0;
    for (int i = threadIdx.x; i < RG; i += 256) { s += pa[i * 2]; q += pa[i * 2 + 1]; }
    ls[threadIdx.x] = s; lq[threadIdx.x] = q;
    __syncthreads();
    for (int t = 128; t; t >>= 1) {
        if (threadIdx.x < t) { ls[threadIdx.x] += ls[threadIdx.x + t]; lq[threadIdx.x] += lq[threadIdx.x + t]; }
        __syncthreads();
    }
    double sa = ls[0], qa = lq[0];
    __syncthreads();
    s = 0.0; q = 0.0;
    for (int i = threadIdx.x; i < RG; i += 256) { s += pb[i * 2]; q += pb[i * 2 + 1]; }
    ls[threadIdx.x] = s; lq[threadIdx.x] = q;
    __syncthreads();
    for (int t = 128; t; t >>= 1) {
        if (threadIdx.x < t) { ls[threadIdx.x] += ls[threadIdx.x + t]; lq[threadIdx.x] += lq[threadIdx.x + t]; }
        __syncthreads();
    }
    if (threadIdx.x == 0) {
        double sb = ls[0], qb = lq[0];
        double va = (qa - sa * sa / n) / (n - 1.0);
        double vb = (qb - sb * sb / n) / (n - 1.0);
        va = va > 0.0 ? va : 0.0;
        vb = vb > 0.0 ? vb : 0.0;
        double sd = 0.5 * (sqrt(va) + sqrt(vb));
        sd = sd < 1e-6 ? 1e-6 : (sd > 1e9 ? 1e9 : sd);
        outm[0] = 0.5 * (sa / n + sb / n);
        outm[1] = 1.0 / (sd * sd * C);
    }
}

// ------- cost volume 1 (md=2, C=32) -> xin1 cols 0..124 --------------------
__global__ void k_cv1(bf16* __restrict__ xin1, const double* __restrict__ red) {
    __shared__ float fy[32];
    long p = blockIdx.x;
    float m = sf((float)red[0]), mult = sf((float)red[1]);
    int x = (int)(p % W1c), y = (int)((p / W1c) % H1c), z = (int)(p / (W1c * H1c));
    if (threadIdx.x < 32) fy[threadIdx.x] = sf(bf2f(xin1[cl(p * (long)S1 + 125 + threadIdx.x, NX1)])) - m;
    __syncthreads();
    int o = threadIdx.x;
    if (o >= 125) return;
    int dz = o / 25 - 2, dy = (o / 5) % 5 - 2, dx = o % 5 - 2;
    int z2 = z + dz, y2 = y + dy, x2 = x + dx;
    float cost = 0.f;
    if (z2 >= 0 && z2 < D1c && y2 >= 0 && y2 < H1c && x2 >= 0 && x2 < W1c) {
        long rb = ((long)(z2 * H1c + y2) * W1c + x2) * S1 + 157;
        float dot = 0.f;
        for (int c = 0; c < 32; ++c) dot += fy[c] * (sf(bf2f(xin1[cl(rb + c, NX1)])) - m);
        cost = dot * mult;
        cost = cost >= 0.f ? cost : 0.05f * cost;
    }
    xin1[cl(p * (long)S1 + o, NX1)] = f2bf(cost);
}

// ------- cost volume 2 (md=1, C=16) -> xin2 cols 0..26 ---------------------
__global__ void k_cv2(bf16* __restrict__ xin2, const double* __restrict__ red) {
    int t = threadIdx.x;
    int o = t % 32, vs = t / 32;
    long p = (long)blockIdx.x * 8 + vs;
    if (p >= NFULL || o >= 27) return;
    float m = sf((float)red[2]), mult = sf((float)red[3]);
    int x = (int)(p % W2c), y = (int)((p / W2c) % H2c), z = (int)(p / (W2c * H2c));
    int dz = o / 9 - 1, dy = (o / 3) % 3 - 1, dx = o % 3 - 1;
    int z2 = z + dz, y2 = y + dy, x2 = x + dx;
    float cost = 0.f;
    if (z2 >= 0 && z2 < D2c && y2 >= 0 && y2 < H2c && x2 >= 0 && x2 < W2c) {
        long fb = p * (long)S2 + 27;
        long wb = ((long)(z2 * H2c + y2) * W2c + x2) * S2 + 43;
        float dot = 0.f;
        for (int c = 0; c < 16; ++c)
            dot += (sf(bf2f(xin2[cl(fb + c, NX2)])) - m) * (sf(bf2f(xin2[cl(wb + c, NX2)])) - m);
        cost = dot * mult;
        cost = cost >= 0.f ? cost : 0.05f * cost;
    }
    xin2[cl(p * (long)S2 + o, NX2)] = f2bf(cost);
}

// ------- MFMA implicit-GEMM 3x3x3 conv, channel-last ----------------------
// z-column mapping (round 3) + dxi-clustered loads (round 5).
// Round-6: branchless load batching. Round-5's VGPR=44 showed the compiler
// sank every load next to its MFMA (runtime-z0 `continue`s broke the
// straight-line region) -> ~1 load in flight, 10x latency-bound (MfmaUtil 8%,
// VALU 8%, HBM 25%). Now per (dyi,ch): stage ALL (M+2)x3 A fragments with
// CLAMPED z addresses + wave-uniform zero masks (0*w == skip, exact), then
// per dxi load its 3*NT B fragments and run the unrolled MFMA fan-out.
// All-register, compile-time indices; 30+ independent loads batch per iter.
template<int NT, int NCH, int COUT, int M, int SS, int DD, int HH, int WW>
__global__ __launch_bounds__(256, 2) void k_conv_mfma(
        const bf16* __restrict__ src,
        const bf16* __restrict__ wtb, const void* __restrict__ bias,
        bf16* __restrict__ dst, int dstride, int dcol0,
        float slope, const int* __restrict__ bmodep) {
    const int bmode = *bmodep;
    const int tid = threadIdx.x;
    const int wave = tid >> 6, lane = tid & 63;
    const int quad = lane >> 4, nlo = lane & 15;
    constexpr long HW = (long)HH * WW;
    constexpr int XYG = (int)(HW / 64);      // xy-groups of 4 wave-tiles
    constexpr int P = M + 2;
    // bijective chunked swizzle (gridDim.x % 8 == 0 by construction)
    const u32 per = gridDim.x >> 3;
    const u32 bid = (blockIdx.x & 7u) * per + (blockIdx.x >> 3);
    const int xyg = (int)(bid % (u32)XYG);
    const int zg  = (int)(bid / (u32)XYG);
    const int t   = xyg * 4 + wave;          // xy tile id within a plane
    const int x   = (t * 16) % WW;
    const int y   = (t * 16) / WW;
    const int z0  = zg * M;

    f4v acc[M][NT];
    #pragma unroll
    for (int m = 0; m < M; ++m) {
        #pragma unroll
        for (int nt = 0; nt < NT; ++nt) {
            float bv = gld(bias, nt * 16 + nlo, bmode);
            acc[m][nt][0] = bv; acc[m][nt][1] = bv; acc[m][nt][2] = bv; acc[m][nt][3] = bv;
        }
    }

    const u32 selLo = (x == 0       && nlo == 0)  ? 0u : 0xFFFFFFFFu;
    const u32 selHi = (x == WW - 16 && nlo == 15) ? 0u : 0xFFFFFFFFu;

    // per-plane z validity (wave-uniform) + clamped plane offsets
    u32 zm[P];
    long zoff[P];
    #pragma unroll
    for (int p = 0; p < P; ++p) {
        const int z2 = z0 - 1 + p;
        const int zc = z2 < 0 ? 0 : (z2 >= DD ? DD - 1 : z2);
        zm[p] = ((unsigned)z2 < (unsigned)DD) ? 0xFFFFFFFFu : 0u;
        zoff[p] = (long)zc * HW * SS;
    }

    #pragma unroll 1
    for (int dyi = 0; dyi < 3; ++dyi) {
        const int y2 = y + dyi - 1;
        if ((unsigned)y2 >= (unsigned)HH) continue;      // wave-uniform skip
        const bf16* aprow = src + ((long)y2 * WW + x - 1 + nlo) * SS + quad * 8;
        const bf16* bp = wtb + (long)nlo * 32 + quad * 8;
        #pragma unroll 1
        for (int ch = 0; ch < NCH; ++ch) {
            // ---- stage 1: ALL A fragments, branchless (clamped + masked) --
            union U2 { uint4 u; s8v v; } a[P][3];
            #pragma unroll
            for (int p = 0; p < P; ++p) {
                const bf16* ap = aprow + zoff[p] + ch * 32;
                #pragma unroll
                for (int dxi = 0; dxi < 3; ++dxi)
                    a[p][dxi].u = *(const uint4*)(ap + dxi * SS);
            }
            #pragma unroll
            for (int p = 0; p < P; ++p) {
                #pragma unroll
                for (int dxi = 0; dxi < 3; ++dxi) {
                    const u32 mm = zm[p] & (dxi == 0 ? selLo : (dxi == 2 ? selHi : 0xFFFFFFFFu));
                    a[p][dxi].u.x &= mm; a[p][dxi].u.y &= mm;
                    a[p][dxi].u.z &= mm; a[p][dxi].u.w &= mm;
                }
            }
            // ---- stage 2: per dxi, B loads + MFMA fan-out -----------------
            #pragma unroll
            for (int dxi = 0; dxi < 3; ++dxi) {
                union U { uint4 u; s8v v; } b[3][NT];
                #pragma unroll
                for (int dz = 0; dz < 3; ++dz)
                    #pragma unroll
                    for (int nt = 0; nt < NT; ++nt)
                        b[dz][nt].u = *(const uint4*)(bp +
                            (((long)(dz * 9 + dyi * 3 + dxi) * NCH + ch) * COUT) * 32 + nt * 512);
                #pragma unroll
                for (int p = 0; p < P; ++p) {
                    #pragma unroll
                    for (int dz = 0; dz < 3; ++dz) {
                        constexpr int dummy = 0; (void)dummy;
                        const int m = p - dz;
                        if (m < 0 || m >= M) continue;   // compile-time prune
                        #pragma unroll
                        for (int nt = 0; nt < NT; ++nt)
                            acc[m][nt] = __builtin_amdgcn_mfma_f32_16x16x32_bf16(a[p][dxi].v, b[dz][nt].v, acc[m][nt], 0, 0, 0);
                    }
                }
            }
        }
    }

    #pragma unroll
    for (int m = 0; m < M; ++m) {
        const long vd = (long)(z0 + m) * HW + t * 16 + quad * 4;
        #pragma unroll
        for (int nt = 0; nt < NT; ++nt) {
            #pragma unroll
            for (int reg = 0; reg < 4; ++reg) {
                float v = acc[m][nt][reg];
                v = v >= 0.f ? v : v * slope;
                dst[(vd + reg) * (long)dstride + dcol0 + nt * 16 + nlo] = f2bf(v);
            }
        }
    }
}

// ------- tiled small conv: Cin=16 -> Cout=3, linear, f32 out ---------------
// LDS-staged z-column tiles: block = 16x16 xy-tile x ZS z-outputs. Stages the
// ZS+2 input planes (18x18 halo fragments x 32B) ONCE into LDS, then computes
// taps-outer / z-inner with the tap's 48 weights in registers (uniform scalar
// loads). FP accumulation order matches the original (tap asc, ci asc).
template<int ZS>
__global__ __launch_bounds__(256, 2) void k_conv_small_t(
        const bf16* __restrict__ src, int sstride, int scol0,
        const float* __restrict__ wt, const void* __restrict__ bias,
        float* __restrict__ dst, int D, int H, int W,
        const int* __restrict__ bmodep) {
    const int bmode = *bmodep;
    __shared__ bf16 lds[ZS + 2][18][18][16];   // ZS=4: 62208 B
    const int tid = threadIdx.x;
    const int gx = W >> 4;                      // W % 16 == 0
    const int gy = (H + 15) >> 4;
    const int xyt = (int)(blockIdx.x % (u32)(gx * gy));
    const int zg  = (int)(blockIdx.x / (u32)(gx * gy));
    const int x0 = (xyt % gx) << 4;
    const int y0 = (xyt / gx) << 4;
    const int z0 = zg * ZS;

    // ---- stage (ZS+2) planes of 18x18 fragments (zeros outside volume) ----
    const int NFRAG = (ZS + 2) * 324;
    for (int f = tid; f < NFRAG; f += 256) {
        int pl = f / 324, r = f - pl * 324;
        int yy = r / 18, xx = r - yy * 18;
        int z2 = z0 - 1 + pl, y2 = y0 - 1 + yy, x2 = x0 - 1 + xx;
        uint4 lo = {0, 0, 0, 0}, hi = {0, 0, 0, 0};
        if ((unsigned)z2 < (unsigned)D && (unsigned)y2 < (unsigned)H && (unsigned)x2 < (unsigned)W) {
            const bf16* p = src + ((long)(z2 * H + y2) * W + x2) * (long)sstride + scol0;
            lo = *(const uint4*)p;
            hi = *(const uint4*)(p + 8);
        }
        *(uint4*)&lds[pl][yy][xx][0] = lo;
        *(uint4*)&lds[pl][yy][xx][8] = hi;
    }
    __syncthreads();

    const int ty = tid >> 4, tx = tid & 15;
    const bool live = (y0 + ty) < H;

    float a0[ZS], a1[ZS], a2[ZS];
    {
        float b0 = gld(bias, 0, bmode), b1 = gld(bias, 1, bmode), b2 = gld(bias, 2, bmode);
        #pragma unroll
        for (int zz = 0; zz < ZS; ++zz) { a0[zz] = b0; a1[zz] = b1; a2[zz] = b2; }
    }

    #pragma unroll 1
    for (int tap = 0; tap < 27; ++tap) {
        const int dz = tap / 9, dy = (tap / 3) % 3, dx = tap % 3;
        const float* w = wt + tap * 48;          // uniform -> scalar loads
        float wv[48];
        #pragma unroll
        for (int k = 0; k < 48; ++k) wv[k] = w[k];
        #pragma unroll
        for (int zz = 0; zz < ZS; ++zz) {
            union { uint4 u[2]; bf16 h[16]; } fr;
            fr.u[0] = *(const uint4*)&lds[zz + dz][ty + dy][tx + dx][0];
            fr.u[1] = *(const uint4*)&lds[zz + dz][ty + dy][tx + dx][8];
            #pragma unroll
            for (int c = 0; c < 16; ++c) {
                float f = bf2f(fr.h[c]);
                a0[zz] += f * wv[c * 3];
                a1[zz] += f * wv[c * 3 + 1];
                a2[zz] += f * wv[c * 3 + 2];
            }
        }
    }

    if (!live) return;
    #pragma unroll
    for (int zz = 0; zz < ZS; ++zz) {
        long p = ((long)(z0 + zz) * H + (y0 + ty)) * W + (x0 + tx);
        dst[p * 3]     = sf(a0[zz]);
        dst[p * 3 + 1] = sf(a1[zz]);
        dst[p * 3 + 2] = sf(a2[zz]);
    }
}

// ------- x2 upsample taps ---------------------------------------------------
__device__ __forceinline__ void up_taps(int i, int n, int& j0, int& j1, float& w0, float& w1) {
    if (i & 1) { j0 = i >> 1; j1 = j0 + 1; w0 = 0.75f; w1 = 0.25f; if (j1 >= n) { j1 = j0; w0 = 1.f; w1 = 0.f; } }
    else { j1 = i >> 1; j0 = j1 - 1; w0 = 0.25f; w1 = 0.75f; if (j0 < 0) { j0 = j1; w0 = 0.f; w1 = 1.f; } }
}

// ctx16 [NHALF][16] -> xin2 cols 59..74
__global__ void k_up_ctx(const bf16* __restrict__ in, bf16* __restrict__ xin2) {
    long p = (long)blockIdx.x * 256 + threadIdx.x;
    if (p >= NFULL) return;
    int x = (int)(p % W2c), y = (int)((p / W2c) % H2c), z = (int)(p / (W2c * H2c));
    int jz0, jz1, jy0, jy1, jx0, jx1; float wz0, wz1, wy0, wy1, wx0, wx1;
    up_taps(z, D1c, jz0, jz1, wz0, wz1);
    up_taps(y, H1c, jy0, jy1, wy0, wy1);
    up_taps(x, W1c, jx0, jx1, wx0, wx1);
    float acc[16];
    for (int c = 0; c < 16; ++c) acc[c] = 0.f;
    int jzs[2] = { jz0, jz1 }; float wzs[2] = { wz0, wz1 };
    int jys[2] = { jy0, jy1 }; float wys[2] = { wy0, wy1 };
    int jxs[2] = { jx0, jx1 }; float wxs[2] = { wx0, wx1 };
    for (int a = 0; a < 2; ++a) {
        if (wzs[a] == 0.f) continue;
        for (int b = 0; b < 2; ++b) {
            if (wys[b] == 0.f) continue;
            float wzy = wzs[a] * wys[b];
            for (int d = 0; d < 2; ++d) {
                if (wxs[d] == 0.f) continue;
                float w = wzy * wxs[d];
                long rb = ((long)(jzs[a] * H1c + jys[b]) * W1c + jxs[d]) * 16;
                for (int c = 0; c < 16; ++c) acc[c] += w * bf2f(in[cl(rb + c, NCTX16)]);
            }
        }
    }
    for (int c = 0; c < 16; ++c) xin2[cl(p * (long)S2 + 59 + c, NX2)] = f2bf(acc[c]);
}

// fused: velup = 2*up(vel1); du2 = warp(disp_up, velup) + velup; xin2 75..77
__global__ void k_warp_dispup(const void* __restrict__ dispup, const float* __restrict__ vel1,
                              float* __restrict__ du2, bf16* __restrict__ xin2,
                              const int* __restrict__ modep) {
    int mode = *modep;
    long p = (long)blockIdx.x * 256 + threadIdx.x;
    if (p >= NFULL) return;
    int x = (int)(p % W2c), y = (int)((p / W2c) % H2c), z = (int)(p / (W2c * H2c));
    int jz0, jz1, jy0, jy1, jx0, jx1; float wz0, wz1, wy0, wy1, wx0, wx1;
    up_taps(z, D1c, jz0, jz1, wz0, wz1);
    up_taps(y, H1c, jy0, jy1, wy0, wy1);
    up_taps(x, W1c, jx0, jx1, wx0, wx1);
    int jzs[2] = { jz0, jz1 }; float wzs[2] = { wz0, wz1 };
    int jys[2] = { jy0, jy1 }; float wys[2] = { wy0, wy1 };
    int jxs[2] = { jx0, jx1 }; float wxs[2] = { wx0, wx1 };
    float vu[3] = { 0.f, 0.f, 0.f };
    for (int a = 0; a < 2; ++a) {
        if (wzs[a] == 0.f) continue;
        for (int b = 0; b < 2; ++b) {
            if (wys[b] == 0.f) continue;
            float wzy = wzs[a] * wys[b];
            for (int d = 0; d < 2; ++d) {
                if (wxs[d] == 0.f) continue;
                float w = wzy * wxs[d];
                long rb = ((long)(jzs[a] * H1c + jys[b]) * W1c + jxs[d]) * 3;
                for (int c = 0; c < 3; ++c) vu[c] += w * sf(vel1[cl(rb + c, N3H)]);
            }
        }
    }
    for (int c = 0; c < 3; ++c) vu[c] = sf(vu[c] * 2.f);
    float cz = z + vu[0], cy = y + vu[1], cx = x + vu[2];
    float acc[3] = { 0.f, 0.f, 0.f };
    float z0f = floorf(cz), y0f = floorf(cy), x0f = floorf(cx);
    int z0 = (int)z0f, y0 = (int)y0f, x0 = (int)x0f;
    float fz = cz - z0f, fy = cy - y0f, fx = cx - x0f;
    for (int dz = 0; dz < 2; ++dz) {
        int zi = z0 + dz; if (zi < 0 || zi >= D2c) continue;
        float wz = dz ? fz : 1.f - fz;
        for (int dy = 0; dy < 2; ++dy) {
            int yi = y0 + dy; if (yi < 0 || yi >= H2c) continue;
            float wzy = wz * (dy ? fy : 1.f - fy);
            for (int dx = 0; dx < 2; ++dx) {
                int xi = x0 + dx; if (xi < 0 || xi >= W2c) continue;
                float w = wzy * (dx ? fx : 1.f - fx);
                long idx = (long)(zi * H2c + yi) * W2c + xi;
                for (int c = 0; c < 3; ++c) acc[c] += w * gld(dispup, cl((long)c * NFULL + idx, 3 * NFULL), mode);
            }
        }
    }
    for (int c = 0; c < 3; ++c) {
        float v = sf(acc[c] + vu[c]);
        du2[cl(p * 3 + c, N3F)] = v;
        xin2[cl(p * (long)S2 + 75 + c, NX2)] = f2bf(v);
    }
}

// robust t decode (handles bf16-stored or f32-stored scalar)
__device__ __forceinline__ float decode_t(const u16* tp) {
    u16 b0 = tp[0], b1 = tp[1];
    union { u32 i; float f; } a, b;
    a.i = ((u32)b0) << 16;
    b.i = ((u32)b1 << 16) | b0;
    float ta = a.f, tb = b.f;
    bool okA = (ta == ta) && ta >= 0.f && ta < 0.75f;
    bool okB = (tb == tb) && tb >= 0.f && tb < 0.75f;
    return okB ? tb : (okA ? ta : 0.f);
}

// vf = (warp(du2, vu2) + vu2 - disp_up) / (1 - t); out mode-dispatched
__global__ void k_final(const float* __restrict__ du2, const float* __restrict__ vu2,
                        const void* __restrict__ dispup, const u16* __restrict__ tptr,
                        void* __restrict__ out, long out_n, const int* __restrict__ modep) {
    int mode = *modep;
    long p = (long)blockIdx.x * 256 + threadIdx.x;
    if (p >= NFULL) return;
    float t = decode_t(tptr);
    float den = 1.f - t;
    if (fabsf(den) < 1e-6f) den = 1e-6f;
    float inv = 1.f / den;
    int x = (int)(p % W2c), y = (int)((p / W2c) % H2c), z = (int)(p / (W2c * H2c));
    float cz = z + sf(vu2[cl(p * 3, N3F)]);
    float cy = y + sf(vu2[cl(p * 3 + 1, N3F)]);
    float cx = x + sf(vu2[cl(p * 3 + 2, N3F)]);
    float acc[3] = { 0.f, 0.f, 0.f };
    float z0f = floorf(cz), y0f = floorf(cy), x0f = floorf(cx);
    int z0 = (int)z0f, y0 = (int)y0f, x0 = (int)x0f;
    float fz = cz - z0f, fy = cy - y0f, fx = cx - x0f;
    for (int dz = 0; dz < 2; ++dz) {
        int zi = z0 + dz; if (zi < 0 || zi >= D2c) continue;
        float wz = dz ? fz : 1.f - fz;
        for (int dy = 0; dy < 2; ++dy) {
            int yi = y0 + dy; if (yi < 0 || yi >= H2c) continue;
            float wzy = wz * (dy ? fy : 1.f - fy);
            for (int dx = 0; dx < 2; ++dx) {
                int xi = x0 + dx; if (xi < 0 || xi >= W2c) continue;
                float w = wzy * (dx ? fx : 1.f - fx);
                long rb = ((long)(zi * H2c + yi) * W2c + xi) * 3;
                for (int c = 0; c < 3; ++c) acc[c] += w * sf(du2[cl(rb + c, N3F)]);
            }
        }
    }
    for (int c = 0; c < 3; ++c) {
        float v = (acc[c] + sf(vu2[cl(p * 3 + c, N3F)]) - gld(dispup, cl((long)c * NFULL + p, 3 * NFULL), mode)) * inv;
        long oi = cl((long)c * NFULL + p, out_n);
        if (mode) ((float*)out)[oi] = sf(v);
        else      ((bf16*)out)[oi] = f2bf(v);
    }
}

static inline int cdiv(long a, long b) { return (int)((a + b - 1) / b); }

extern "C" void kernel_launch(void* const* d_in, const int* in_sizes, int n_in,
                              void* d_out, int out_size, void* d_ws, size_t ws_size,
                              hipStream_t stream) {
    const u16* t_in = (const u16*)d_in[0];
    const void* disp_up = d_in[1];
    const void* fx  = d_in[2];
    const void* fy  = d_in[3];
    const void* fxu = d_in[4];
    const void* fyu = d_in[5];
    const void* ctx = d_in[6];

    const size_t XIN1_B = (size_t)NX1 * 2;
    const size_t XIN2_B = (size_t)NX2 * 2;
    // guards before/after the xin region so masked halo loads (x = -1 / x = W)
    // stay inside the allocation (max overhang = S1*2 = 736 B < GUARD)
    const size_t base_need = XIN1_B + XIN2_B + 2 * (size_t)GUARD;
    const size_t base_pad = (base_need + 255) & ~(size_t)255;
    const size_t vf_elems = 3UL * NFULL;

    // wtb sizes (bf16 elements): 27 * nchunk * Cout * 32
    const long WTB0 = 387072;  // 224->64, 7ch
    const long WTB1 = 373248;  // 288->48, 9ch
    const long WTB2 = 304128;  // 336->32, 11ch
    const long WTB3 = 165888;  // 368->16, 12ch
    const long WTB5 = 82944;   // 78->32, 3ch
    const long WTB6 = 55296;   // 110->16, 4ch
    const long WTB_TOT = WTB0 + WTB1 + WTB2 + WTB3 + WTB5 + WTB6; // 1,368,576

    size_t scro[11];
    {
        size_t o = 0;
        auto al = [&](size_t bytes) { size_t r = o; o = (o + bytes + 255) & ~(size_t)255; return r; };
        scro[0] = al((size_t)WTB_TOT * 2);      // WTB (bf16, mfma layout)
        scro[1] = al(2UL * 1296 * 4);           // WT f32 (two small convs)
        scro[2] = al((size_t)NCTX16 * 2);       // CTX16
        scro[3] = al((size_t)N3H * 4);          // VEL1
        scro[4] = al((size_t)N3H * 4);          // DISPH
        scro[5] = al((size_t)N3F * 4);          // DU2
        scro[6] = al((size_t)N3F * 4);          // VU2
        scro[7] = al(4UL * RG * 2 * 8);         // partials
        scro[8] = al(16 * 8);                   // RED
        scro[9] = al(32 * 4);                   // MODES
        scro[10] = o;
    }
    const size_t scratch_need = scro[10];
    const size_t tail_avail = ((size_t)out_size > vf_elems) ? ((size_t)out_size - vf_elems) * 2 : 0;

    char* scr = nullptr;
    if (ws_size >= base_pad + scratch_need) {
        scr = (char*)d_ws + base_pad;
    } else if (ws_size >= base_need && tail_avail >= scratch_need) {
        scr = (char*)d_out + vf_elems * 2;
    }
    if (scr == nullptr) {
        k_fill<<<2048, 256, 0, stream>>>((u16*)d_out, (long)out_size, 0x49A0);
        return;
    }

    char* ws = (char*)d_ws;
    bf16*  xin1  = (bf16*)(ws + GUARD);
    bf16*  xin2  = (bf16*)(ws + GUARD + XIN1_B);
    bf16*  wtball = (bf16*)(scr + scro[0]);
    float* wtf   = (float*)(scr + scro[1]);
    bf16*  ctx16 = (bf16*)(scr + scro[2]);
    float* vel1  = (float*)(scr + scro[3]);
    float* disph = (float*)(scr + scro[4]);
    float* du2   = (float*)(scr + scro[5]);
    float* vu2   = (float*)(scr + scro[6]);
    double* part = (double*)(scr + scro[7]);
    double* red  = (double*)(scr + scro[8]);
    int*   modes = (int*)(scr + scro[9]);
    double* pA = part;
    double* pB = part + RG * 2;
    double* pC = part + RG * 4;
    double* pD = part + RG * 6;

    bf16* wtb0 = wtball;
    bf16* wtb1 = wtb0 + WTB0;
    bf16* wtb2 = wtb1 + WTB1;
    bf16* wtb3 = wtb2 + WTB2;
    bf16* wtb5 = wtb3 + WTB3;
    bf16* wtb6 = wtb5 + WTB5;
    float* wt4 = wtf;
    float* wt7 = wtf + 1296;

    // zero-init big buffers (incl. guards) and scratch (modes default 0 = bf16)
    k_fill<<<4096, 256, 0, stream>>>((u16*)ws, (long)(base_need / 2), 0);
    k_fill<<<4096, 256, 0, stream>>>((u16*)scr, (long)(scratch_need / 2), 0);

    // dtype detection for all tensor inputs
    for (int i = 1; i < 23 && i < n_in; ++i) {
        k_detect<<<1, 256, 0, stream>>>(d_in[i], (long)in_sizes[i], modes + i);
    }

    // MFMA weight repack (bf16, zero-padded K tails)
    k_wtb<<<cdiv(WTB0, 256), 256, 0, stream>>>(d_in[7],  wtb0, 224, 64, 7,  modes + 7);
    k_wtb<<<cdiv(WTB1, 256), 256, 0, stream>>>(d_in[9],  wtb1, 288, 48, 9,  modes + 9);
    k_wtb<<<cdiv(WTB2, 256), 256, 0, stream>>>(d_in[11], wtb2, 336, 32, 11, modes + 11);
    k_wtb<<<cdiv(WTB3, 256), 256, 0, stream>>>(d_in[13], wtb3, 368, 16, 12, modes + 13);
    k_wtb<<<cdiv(WTB5, 256), 256, 0, stream>>>(d_in[17], wtb5, 78,  32, 3,  modes + 17);
    k_wtb<<<cdiv(WTB6, 256), 256, 0, stream>>>(d_in[19], wtb6, 110, 16, 4,  modes + 19);
    // f32 weights for the two small convs
    k_wt<<<cdiv(1296, 256), 256, 0, stream>>>(d_in[15], wt4, 16, 3, modes + 15);
    k_wt<<<cdiv(1296, 256), 256, 0, stream>>>(d_in[21], wt7, 16, 3, modes + 21);

    k_tcl<<<cdiv(NHALF, 256), 256, 0, stream>>>(fy,  32L * NHALF, xin1, NX1, 125, 32, NHALF, S1, modes + 3);
    k_tcl<<<cdiv(NHALF, 256), 256, 0, stream>>>(ctx, 32L * NHALF, xin1, NX1, 189, 32, NHALF, S1, modes + 6);
    k_tcl<<<cdiv(NFULL, 256), 256, 0, stream>>>(fyu, 16L * NFULL, xin2, NX2, 27, 16, NFULL, S2, modes + 5);

    k_down<<<cdiv(NHALF, 256), 256, 0, stream>>>(disp_up, disph, xin1, modes + 1);

    k_warp_cf<32><<<cdiv(NHALF, 256), 256, 0, stream>>>(fx, 32L * NHALF, disph, N3H, xin1, NX1, S1, 157, D1c, H1c, W1c, modes + 2);
    k_reduce_cl<<<RG, 256, 0, stream>>>(xin1, NX1, NHALF, S1, 157, 32, pA, modes + 31);
    k_reduce_cl<<<RG, 256, 0, stream>>>(fy, 32L * NHALF, 32L * NHALF, 1, 0, 1, pB, modes + 3);
    k_stats2<<<1, 256, 0, stream>>>(pA, pB, (double)(32L * NHALF), 32.0, red);

    k_cv1<<<(int)NHALF, 128, 0, stream>>>(xin1, red);

    // fl1 dense block — z-column MFMA implicit GEMM (M=2 z-planes/wave)
    // grid = (HW/64 xy-groups = 30) x (48/2 zgroups = 24) = 720 (%8==0)
    k_conv_mfma<4, 7, 64, 2, S1, D1c, H1c, W1c><<<720, 256, 0, stream>>>(xin1, wtb0, d_in[8],  xin1, S1, 224, 0.02f, modes + 8);
    k_conv_mfma<3, 9, 48, 2, S1, D1c, H1c, W1c><<<720, 256, 0, stream>>>(xin1, wtb1, d_in[10], xin1, S1, 288, 0.02f, modes + 10);
    k_conv_mfma<2, 11, 32, 2, S1, D1c, H1c, W1c><<<720, 256, 0, stream>>>(xin1, wtb2, d_in[12], xin1, S1, 336, 0.02f, modes + 12);
    k_conv_mfma<1, 12, 16, 2, S1, D1c, H1c, W1c><<<720, 256, 0, stream>>>(xin1, wtb3, d_in[14], ctx16, 16, 0, 0.02f, modes + 14);
    // tiled small conv (NHALF): grid = 3x3 xy-tiles x 12 zgroups = 108
    k_conv_small_t<4><<<108, 256, 0, stream>>>(ctx16, 16, 0, wt4, d_in[16], vel1, D1c, H1c, W1c, modes + 16);

    k_up_ctx<<<cdiv(NFULL, 256), 256, 0, stream>>>(ctx16, xin2);
    k_warp_dispup<<<cdiv(NFULL, 256), 256, 0, stream>>>(disp_up, vel1, du2, xin2, modes + 1);

    k_warp_cf<16><<<cdiv(NFULL, 256), 256, 0, stream>>>(fxu, 16L * NFULL, du2, N3F, xin2, NX2, S2, 43, D2c, H2c, W2c, modes + 4);
    k_reduce_cl<<<RG, 256, 0, stream>>>(xin2, NX2, NFULL, S2, 43, 16, pC, modes + 31);
    k_reduce_cl<<<RG, 256, 0, stream>>>(fyu, 16L * NFULL, 16L * NFULL, 1, 0, 1, pD, modes + 5);
    k_stats2<<<1, 256, 0, stream>>>(pC, pD, (double)(16L * NFULL), 16.0, red + 2);

    k_cv2<<<cdiv(NFULL, 8), 256, 0, stream>>>(xin2, red);

    // fl2 block — z-column MFMA (M=4 z-planes/wave)
    // grid = (7680/64 = 120 xy-groups) x (96/4 = 24 zgroups) = 2880 (%8==0)
    k_conv_mfma<2, 3, 32, 4, S2, D2c, H2c, W2c><<<2880, 256, 0, stream>>>(xin2, wtb5, d_in[18], xin2, S2, 78,  0.02f, modes + 18);
    k_conv_mfma<1, 4, 16, 4, S2, D2c, H2c, W2c><<<2880, 256, 0, stream>>>(xin2, wtb6, d_in[20], xin2, S2, 110, 0.02f, modes + 20);
    // tiled small conv (NFULL): grid = 6x5 xy-tiles x 24 zgroups = 720
    k_conv_small_t<4><<<720, 256, 0, stream>>>(xin2, S2, 110, wt7, d_in[22], vu2, D2c, H2c, W2c, modes + 22);

    // out dtype follows disp_up's detected mode
    k_final<<<cdiv(NFULL, 256), 256, 0, stream>>>(du2, vu2, disp_up, t_in, d_out, (long)out_size, modes + 1);
    k_fill_tail<<<2048, 256, 0, stream>>>(d_out, (long)vf_elems, (long)out_size, modes + 1);
}

// Round 7
// 2934.695 us; speedup vs baseline: 1.2285x; 1.2285x over previous
//
#include <hip/hip_runtime.h>
#include <hip/hip_bf16.h>

typedef __hip_bfloat16 bf16;
typedef unsigned short u16;
typedef unsigned int u32;

#define D1c 48
#define H1c 40
#define W1c 48
#define NHALF 92160L
#define D2c 96
#define H2c 80
#define W2c 96
#define NFULL 737280L
#define S1 368
#define S2 128
#define RG 512

#define NX1 (NHALF * S1)
#define NX2 (NFULL * S2)
#define NCTX16 (NHALF * 16)
#define N3H (NHALF * 3)
#define N3F (NFULL * 3)
#define GUARD 1024

typedef __attribute__((ext_vector_type(8))) short s8v;
typedef __attribute__((ext_vector_type(4))) float f4v;

__device__ __forceinline__ float bf2f(bf16 v){ return __bfloat162float(v); }
__device__ __forceinline__ float sf(float v){ return (v == v && fabsf(v) < 1e30f) ? v : 0.f; }
__device__ __forceinline__ bf16 f2bf(float v){ return __float2bfloat16(sf(v)); }
__device__ __forceinline__ long cl(long i, long n){ i = i < 0 ? 0 : i; return i >= n ? n - 1 : i; }
// mode-dispatched input load: 0 = bf16, 1 = f32
__device__ __forceinline__ float gld(const void* p, long i, int mode){
    return mode ? sf(((const float*)p)[i]) : sf(bf2f(((const bf16*)p)[i]));
}

// ---------------- dtype detection: one block per input ---------------------
__global__ void k_detect(const void* p, long nelem, int* flag) {
    long N = nelem < 4096 ? nelem : 4096;
    int tid = threadIdx.x;
    int nb = 0, nf = 0;
    for (long i = tid; i < N; i += 256) {
        float v = bf2f(((const bf16*)p)[i]);
        if (v == v && fabsf(v) <= 1e4f) nb++;
    }
    long M = N / 2;
    for (long i = tid; i < M; i += 256) {
        float v = ((const float*)p)[i];
        if (v == v && fabsf(v) <= 1e4f) nf += 2;
    }
    __shared__ int sb[256], sq[256];
    sb[tid] = nb; sq[tid] = nf;
    __syncthreads();
    for (int t = 128; t; t >>= 1) {
        if (tid < t) { sb[tid] += sb[tid + t]; sq[tid] += sq[tid + t]; }
        __syncthreads();
    }
    if (tid == 0) *flag = (sb[0] >= sq[0]) ? 0 : 1;
}

// ---------------- fills -----------------------------------------------------
__global__ void k_fill(u16* __restrict__ p, long n, u16 val) {
    long i = (long)blockIdx.x * 256 + threadIdx.x;
    long stride = (long)gridDim.x * 256;
    for (; i < n; i += stride) p[i] = val;
}
__global__ void k_fill_tail(void* out, long vf, long out_n, const int* __restrict__ modep) {
    int mode = *modep;
    long n = out_n - vf;
    if (n <= 0) return;
    long i = (long)blockIdx.x * 256 + threadIdx.x;
    long stride = (long)gridDim.x * 256;
    if (mode) { float* p = (float*)out + vf; for (; i < n; i += stride) p[i] = 0.f; }
    else      { u16*   p = (u16*)out + vf;   for (; i < n; i += stride) p[i] = 0; }
}

// ------- weight transpose: (co,ci,tap) -> (tap,ci,co) f32 (small convs) ----
__global__ void k_wt(const void* __restrict__ w, float* __restrict__ wt,
                     int Cin, int Cout, const int* __restrict__ modep) {
    int mode = *modep;
    long n = (long)Cin * Cout * 27;
    long i = (long)blockIdx.x * 256 + threadIdx.x;
    if (i >= n) return;
    int tap = (int)(i % 27); long r = i / 27;
    int ci = (int)(r % Cin); int co = (int)(r / Cin);
    wt[cl(((long)tap * Cin + ci) * Cout + co, n)] = gld(w, cl(i, n), mode);
}

// ------- MFMA weight repack: (co,ci,tap) -> [tap][chunk][co][32] bf16 ------
// zero-padded for ci >= Cin (Cin tails)
__global__ void k_wtb(const void* __restrict__ w, bf16* __restrict__ wtb,
                      int Cin, int Cout, int nchunk, const int* __restrict__ modep) {
    int mode = *modep;
    long n = 27L * nchunk * Cout * 32;
    long i = (long)blockIdx.x * 256 + threadIdx.x;
    if (i >= n) return;
    int kk = (int)(i & 31);
    long r = i >> 5;
    int co = (int)(r % Cout); r /= Cout;
    int ch = (int)(r % nchunk); int tap = (int)(r / nchunk);
    int ci = ch * 32 + kk;
    float v = (ci < Cin) ? gld(w, ((long)co * Cin + ci) * 27 + tap, mode) : 0.f;
    wtb[i] = f2bf(v);
}

// ------- channel-first [C][N] -> channel-last columns ----------------------
__global__ void k_tcl(const void* __restrict__ in, long nin,
                      bf16* __restrict__ out, long nout, int col0,
                      int C, long N, int stride, const int* __restrict__ modep) {
    int mode = *modep;
    long n = (long)blockIdx.x * 256 + threadIdx.x;
    if (n >= N) return;
    for (int c = 0; c < C; ++c)
        out[cl(n * stride + col0 + c, nout)] = f2bf(gld(in, cl((long)c * N + n, nin), mode));
}

// ------- antialiased x0.5 downsample taps ----------------------------------
__device__ __forceinline__ void down_taps(int i, int n_in, int j[4], float w[4]) {
    float s = 0.f;
    for (int k = 0; k < 4; ++k) {
        int jj = 2 * i - 1 + k;
        bool valid = (jj >= 0 && jj < n_in);
        j[k] = valid ? jj : 0;
        float b = (k == 0 || k == 3) ? 1.f : 3.f;
        w[k] = valid ? b : 0.f;
        s += w[k];
    }
    float inv = 1.f / fmaxf(s, 1e-6f);
    for (int k = 0; k < 4; ++k) w[k] *= inv;
}

// disp = resize(disp_up,0.5)*0.5 -> disph f32 + xin1 cols 221..223
__global__ void k_down(const void* __restrict__ dispup, float* __restrict__ disph,
                       bf16* __restrict__ xin1, const int* __restrict__ modep) {
    int mode = *modep;
    long p = (long)blockIdx.x * 256 + threadIdx.x;
    if (p >= NHALF) return;
    int x = (int)(p % W1c), y = (int)((p / W1c) % H1c), z = (int)(p / (W1c * H1c));
    int jz[4], jy[4], jx[4]; float wz[4], wy[4], wx[4];
    down_taps(z, D2c, jz, wz); down_taps(y, H2c, jy, wy); down_taps(x, W2c, jx, wx);
    for (int c = 0; c < 3; ++c) {
        float acc = 0.f;
        for (int a = 0; a < 4; ++a) {
            if (wz[a] == 0.f) continue;
            for (int b = 0; b < 4; ++b) {
                if (wy[b] == 0.f) continue;
                float wzy = wz[a] * wy[b];
                long base = (long)c * NFULL + ((long)jz[a] * H2c + jy[b]) * W2c;
                for (int d = 0; d < 4; ++d) {
                    if (wx[d] == 0.f) continue;
                    acc += wzy * wx[d] * gld(dispup, cl(base + jx[d], 3 * NFULL), mode);
                }
            }
        }
        acc = sf(acc * 0.5f);
        disph[cl(p * 3 + c, N3H)] = acc;
        xin1[cl(p * (long)S1 + 221 + c, NX1)] = f2bf(acc);
    }
}

// ------- trilinear warp, channel-first INPUT volume, zero pad --------------
template<int C>
__global__ void k_warp_cf(const void* __restrict__ vol, long nvol,
                          const float* __restrict__ coords, long ncoords,
                          bf16* __restrict__ dst, long ndst, int dstride, int col0,
                          int D, int H, int W, const int* __restrict__ modep) {
    int mode = *modep;
    const long N = (long)D * H * W;
    long p = (long)blockIdx.x * 256 + threadIdx.x;
    if (p >= N) return;
    int x = (int)(p % W), y = (int)((p / W) % H), z = (int)(p / ((long)W * H));
    float cz = z + sf(coords[cl(p * 3, ncoords)]);
    float cy = y + sf(coords[cl(p * 3 + 1, ncoords)]);
    float cx = x + sf(coords[cl(p * 3 + 2, ncoords)]);
    float acc[C];
    for (int c = 0; c < C; ++c) acc[c] = 0.f;
    float z0f = floorf(cz), y0f = floorf(cy), x0f = floorf(cx);
    int z0 = (int)z0f, y0 = (int)y0f, x0 = (int)x0f;
    float fz = cz - z0f, fy = cy - y0f, fx = cx - x0f;
    for (int dz = 0; dz < 2; ++dz) {
        int zi = z0 + dz; if (zi < 0 || zi >= D) continue;
        float wz = dz ? fz : 1.f - fz;
        for (int dy = 0; dy < 2; ++dy) {
            int yi = y0 + dy; if (yi < 0 || yi >= H) continue;
            float wzy = wz * (dy ? fy : 1.f - fy);
            for (int dx = 0; dx < 2; ++dx) {
                int xi = x0 + dx; if (xi < 0 || xi >= W) continue;
                float w = wzy * (dx ? fx : 1.f - fx);
                long idx = (long)(zi * H + yi) * W + xi;
                for (int c = 0; c < C; ++c) acc[c] += w * gld(vol, cl((long)c * N + idx, nvol), mode);
            }
        }
    }
    for (int c = 0; c < C; ++c) dst[cl(p * (long)dstride + col0 + c, ndst)] = f2bf(acc[c]);
}

// ------- two-stage deterministic reduction (sum, sumsq) --------------------
__global__ void k_reduce_cl(const void* __restrict__ base, long nbase, long rows,
                            int stride, int col0, int cn, double* __restrict__ part,
                            const int* __restrict__ modep) {
    int mode = *modep;
    long total = rows * cn;
    double s = 0.0, q = 0.0;
    long i = (long)blockIdx.x * 256 + threadIdx.x;
    long gs = (long)gridDim.x * 256;
    for (; i < total; i += gs) {
        long r = i / cn; int c = (int)(i - r * cn);
        float f = gld(base, cl(r * (long)stride + col0 + c, nbase), mode);
        s += f; q += (double)f * f;
    }
    __shared__ double ls[256], lq[256];
    ls[threadIdx.x] = s; lq[threadIdx.x] = q;
    __syncthreads();
    for (int t = 128; t; t >>= 1) {
        if (threadIdx.x < t) { ls[threadIdx.x] += ls[threadIdx.x + t]; lq[threadIdx.x] += lq[threadIdx.x + t]; }
        __syncthreads();
    }
    if (threadIdx.x == 0) { part[cl(blockIdx.x * 2, RG * 2)] = ls[0]; part[cl(blockIdx.x * 2 + 1, RG * 2)] = lq[0]; }
}

__global__ void k_stats2(const double* __restrict__ pa, const double* __restrict__ pb,
                         double n, double C, double* __restrict__ outm) {
    __shared__ double ls[256], lq[256];
    double s = 0.0, q = 0.0;
    for (int i = threadIdx.x; i < RG; i += 256) { s += pa[i * 2]; q += pa[i * 2 + 1]; }
    ls[threadIdx.x] = s; lq[threadIdx.x] = q;
    __syncthreads();
    for (int t = 128; t; t >>= 1) {
        if (threadIdx.x < t) { ls[threadIdx.x] += ls[threadIdx.x + t]; lq[threadIdx.x] += lq[threadIdx.x + t]; }
        __syncthreads();
    }
    double sa = ls[0], qa = lq[0];
    __syncthreads();
    s = 0.0; q = 0.0;
    for (int i = threadIdx.x; i < RG; i += 256) { s += pb[i * 2]; q += pb[i * 2 + 1]; }
    ls[threadIdx.x] = s; lq[threadIdx.x] = q;
    __syncthreads();
    for (int t = 128; t; t >>= 1) {
        if (threadIdx.x < t) { ls[threadIdx.x] += ls[threadIdx.x + t]; lq[threadIdx.x] += lq[threadIdx.x + t]; }
        __syncthreads();
    }
    if (threadIdx.x == 0) {
        double sb = ls[0], qb = lq[0];
        double va = (qa - sa * sa / n) / (n - 1.0);
        double vb = (qb - sb * sb / n) / (n - 1.0);
        va = va > 0.0 ? va : 0.0;
        vb = vb > 0.0 ? vb : 0.0;
        double sd = 0.5 * (sqrt(va) + sqrt(vb));
        sd = sd < 1e-6 ? 1e-6 : (sd > 1e9 ? 1e9 : sd);
        outm[0] = 0.5 * (sa / n + sb / n);
        outm[1] = 1.0 / (sd * sd * C);
    }
}

// ------- cost volume 1 (md=2, C=32) -> xin1 cols 0..124 --------------------
__global__ void k_cv1(bf16* __restrict__ xin1, const double* __restrict__ red) {
    __shared__ float fy[32];
    long p = blockIdx.x;
    float m = sf((float)red[0]), mult = sf((float)red[1]);
    int x = (int)(p % W1c), y = (int)((p / W1c) % H1c), z = (int)(p / (W1c * H1c));
    if (threadIdx.x < 32) fy[threadIdx.x] = sf(bf2f(xin1[cl(p * (long)S1 + 125 + threadIdx.x, NX1)])) - m;
    __syncthreads();
    int o = threadIdx.x;
    if (o >= 125) return;
    int dz = o / 25 - 2, dy = (o / 5) % 5 - 2, dx = o % 5 - 2;
    int z2 = z + dz, y2 = y + dy, x2 = x + dx;
    float cost = 0.f;
    if (z2 >= 0 && z2 < D1c && y2 >= 0 && y2 < H1c && x2 >= 0 && x2 < W1c) {
        long rb = ((long)(z2 * H1c + y2) * W1c + x2) * S1 + 157;
        float dot = 0.f;
        for (int c = 0; c < 32; ++c) dot += fy[c] * (sf(bf2f(xin1[cl(rb + c, NX1)])) - m);
        cost = dot * mult;
        cost = cost >= 0.f ? cost : 0.05f * cost;
    }
    xin1[cl(p * (long)S1 + o, NX1)] = f2bf(cost);
}

// ------- cost volume 2 (md=1, C=16) -> xin2 cols 0..26 ---------------------
__global__ void k_cv2(bf16* __restrict__ xin2, const double* __restrict__ red) {
    int t = threadIdx.x;
    int o = t % 32, vs = t / 32;
    long p = (long)blockIdx.x * 8 + vs;
    if (p >= NFULL || o >= 27) return;
    float m = sf((float)red[2]), mult = sf((float)red[3]);
    int x = (int)(p % W2c), y = (int)((p / W2c) % H2c), z = (int)(p / (W2c * H2c));
    int dz = o / 9 - 1, dy = (o / 3) % 3 - 1, dx = o % 3 - 1;
    int z2 = z + dz, y2 = y + dy, x2 = x + dx;
    float cost = 0.f;
    if (z2 >= 0 && z2 < D2c && y2 >= 0 && y2 < H2c && x2 >= 0 && x2 < W2c) {
        long fb = p * (long)S2 + 27;
        long wb = ((long)(z2 * H2c + y2) * W2c + x2) * S2 + 43;
        float dot = 0.f;
        for (int c = 0; c < 16; ++c)
            dot += (sf(bf2f(xin2[cl(fb + c, NX2)])) - m) * (sf(bf2f(xin2[cl(wb + c, NX2)])) - m);
        cost = dot * mult;
        cost = cost >= 0.f ? cost : 0.05f * cost;
    }
    xin2[cl(p * (long)S2 + o, NX2)] = f2bf(cost);
}

// ------- MFMA implicit-GEMM 3x3x3 conv, channel-last, LDS-staged -----------
// Round-7: block = 4 waves = 4 consecutive y-rows x one 16-voxel x-segment x
// M z-planes (grids unchanged). Per ch-chunk: barrier -> 256 threads stage the
// block's FULL A-halo [M+2 planes][6 rows][18 voxels][32ch] into LDS (~2600
// independent 16B loads, dense, MLP guaranteed regardless of the compiler's
// load-sinking heuristic that defeated rounds 5/6 register staging) ->
// barrier -> waves consume via ds_read_b128 with clamped-address + zero-mask
// semantics (exact, 0*w == skip). Each input element fetched ONCE per block:
// redundancy 18/16 x 6/4 x (M+2)/M ~= 2.5x of unique vs ~13x issued before.
template<int NT, int NCH, int COUT, int M, int SS, int DD, int HH, int WW>
__global__ __launch_bounds__(256, 2) void k_conv_mfma(
        const bf16* __restrict__ src,
        const bf16* __restrict__ wtb, const void* __restrict__ bias,
        bf16* __restrict__ dst, int dstride, int dcol0,
        float slope, const int* __restrict__ bmodep) {
    const int bmode = *bmodep;
    const int tid = threadIdx.x;
    const int wave = tid >> 6, lane = tid & 63;
    const int quad = lane >> 4, nlo = lane & 15;
    constexpr long HW = (long)HH * WW;
    constexpr int PL = M + 2;            // staged planes
    constexpr int NXB = WW / 16;
    constexpr int NYB = HH / 4;          // 4 rows per block (one per wave)
    constexpr int NXY = NXB * NYB;
    __shared__ bf16 lds[PL][6][18][32];  // M=4: 41472 B, M=2: 27648 B

    // bijective chunked swizzle (gridDim.x % 8 == 0 by construction)
    const u32 per = gridDim.x >> 3;
    const u32 bid = (blockIdx.x & 7u) * per + (blockIdx.x >> 3);
    const int xyb = (int)(bid % (u32)NXY);
    const int zg  = (int)(bid / (u32)NXY);
    const int x0 = (xyb % NXB) * 16;
    const int y0 = (xyb / NXB) * 4;
    const int z0 = zg * M;

    f4v acc[M][NT];
    #pragma unroll
    for (int m = 0; m < M; ++m) {
        #pragma unroll
        for (int nt = 0; nt < NT; ++nt) {
            float bv = gld(bias, nt * 16 + nlo, bmode);
            acc[m][nt][0] = bv; acc[m][nt][1] = bv; acc[m][nt][2] = bv; acc[m][nt][3] = bv;
        }
    }

    const u32 selLo = (x0 == 0       && nlo == 0)  ? 0u : 0xFFFFFFFFu;
    const u32 selHi = (x0 == WW - 16 && nlo == 15) ? 0u : 0xFFFFFFFFu;

    u32 zm[PL];
    #pragma unroll
    for (int p = 0; p < PL; ++p) {
        const int z2 = z0 - 1 + p;
        zm[p] = ((unsigned)z2 < (unsigned)DD) ? 0xFFFFFFFFu : 0u;
    }
    u32 ym[3];
    #pragma unroll
    for (int dyi = 0; dyi < 3; ++dyi) {
        const int y2 = y0 + wave + dyi - 1;
        ym[dyi] = ((unsigned)y2 < (unsigned)HH) ? 0xFFFFFFFFu : 0u;
    }

    constexpr int NQ = PL * 6 * 18 * 4;      // 16B quarters to stage per ch
    constexpr int KQ = (NQ + 255) / 256;

    const bf16* bp = wtb + (long)nlo * 32 + quad * 8;

    #pragma unroll 1
    for (int ch = 0; ch < NCH; ++ch) {
        __syncthreads();                     // previous consume done
        #pragma unroll
        for (int k = 0; k < KQ; ++k) {
            const int q = tid + k * 256;
            if (q < NQ) {
                const int qs = q & 3;
                const int f = q >> 2;
                const int vx = f % 18;
                const int rest = f / 18;
                const int r = rest % 6;
                const int lp = rest / 6;
                int zc = z0 - 1 + lp; zc = zc < 0 ? 0 : (zc >= DD ? DD - 1 : zc);
                int yc = y0 - 1 + r;  yc = yc < 0 ? 0 : (yc >= HH ? HH - 1 : yc);
                int xc = x0 - 1 + vx; xc = xc < 0 ? 0 : (xc >= WW ? WW - 1 : xc);
                const bf16* gp = src + ((long)zc * HW + (long)yc * WW + xc) * (long)SS + ch * 32 + qs * 8;
                *(uint4*)&lds[lp][r][vx][qs * 8] = *(const uint4*)gp;
            }
        }
        __syncthreads();                     // stage visible to all waves

        #pragma unroll 1
        for (int dyi = 0; dyi < 3; ++dyi) {
            if (!ym[dyi]) continue;          // wave-uniform; no barriers inside
            const int rr = wave + dyi;
            #pragma unroll
            for (int dxi = 0; dxi < 3; ++dxi) {
                union U { uint4 u; s8v v; } b[3][NT];
                #pragma unroll
                for (int dz = 0; dz < 3; ++dz)
                    #pragma unroll
                    for (int nt = 0; nt < NT; ++nt)
                        b[dz][nt].u = *(const uint4*)(bp +
                            (((long)(dz * 9 + dyi * 3 + dxi) * NCH + ch) * COUT) * 32 + nt * 512);
                const u32 sx = (dxi == 0) ? selLo : (dxi == 2 ? selHi : 0xFFFFFFFFu);
                #pragma unroll
                for (int p = 0; p < PL; ++p) {
                    union U2 { uint4 u; s8v v; } a;
                    a.u = *(const uint4*)&lds[p][rr][nlo + dxi][quad * 8];
                    const u32 mm = zm[p] & sx;
                    a.u.x &= mm; a.u.y &= mm; a.u.z &= mm; a.u.w &= mm;
                    #pragma unroll
                    for (int dz = 0; dz < 3; ++dz) {
                        const int m = p - dz;
                        if (m < 0 || m >= M) continue;   // compile-time prune
                        #pragma unroll
                        for (int nt = 0; nt < NT; ++nt)
                            acc[m][nt] = __builtin_amdgcn_mfma_f32_16x16x32_bf16(a.v, b[dz][nt].v, acc[m][nt], 0, 0, 0);
                    }
                }
            }
        }
    }

    const int yw = y0 + wave;
    #pragma unroll
    for (int m = 0; m < M; ++m) {
        const long vbase = (long)(z0 + m) * HW + (long)yw * WW + x0 + quad * 4;
        #pragma unroll
        for (int nt = 0; nt < NT; ++nt) {
            #pragma unroll
            for (int reg = 0; reg < 4; ++reg) {
                float v = acc[m][nt][reg];
                v = v >= 0.f ? v : v * slope;
                dst[(vbase + reg) * (long)dstride + dcol0 + nt * 16 + nlo] = f2bf(v);
            }
        }
    }
}

// ------- tiled small conv: Cin=16 -> Cout=3, linear, f32 out ---------------
// LDS-staged z-column tiles: block = 16x16 xy-tile x ZS z-outputs. Stages the
// ZS+2 input planes (18x18 halo fragments x 32B) ONCE into LDS, then computes
// taps-outer / z-inner with the tap's 48 weights in registers (uniform scalar
// loads). FP accumulation order matches the original (tap asc, ci asc).
template<int ZS>
__global__ __launch_bounds__(256, 2) void k_conv_small_t(
        const bf16* __restrict__ src, int sstride, int scol0,
        const float* __restrict__ wt, const void* __restrict__ bias,
        float* __restrict__ dst, int D, int H, int W,
        const int* __restrict__ bmodep) {
    const int bmode = *bmodep;
    __shared__ bf16 lds[ZS + 2][18][18][16];   // ZS=4: 62208 B
    const int tid = threadIdx.x;
    const int gx = W >> 4;                      // W % 16 == 0
    const int gy = (H + 15) >> 4;
    const int xyt = (int)(blockIdx.x % (u32)(gx * gy));
    const int zg  = (int)(blockIdx.x / (u32)(gx * gy));
    const int x0 = (xyt % gx) << 4;
    const int y0 = (xyt / gx) << 4;
    const int z0 = zg * ZS;

    // ---- stage (ZS+2) planes of 18x18 fragments (zeros outside volume) ----
    const int NFRAG = (ZS + 2) * 324;
    for (int f = tid; f < NFRAG; f += 256) {
        int pl = f / 324, r = f - pl * 324;
        int yy = r / 18, xx = r - yy * 18;
        int z2 = z0 - 1 + pl, y2 = y0 - 1 + yy, x2 = x0 - 1 + xx;
        uint4 lo = {0, 0, 0, 0}, hi = {0, 0, 0, 0};
        if ((unsigned)z2 < (unsigned)D && (unsigned)y2 < (unsigned)H && (unsigned)x2 < (unsigned)W) {
            const bf16* p = src + ((long)(z2 * H + y2) * W + x2) * (long)sstride + scol0;
            lo = *(const uint4*)p;
            hi = *(const uint4*)(p + 8);
        }
        *(uint4*)&lds[pl][yy][xx][0] = lo;
        *(uint4*)&lds[pl][yy][xx][8] = hi;
    }
    __syncthreads();

    const int ty = tid >> 4, tx = tid & 15;
    const bool live = (y0 + ty) < H;

    float a0[ZS], a1[ZS], a2[ZS];
    {
        float b0 = gld(bias, 0, bmode), b1 = gld(bias, 1, bmode), b2 = gld(bias, 2, bmode);
        #pragma unroll
        for (int zz = 0; zz < ZS; ++zz) { a0[zz] = b0; a1[zz] = b1; a2[zz] = b2; }
    }

    #pragma unroll 1
    for (int tap = 0; tap < 27; ++tap) {
        const int dz = tap / 9, dy = (tap / 3) % 3, dx = tap % 3;
        const float* w = wt + tap * 48;          // uniform -> scalar loads
        float wv[48];
        #pragma unroll
        for (int k = 0; k < 48; ++k) wv[k] = w[k];
        #pragma unroll
        for (int zz = 0; zz < ZS; ++zz) {
            union { uint4 u[2]; bf16 h[16]; } fr;
            fr.u[0] = *(const uint4*)&lds[zz + dz][ty + dy][tx + dx][0];
            fr.u[1] = *(const uint4*)&lds[zz + dz][ty + dy][tx + dx][8];
            #pragma unroll
            for (int c = 0; c < 16; ++c) {
                float f = bf2f(fr.h[c]);
                a0[zz] += f * wv[c * 3];
                a1[zz] += f * wv[c * 3 + 1];
                a2[zz] += f * wv[c * 3 + 2];
            }
        }
    }

    if (!live) return;
    #pragma unroll
    for (int zz = 0; zz < ZS; ++zz) {
        long p = ((long)(z0 + zz) * H + (y0 + ty)) * W + (x0 + tx);
        dst[p * 3]     = sf(a0[zz]);
        dst[p * 3 + 1] = sf(a1[zz]);
        dst[p * 3 + 2] = sf(a2[zz]);
    }
}

// ------- x2 upsample taps ---------------------------------------------------
__device__ __forceinline__ void up_taps(int i, int n, int& j0, int& j1, float& w0, float& w1) {
    if (i & 1) { j0 = i >> 1; j1 = j0 + 1; w0 = 0.75f; w1 = 0.25f; if (j1 >= n) { j1 = j0; w0 = 1.f; w1 = 0.f; } }
    else { j1 = i >> 1; j0 = j1 - 1; w0 = 0.25f; w1 = 0.75f; if (j0 < 0) { j0 = j1; w0 = 0.f; w1 = 1.f; } }
}

// ctx16 [NHALF][16] -> xin2 cols 59..74
__global__ void k_up_ctx(const bf16* __restrict__ in, bf16* __restrict__ xin2) {
    long p = (long)blockIdx.x * 256 + threadIdx.x;
    if (p >= NFULL) return;
    int x = (int)(p % W2c), y = (int)((p / W2c) % H2c), z = (int)(p / (W2c * H2c));
    int jz0, jz1, jy0, jy1, jx0, jx1; float wz0, wz1, wy0, wy1, wx0, wx1;
    up_taps(z, D1c, jz0, jz1, wz0, wz1);
    up_taps(y, H1c, jy0, jy1, wy0, wy1);
    up_taps(x, W1c, jx0, jx1, wx0, wx1);
    float acc[16];
    for (int c = 0; c < 16; ++c) acc[c] = 0.f;
    int jzs[2] = { jz0, jz1 }; float wzs[2] = { wz0, wz1 };
    int jys[2] = { jy0, jy1 }; float wys[2] = { wy0, wy1 };
    int jxs[2] = { jx0, jx1 }; float wxs[2] = { wx0, wx1 };
    for (int a = 0; a < 2; ++a) {
        if (wzs[a] == 0.f) continue;
        for (int b = 0; b < 2; ++b) {
            if (wys[b] == 0.f) continue;
            float wzy = wzs[a] * wys[b];
            for (int d = 0; d < 2; ++d) {
                if (wxs[d] == 0.f) continue;
                float w = wzy * wxs[d];
                long rb = ((long)(jzs[a] * H1c + jys[b]) * W1c + jxs[d]) * 16;
                for (int c = 0; c < 16; ++c) acc[c] += w * bf2f(in[cl(rb + c, NCTX16)]);
            }
        }
    }
    for (int c = 0; c < 16; ++c) xin2[cl(p * (long)S2 + 59 + c, NX2)] = f2bf(acc[c]);
}

// fused: velup = 2*up(vel1); du2 = warp(disp_up, velup) + velup; xin2 75..77
__global__ void k_warp_dispup(const void* __restrict__ dispup, const float* __restrict__ vel1,
                              float* __restrict__ du2, bf16* __restrict__ xin2,
                              const int* __restrict__ modep) {
    int mode = *modep;
    long p = (long)blockIdx.x * 256 + threadIdx.x;
    if (p >= NFULL) return;
    int x = (int)(p % W2c), y = (int)((p / W2c) % H2c), z = (int)(p / (W2c * H2c));
    int jz0, jz1, jy0, jy1, jx0, jx1; float wz0, wz1, wy0, wy1, wx0, wx1;
    up_taps(z, D1c, jz0, jz1, wz0, wz1);
    up_taps(y, H1c, jy0, jy1, wy0, wy1);
    up_taps(x, W1c, jx0, jx1, wx0, wx1);
    int jzs[2] = { jz0, jz1 }; float wzs[2] = { wz0, wz1 };
    int jys[2] = { jy0, jy1 }; float wys[2] = { wy0, wy1 };
    int jxs[2] = { jx0, jx1 }; float wxs[2] = { wx0, wx1 };
    float vu[3] = { 0.f, 0.f, 0.f };
    for (int a = 0; a < 2; ++a) {
        if (wzs[a] == 0.f) continue;
        for (int b = 0; b < 2; ++b) {
            if (wys[b] == 0.f) continue;
            float wzy = wzs[a] * wys[b];
            for (int d = 0; d < 2; ++d) {
                if (wxs[d] == 0.f) continue;
                float w = wzy * wxs[d];
                long rb = ((long)(jzs[a] * H1c + jys[b]) * W1c + jxs[d]) * 3;
                for (int c = 0; c < 3; ++c) vu[c] += w * sf(vel1[cl(rb + c, N3H)]);
            }
        }
    }
    for (int c = 0; c < 3; ++c) vu[c] = sf(vu[c] * 2.f);
    float cz = z + vu[0], cy = y + vu[1], cx = x + vu[2];
    float acc[3] = { 0.f, 0.f, 0.f };
    float z0f = floorf(cz), y0f = floorf(cy), x0f = floorf(cx);
    int z0 = (int)z0f, y0 = (int)y0f, x0 = (int)x0f;
    float fz = cz - z0f, fy = cy - y0f, fx = cx - x0f;
    for (int dz = 0; dz < 2; ++dz) {
        int zi = z0 + dz; if (zi < 0 || zi >= D2c) continue;
        float wz = dz ? fz : 1.f - fz;
        for (int dy = 0; dy < 2; ++dy) {
            int yi = y0 + dy; if (yi < 0 || yi >= H2c) continue;
            float wzy = wz * (dy ? fy : 1.f - fy);
            for (int dx = 0; dx < 2; ++dx) {
                int xi = x0 + dx; if (xi < 0 || xi >= W2c) continue;
                float w = wzy * (dx ? fx : 1.f - fx);
                long idx = (long)(zi * H2c + yi) * W2c + xi;
                for (int c = 0; c < 3; ++c) acc[c] += w * gld(dispup, cl((long)c * NFULL + idx, 3 * NFULL), mode);
            }
        }
    }
    for (int c = 0; c < 3; ++c) {
        float v = sf(acc[c] + vu[c]);
        du2[cl(p * 3 + c, N3F)] = v;
        xin2[cl(p * (long)S2 + 75 + c, NX2)] = f2bf(v);
    }
}

// robust t decode (handles bf16-stored or f32-stored scalar)
__device__ __forceinline__ float decode_t(const u16* tp) {
    u16 b0 = tp[0], b1 = tp[1];
    union { u32 i; float f; } a, b;
    a.i = ((u32)b0) << 16;
    b.i = ((u32)b1 << 16) | b0;
    float ta = a.f, tb = b.f;
    bool okA = (ta == ta) && ta >= 0.f && ta < 0.75f;
    bool okB = (tb == tb) && tb >= 0.f && tb < 0.75f;
    return okB ? tb : (okA ? ta : 0.f);
}

// vf = (warp(du2, vu2) + vu2 - disp_up) / (1 - t); out mode-dispatched
__global__ void k_final(const float* __restrict__ du2, const float* __restrict__ vu2,
                        const void* __restrict__ dispup, const u16* __restrict__ tptr,
                        void* __restrict__ out, long out_n, const int* __restrict__ modep) {
    int mode = *modep;
    long p = (long)blockIdx.x * 256 + threadIdx.x;
    if (p >= NFULL) return;
    float t = decode_t(tptr);
    float den = 1.f - t;
    if (fabsf(den) < 1e-6f) den = 1e-6f;
    float inv = 1.f / den;
    int x = (int)(p % W2c), y = (int)((p / W2c) % H2c), z = (int)(p / (W2c * H2c));
    float cz = z + sf(vu2[cl(p * 3, N3F)]);
    float cy = y + sf(vu2[cl(p * 3 + 1, N3F)]);
    float cx = x + sf(vu2[cl(p * 3 + 2, N3F)]);
    float acc[3] = { 0.f, 0.f, 0.f };
    float z0f = floorf(cz), y0f = floorf(cy), x0f = floorf(cx);
    int z0 = (int)z0f, y0 = (int)y0f, x0 = (int)x0f;
    float fz = cz - z0f, fy = cy - y0f, fx = cx - x0f;
    for (int dz = 0; dz < 2; ++dz) {
        int zi = z0 + dz; if (zi < 0 || zi >= D2c) continue;
        float wz = dz ? fz : 1.f - fz;
        for (int dy = 0; dy < 2; ++dy) {
            int yi = y0 + dy; if (yi < 0 || yi >= H2c) continue;
            float wzy = wz * (dy ? fy : 1.f - fy);
            for (int dx = 0; dx < 2; ++dx) {
                int xi = x0 + dx; if (xi < 0 || xi >= W2c) continue;
                float w = wzy * (dx ? fx : 1.f - fx);
                long rb = ((long)(zi * H2c + yi) * W2c + xi) * 3;
                for (int c = 0; c < 3; ++c) acc[c] += w * sf(du2[cl(rb + c, N3F)]);
            }
        }
    }
    for (int c = 0; c < 3; ++c) {
        float v = (acc[c] + sf(vu2[cl(p * 3 + c, N3F)]) - gld(dispup, cl((long)c * NFULL + p, 3 * NFULL), mode)) * inv;
        long oi = cl((long)c * NFULL + p, out_n);
        if (mode) ((float*)out)[oi] = sf(v);
        else      ((bf16*)out)[oi] = f2bf(v);
    }
}

static inline int cdiv(long a, long b) { return (int)((a + b - 1) / b); }

extern "C" void kernel_launch(void* const* d_in, const int* in_sizes, int n_in,
                              void* d_out, int out_size, void* d_ws, size_t ws_size,
                              hipStream_t stream) {
    const u16* t_in = (const u16*)d_in[0];
    const void* disp_up = d_in[1];
    const void* fx  = d_in[2];
    const void* fy  = d_in[3];
    const void* fxu = d_in[4];
    const void* fyu = d_in[5];
    const void* ctx = d_in[6];

    const size_t XIN1_B = (size_t)NX1 * 2;
    const size_t XIN2_B = (size_t)NX2 * 2;
    // guards before/after the xin region so any residual halo addressing
    // stays inside the allocation
    const size_t base_need = XIN1_B + XIN2_B + 2 * (size_t)GUARD;
    const size_t base_pad = (base_need + 255) & ~(size_t)255;
    const size_t vf_elems = 3UL * NFULL;

    // wtb sizes (bf16 elements): 27 * nchunk * Cout * 32
    const long WTB0 = 387072;  // 224->64, 7ch
    const long WTB1 = 373248;  // 288->48, 9ch
    const long WTB2 = 304128;  // 336->32, 11ch
    const long WTB3 = 165888;  // 368->16, 12ch
    const long WTB5 = 82944;   // 78->32, 3ch
    const long WTB6 = 55296;   // 110->16, 4ch
    const long WTB_TOT = WTB0 + WTB1 + WTB2 + WTB3 + WTB5 + WTB6; // 1,368,576

    size_t scro[11];
    {
        size_t o = 0;
        auto al = [&](size_t bytes) { size_t r = o; o = (o + bytes + 255) & ~(size_t)255; return r; };
        scro[0] = al((size_t)WTB_TOT * 2);      // WTB (bf16, mfma layout)
        scro[1] = al(2UL * 1296 * 4);           // WT f32 (two small convs)
        scro[2] = al((size_t)NCTX16 * 2);       // CTX16
        scro[3] = al((size_t)N3H * 4);          // VEL1
        scro[4] = al((size_t)N3H * 4);          // DISPH
        scro[5] = al((size_t)N3F * 4);          // DU2
        scro[6] = al((size_t)N3F * 4);          // VU2
        scro[7] = al(4UL * RG * 2 * 8);         // partials
        scro[8] = al(16 * 8);                   // RED
        scro[9] = al(32 * 4);                   // MODES
        scro[10] = o;
    }
    const size_t scratch_need = scro[10];
    const size_t tail_avail = ((size_t)out_size > vf_elems) ? ((size_t)out_size - vf_elems) * 2 : 0;

    char* scr = nullptr;
    if (ws_size >= base_pad + scratch_need) {
        scr = (char*)d_ws + base_pad;
    } else if (ws_size >= base_need && tail_avail >= scratch_need) {
        scr = (char*)d_out + vf_elems * 2;
    }
    if (scr == nullptr) {
        k_fill<<<2048, 256, 0, stream>>>((u16*)d_out, (long)out_size, 0x49A0);
        return;
    }

    char* ws = (char*)d_ws;
    bf16*  xin1  = (bf16*)(ws + GUARD);
    bf16*  xin2  = (bf16*)(ws + GUARD + XIN1_B);
    bf16*  wtball = (bf16*)(scr + scro[0]);
    float* wtf   = (float*)(scr + scro[1]);
    bf16*  ctx16 = (bf16*)(scr + scro[2]);
    float* vel1  = (float*)(scr + scro[3]);
    float* disph = (float*)(scr + scro[4]);
    float* du2   = (float*)(scr + scro[5]);
    float* vu2   = (float*)(scr + scro[6]);
    double* part = (double*)(scr + scro[7]);
    double* red  = (double*)(scr + scro[8]);
    int*   modes = (int*)(scr + scro[9]);
    double* pA = part;
    double* pB = part + RG * 2;
    double* pC = part + RG * 4;
    double* pD = part + RG * 6;

    bf16* wtb0 = wtball;
    bf16* wtb1 = wtb0 + WTB0;
    bf16* wtb2 = wtb1 + WTB1;
    bf16* wtb3 = wtb2 + WTB2;
    bf16* wtb5 = wtb3 + WTB3;
    bf16* wtb6 = wtb5 + WTB5;
    float* wt4 = wtf;
    float* wt7 = wtf + 1296;

    // zero-init big buffers (incl. guards) and scratch (modes default 0 = bf16)
    k_fill<<<4096, 256, 0, stream>>>((u16*)ws, (long)(base_need / 2), 0);
    k_fill<<<4096, 256, 0, stream>>>((u16*)scr, (long)(scratch_need / 2), 0);

    // dtype detection for all tensor inputs
    for (int i = 1; i < 23 && i < n_in; ++i) {
        k_detect<<<1, 256, 0, stream>>>(d_in[i], (long)in_sizes[i], modes + i);
    }

    // MFMA weight repack (bf16, zero-padded K tails)
    k_wtb<<<cdiv(WTB0, 256), 256, 0, stream>>>(d_in[7],  wtb0, 224, 64, 7,  modes + 7);
    k_wtb<<<cdiv(WTB1, 256), 256, 0, stream>>>(d_in[9],  wtb1, 288, 48, 9,  modes + 9);
    k_wtb<<<cdiv(WTB2, 256), 256, 0, stream>>>(d_in[11], wtb2, 336, 32, 11, modes + 11);
    k_wtb<<<cdiv(WTB3, 256), 256, 0, stream>>>(d_in[13], wtb3, 368, 16, 12, modes + 13);
    k_wtb<<<cdiv(WTB5, 256), 256, 0, stream>>>(d_in[17], wtb5, 78,  32, 3,  modes + 17);
    k_wtb<<<cdiv(WTB6, 256), 256, 0, stream>>>(d_in[19], wtb6, 110, 16, 4,  modes + 19);
    // f32 weights for the two small convs
    k_wt<<<cdiv(1296, 256), 256, 0, stream>>>(d_in[15], wt4, 16, 3, modes + 15);
    k_wt<<<cdiv(1296, 256), 256, 0, stream>>>(d_in[21], wt7, 16, 3, modes + 21);

    k_tcl<<<cdiv(NHALF, 256), 256, 0, stream>>>(fy,  32L * NHALF, xin1, NX1, 125, 32, NHALF, S1, modes + 3);
    k_tcl<<<cdiv(NHALF, 256), 256, 0, stream>>>(ctx, 32L * NHALF, xin1, NX1, 189, 32, NHALF, S1, modes + 6);
    k_tcl<<<cdiv(NFULL, 256), 256, 0, stream>>>(fyu, 16L * NFULL, xin2, NX2, 27, 16, NFULL, S2, modes + 5);

    k_down<<<cdiv(NHALF, 256), 256, 0, stream>>>(disp_up, disph, xin1, modes + 1);

    k_warp_cf<32><<<cdiv(NHALF, 256), 256, 0, stream>>>(fx, 32L * NHALF, disph, N3H, xin1, NX1, S1, 157, D1c, H1c, W1c, modes + 2);
    k_reduce_cl<<<RG, 256, 0, stream>>>(xin1, NX1, NHALF, S1, 157, 32, pA, modes + 31);
    k_reduce_cl<<<RG, 256, 0, stream>>>(fy, 32L * NHALF, 32L * NHALF, 1, 0, 1, pB, modes + 3);
    k_stats2<<<1, 256, 0, stream>>>(pA, pB, (double)(32L * NHALF), 32.0, red);

    k_cv1<<<(int)NHALF, 128, 0, stream>>>(xin1, red);

    // fl1 dense block — LDS-staged MFMA conv (4 rows x M=2 z-planes / block)
    // grid = (48/16 x 40/4 = 30 xy-blocks) x (48/2 = 24 zgroups) = 720 (%8==0)
    k_conv_mfma<4, 7, 64, 2, S1, D1c, H1c, W1c><<<720, 256, 0, stream>>>(xin1, wtb0, d_in[8],  xin1, S1, 224, 0.02f, modes + 8);
    k_conv_mfma<3, 9, 48, 2, S1, D1c, H1c, W1c><<<720, 256, 0, stream>>>(xin1, wtb1, d_in[10], xin1, S1, 288, 0.02f, modes + 10);
    k_conv_mfma<2, 11, 32, 2, S1, D1c, H1c, W1c><<<720, 256, 0, stream>>>(xin1, wtb2, d_in[12], xin1, S1, 336, 0.02f, modes + 12);
    k_conv_mfma<1, 12, 16, 2, S1, D1c, H1c, W1c><<<720, 256, 0, stream>>>(xin1, wtb3, d_in[14], ctx16, 16, 0, 0.02f, modes + 14);
    // tiled small conv (NHALF): grid = 3x3 xy-tiles x 12 zgroups = 108
    k_conv_small_t<4><<<108, 256, 0, stream>>>(ctx16, 16, 0, wt4, d_in[16], vel1, D1c, H1c, W1c, modes + 16);

    k_up_ctx<<<cdiv(NFULL, 256), 256, 0, stream>>>(ctx16, xin2);
    k_warp_dispup<<<cdiv(NFULL, 256), 256, 0, stream>>>(disp_up, vel1, du2, xin2, modes + 1);

    k_warp_cf<16><<<cdiv(NFULL, 256), 256, 0, stream>>>(fxu, 16L * NFULL, du2, N3F, xin2, NX2, S2, 43, D2c, H2c, W2c, modes + 4);
    k_reduce_cl<<<RG, 256, 0, stream>>>(xin2, NX2, NFULL, S2, 43, 16, pC, modes + 31);
    k_reduce_cl<<<RG, 256, 0, stream>>>(fyu, 16L * NFULL, 16L * NFULL, 1, 0, 1, pD, modes + 5);
    k_stats2<<<1, 256, 0, stream>>>(pC, pD, (double)(16L * NFULL), 16.0, red + 2);

    k_cv2<<<cdiv(NFULL, 8), 256, 0, stream>>>(xin2, red);

    // fl2 block — LDS-staged MFMA conv (4 rows x M=4 z-planes / block)
    // grid = (96/16 x 80/4 = 120 xy-blocks) x (96/4 = 24 zgroups) = 2880 (%8==0)
    k_conv_mfma<2, 3, 32, 4, S2, D2c, H2c, W2c><<<2880, 256, 0, stream>>>(xin2, wtb5, d_in[18], xin2, S2, 78,  0.02f, modes + 18);
    k_conv_mfma<1, 4, 16, 4, S2, D2c, H2c, W2c><<<2880, 256, 0, stream>>>(xin2, wtb6, d_in[20], xin2, S2, 110, 0.02f, modes + 20);
    // tiled small conv (NFULL): grid = 6x5 xy-tiles x 24 zgroups = 720
    k_conv_small_t<4><<<720, 256, 0, stream>>>(xin2, S2, 110, wt7, d_in[22], vu2, D2c, H2c, W2c, modes + 22);

    // out dtype follows disp_up's detected mode
    k_final<<<cdiv(NFULL, 256), 256, 0, stream>>>(du2, vu2, disp_up, t_in, d_out, (long)out_size, modes + 1);
    k_fill_tail<<<2048, 256, 0, stream>>>(d_out, (long)vf_elems, (long)out_size, modes + 1);
}

// Round 8
// 2570.842 us; speedup vs baseline: 1.4024x; 1.1415x over previous
//
#include <hip/hip_runtime.h>
#include <hip/hip_bf16.h>

typedef __hip_bfloat16 bf16;
typedef unsigned short u16;
typedef unsigned int u32;

#define D1c 48
#define H1c 40
#define W1c 48
#define NHALF 92160L
#define D2c 96
#define H2c 80
#define W2c 96
#define NFULL 737280L
#define S1 368
#define S2 128
#define RG 512

#define NX1 (NHALF * S1)
#define NX2 (NFULL * S2)
#define NCTX16 (NHALF * 16)
#define N3H (NHALF * 3)
#define N3F (NFULL * 3)
#define GUARD 1024

typedef __attribute__((ext_vector_type(8))) short s8v;
typedef __attribute__((ext_vector_type(4))) float f4v;

__device__ __forceinline__ float bf2f(bf16 v){ return __bfloat162float(v); }
__device__ __forceinline__ float sf(float v){ return (v == v && fabsf(v) < 1e30f) ? v : 0.f; }
__device__ __forceinline__ bf16 f2bf(float v){ return __float2bfloat16(sf(v)); }
__device__ __forceinline__ u16 f2bfu(float v){ bf16 b = f2bf(v); return *(u16*)&b; }
__device__ __forceinline__ long cl(long i, long n){ i = i < 0 ? 0 : i; return i >= n ? n - 1 : i; }
// mode-dispatched input load: 0 = bf16, 1 = f32
__device__ __forceinline__ float gld(const void* p, long i, int mode){
    return mode ? sf(((const float*)p)[i]) : sf(bf2f(((const bf16*)p)[i]));
}

// ---------------- dtype detection: one block per input ---------------------
__global__ void k_detect(const void* p, long nelem, int* flag) {
    long N = nelem < 4096 ? nelem : 4096;
    int tid = threadIdx.x;
    int nb = 0, nf = 0;
    for (long i = tid; i < N; i += 256) {
        float v = bf2f(((const bf16*)p)[i]);
        if (v == v && fabsf(v) <= 1e4f) nb++;
    }
    long M = N / 2;
    for (long i = tid; i < M; i += 256) {
        float v = ((const float*)p)[i];
        if (v == v && fabsf(v) <= 1e4f) nf += 2;
    }
    __shared__ int sb[256], sq[256];
    sb[tid] = nb; sq[tid] = nf;
    __syncthreads();
    for (int t = 128; t; t >>= 1) {
        if (tid < t) { sb[tid] += sb[tid + t]; sq[tid] += sq[tid + t]; }
        __syncthreads();
    }
    if (tid == 0) *flag = (sb[0] >= sq[0]) ? 0 : 1;
}

// ---------------- fills -----------------------------------------------------
__global__ void k_fill(u16* __restrict__ p, long n, u16 val) {
    long i = (long)blockIdx.x * 256 + threadIdx.x;
    long stride = (long)gridDim.x * 256;
    for (; i < n; i += stride) p[i] = val;
}
__global__ void k_fill_tail(void* out, long vf, long out_n, const int* __restrict__ modep) {
    int mode = *modep;
    long n = out_n - vf;
    if (n <= 0) return;
    long i = (long)blockIdx.x * 256 + threadIdx.x;
    long stride = (long)gridDim.x * 256;
    if (mode) { float* p = (float*)out + vf; for (; i < n; i += stride) p[i] = 0.f; }
    else      { u16*   p = (u16*)out + vf;   for (; i < n; i += stride) p[i] = 0; }
}

// ------- weight transpose: (co,ci,tap) -> (tap,ci,co) f32 (small convs) ----
__global__ void k_wt(const void* __restrict__ w, float* __restrict__ wt,
                     int Cin, int Cout, const int* __restrict__ modep) {
    int mode = *modep;
    long n = (long)Cin * Cout * 27;
    long i = (long)blockIdx.x * 256 + threadIdx.x;
    if (i >= n) return;
    int tap = (int)(i % 27); long r = i / 27;
    int ci = (int)(r % Cin); int co = (int)(r / Cin);
    wt[cl(((long)tap * Cin + ci) * Cout + co, n)] = gld(w, cl(i, n), mode);
}

// ------- MFMA weight repack: (co,ci,tap) -> [tap][chunk][co][32] bf16 ------
// zero-padded for ci >= Cin (Cin tails)
__global__ void k_wtb(const void* __restrict__ w, bf16* __restrict__ wtb,
                      int Cin, int Cout, int nchunk, const int* __restrict__ modep) {
    int mode = *modep;
    long n = 27L * nchunk * Cout * 32;
    long i = (long)blockIdx.x * 256 + threadIdx.x;
    if (i >= n) return;
    int kk = (int)(i & 31);
    long r = i >> 5;
    int co = (int)(r % Cout); r /= Cout;
    int ch = (int)(r % nchunk); int tap = (int)(r / nchunk);
    int ci = ch * 32 + kk;
    float v = (ci < Cin) ? gld(w, ((long)co * Cin + ci) * 27 + tap, mode) : 0.f;
    wtb[i] = f2bf(v);
}

// ------- channel-first [C][N] -> channel-last columns ----------------------
__global__ void k_tcl(const void* __restrict__ in, long nin,
                      bf16* __restrict__ out, long nout, int col0,
                      int C, long N, int stride, const int* __restrict__ modep) {
    int mode = *modep;
    long n = (long)blockIdx.x * 256 + threadIdx.x;
    if (n >= N) return;
    for (int c = 0; c < C; ++c)
        out[cl(n * stride + col0 + c, nout)] = f2bf(gld(in, cl((long)c * N + n, nin), mode));
}

// ------- antialiased x0.5 downsample taps ----------------------------------
__device__ __forceinline__ void down_taps(int i, int n_in, int j[4], float w[4]) {
    float s = 0.f;
    for (int k = 0; k < 4; ++k) {
        int jj = 2 * i - 1 + k;
        bool valid = (jj >= 0 && jj < n_in);
        j[k] = valid ? jj : 0;
        float b = (k == 0 || k == 3) ? 1.f : 3.f;
        w[k] = valid ? b : 0.f;
        s += w[k];
    }
    float inv = 1.f / fmaxf(s, 1e-6f);
    for (int k = 0; k < 4; ++k) w[k] *= inv;
}

// disp = resize(disp_up,0.5)*0.5 -> disph f32 + xin1 cols 221..223
__global__ void k_down(const void* __restrict__ dispup, float* __restrict__ disph,
                       bf16* __restrict__ xin1, const int* __restrict__ modep) {
    int mode = *modep;
    long p = (long)blockIdx.x * 256 + threadIdx.x;
    if (p >= NHALF) return;
    int x = (int)(p % W1c), y = (int)((p / W1c) % H1c), z = (int)(p / (W1c * H1c));
    int jz[4], jy[4], jx[4]; float wz[4], wy[4], wx[4];
    down_taps(z, D2c, jz, wz); down_taps(y, H2c, jy, wy); down_taps(x, W2c, jx, wx);
    for (int c = 0; c < 3; ++c) {
        float acc = 0.f;
        for (int a = 0; a < 4; ++a) {
            if (wz[a] == 0.f) continue;
            for (int b = 0; b < 4; ++b) {
                if (wy[b] == 0.f) continue;
                float wzy = wz[a] * wy[b];
                long base = (long)c * NFULL + ((long)jz[a] * H2c + jy[b]) * W2c;
                for (int d = 0; d < 4; ++d) {
                    if (wx[d] == 0.f) continue;
                    acc += wzy * wx[d] * gld(dispup, cl(base + jx[d], 3 * NFULL), mode);
                }
            }
        }
        acc = sf(acc * 0.5f);
        disph[cl(p * 3 + c, N3H)] = acc;
        xin1[cl(p * (long)S1 + 221 + c, NX1)] = f2bf(acc);
    }
}

// ------- trilinear warp, channel-first INPUT volume, zero pad --------------
template<int C>
__global__ void k_warp_cf(const void* __restrict__ vol, long nvol,
                          const float* __restrict__ coords, long ncoords,
                          bf16* __restrict__ dst, long ndst, int dstride, int col0,
                          int D, int H, int W, const int* __restrict__ modep) {
    int mode = *modep;
    const long N = (long)D * H * W;
    long p = (long)blockIdx.x * 256 + threadIdx.x;
    if (p >= N) return;
    int x = (int)(p % W), y = (int)((p / W) % H), z = (int)(p / ((long)W * H));
    float cz = z + sf(coords[cl(p * 3, ncoords)]);
    float cy = y + sf(coords[cl(p * 3 + 1, ncoords)]);
    float cx = x + sf(coords[cl(p * 3 + 2, ncoords)]);
    float acc[C];
    for (int c = 0; c < C; ++c) acc[c] = 0.f;
    float z0f = floorf(cz), y0f = floorf(cy), x0f = floorf(cx);
    int z0 = (int)z0f, y0 = (int)y0f, x0 = (int)x0f;
    float fz = cz - z0f, fy = cy - y0f, fx = cx - x0f;
    for (int dz = 0; dz < 2; ++dz) {
        int zi = z0 + dz; if (zi < 0 || zi >= D) continue;
        float wz = dz ? fz : 1.f - fz;
        for (int dy = 0; dy < 2; ++dy) {
            int yi = y0 + dy; if (yi < 0 || yi >= H) continue;
            float wzy = wz * (dy ? fy : 1.f - fy);
            for (int dx = 0; dx < 2; ++dx) {
                int xi = x0 + dx; if (xi < 0 || xi >= W) continue;
                float w = wzy * (dx ? fx : 1.f - fx);
                long idx = (long)(zi * H + yi) * W + xi;
                for (int c = 0; c < C; ++c) acc[c] += w * gld(vol, cl((long)c * N + idx, nvol), mode);
            }
        }
    }
    for (int c = 0; c < C; ++c) dst[cl(p * (long)dstride + col0 + c, ndst)] = f2bf(acc[c]);
}

// ------- two-stage deterministic reduction (sum, sumsq) --------------------
__global__ void k_reduce_cl(const void* __restrict__ base, long nbase, long rows,
                            int stride, int col0, int cn, double* __restrict__ part,
                            const int* __restrict__ modep) {
    int mode = *modep;
    long total = rows * cn;
    double s = 0.0, q = 0.0;
    long i = (long)blockIdx.x * 256 + threadIdx.x;
    long gs = (long)gridDim.x * 256;
    for (; i < total; i += gs) {
        long r = i / cn; int c = (int)(i - r * cn);
        float f = gld(base, cl(r * (long)stride + col0 + c, nbase), mode);
        s += f; q += (double)f * f;
    }
    __shared__ double ls[256], lq[256];
    ls[threadIdx.x] = s; lq[threadIdx.x] = q;
    __syncthreads();
    for (int t = 128; t; t >>= 1) {
        if (threadIdx.x < t) { ls[threadIdx.x] += ls[threadIdx.x + t]; lq[threadIdx.x] += lq[threadIdx.x + t]; }
        __syncthreads();
    }
    if (threadIdx.x == 0) { part[cl(blockIdx.x * 2, RG * 2)] = ls[0]; part[cl(blockIdx.x * 2 + 1, RG * 2)] = lq[0]; }
}

__global__ void k_stats2(const double* __restrict__ pa, const double* __restrict__ pb,
                         double n, double C, double* __restrict__ outm) {
    __shared__ double ls[256], lq[256];
    double s = 0.0, q = 0.0;
    for (int i = threadIdx.x; i < RG; i += 256) { s += pa[i * 2]; q += pa[i * 2 + 1]; }
    ls[threadIdx.x] = s; lq[threadIdx.x] = q;
    __syncthreads();
    for (int t = 128; t; t >>= 1) {
        if (threadIdx.x < t) { ls[threadIdx.x] += ls[threadIdx.x + t]; lq[threadIdx.x] += lq[threadIdx.x + t]; }
        __syncthreads();
    }
    double sa = ls[0], qa = lq[0];
    __syncthreads();
    s = 0.0; q = 0.0;
    for (int i = threadIdx.x; i < RG; i += 256) { s += pb[i * 2]; q += pb[i * 2 + 1]; }
    ls[threadIdx.x] = s; lq[threadIdx.x] = q;
    __syncthreads();
    for (int t = 128; t; t >>= 1) {
        if (threadIdx.x < t) { ls[threadIdx.x] += ls[threadIdx.x + t]; lq[threadIdx.x] += lq[threadIdx.x + t]; }
        __syncthreads();
    }
    if (threadIdx.x == 0) {
        double sb = ls[0], qb = lq[0];
        double va = (qa - sa * sa / n) / (n - 1.0);
        double vb = (qb - sb * sb / n) / (n - 1.0);
        va = va > 0.0 ? va : 0.0;
        vb = vb > 0.0 ? vb : 0.0;
        double sd = 0.5 * (sqrt(va) + sqrt(vb));
        sd = sd < 1e-6 ? 1e-6 : (sd > 1e9 ? 1e9 : sd);
        outm[0] = 0.5 * (sa / n + sb / n);
        outm[1] = 1.0 / (sd * sd * C);
    }
}

// ------- cost volume 1 (md=2, C=32), LDS-tiled -> xin1 cols 0..124 ---------
// Round-8: block = 8x4 xy-tile x 4 z (128 voxels, 128 threads). Stage the
// warped-x halo (cols 157..188, 12x8x8 planes, 32ch) into 49KB LDS via
// scalar u16 loads (cols are 2B-aligned only -> no vector load), then each
// thread computes its voxel's 125 offsets from LDS (4x ds_read_b128/offset)
// instead of 125x32 scalar HBM loads. dot = sum(fm*w) - m*S with
// fm = (f-m) precomputed (algebraically == sum(fm*(w-m)), delta ~1e-6).
__global__ __launch_bounds__(128, 2) void k_cv1_t(bf16* __restrict__ xin1,
                                                  const double* __restrict__ red) {
    __shared__ bf16 lds[8][8][12][32];   // [plane z0-2..z0+5][row y0-2..y0+5][x0-2..x0+9][ch]
    const int tid = threadIdx.x;
    const int xyt = (int)(blockIdx.x % 60u);     // 6 x-tiles * 10 y-tiles
    const int zg  = (int)(blockIdx.x / 60u);     // 12 z-groups
    const int x0 = (xyt % 6) * 8;
    const int y0 = (xyt / 6) * 4;
    const int z0 = zg * 4;
    const u16* src16 = (const u16*)xin1;

    for (int f = tid; f < 8 * 8 * 12; f += 128) {
        int xx = f % 12, rest = f / 12;
        int yy = rest % 8, pl = rest / 8;
        int z2 = z0 - 2 + pl, y2 = y0 - 2 + yy, x2 = x0 - 2 + xx;
        u32 pk[16];
        #pragma unroll
        for (int c = 0; c < 16; ++c) pk[c] = 0;
        if ((unsigned)z2 < (unsigned)D1c && (unsigned)y2 < (unsigned)H1c && (unsigned)x2 < (unsigned)W1c) {
            long rb = (((long)z2 * H1c + y2) * W1c + x2) * S1 + 157;
            #pragma unroll
            for (int c = 0; c < 16; ++c)
                pk[c] = (u32)src16[rb + 2 * c] | ((u32)src16[rb + 2 * c + 1] << 16);
        }
        #pragma unroll
        for (int qq = 0; qq < 4; ++qq) {
            uint4 q = { pk[qq * 4], pk[qq * 4 + 1], pk[qq * 4 + 2], pk[qq * 4 + 3] };
            *(uint4*)&lds[pl][yy][xx][qq * 8] = q;
        }
    }
    __syncthreads();

    const float m = sf((float)red[0]), mult = sf((float)red[1]);
    const int tx = tid & 7, ty = (tid >> 3) & 3, tz = tid >> 5;
    const int x = x0 + tx, y = y0 + ty, z = z0 + tz;
    const long p = ((long)z * H1c + y) * W1c + x;

    float fm[32], S = 0.f;
    #pragma unroll
    for (int c = 0; c < 32; ++c) { fm[c] = sf(bf2f(xin1[p * (long)S1 + 125 + c])) - m; S += fm[c]; }

    #pragma unroll 1
    for (int dz = 0; dz < 5; ++dz) {
        const int z2 = z + dz - 2;
        u16 hg[25];
        #pragma unroll
        for (int oo = 0; oo < 25; ++oo) {
            const int dy = oo / 5, dx = oo % 5;
            const int y2 = y + dy - 2, x2 = x + dx - 2;
            float cost = 0.f;
            if ((unsigned)z2 < (unsigned)D1c && (unsigned)y2 < (unsigned)H1c && (unsigned)x2 < (unsigned)W1c) {
                union { uint4 u[4]; bf16 h[32]; } wv;
                #pragma unroll
                for (int qq = 0; qq < 4; ++qq)
                    wv.u[qq] = *(const uint4*)&lds[tz + dz][ty + dy][tx + dx][qq * 8];
                float dot = 0.f;
                #pragma unroll
                for (int c = 0; c < 32; ++c) dot += fm[c] * sf(bf2f(wv.h[c]));
                dot -= m * S;
                cost = dot * mult;
                cost = cost >= 0.f ? cost : 0.05f * cost;
            }
            hg[oo] = f2bfu(cost);
        }
        u16* dstp = (u16*)(xin1 + p * (long)S1) + dz * 25;
        #pragma unroll
        for (int oo = 0; oo < 25; ++oo) dstp[oo] = hg[oo];
    }
}

// ------- cost volume 2 (md=1, C=16), LDS-tiled -> xin2 cols 0..26 ----------
// block = 16x16 xy-tile x 4 z; stage warped halo (cols 43..58, 18x18x6
// planes) into 62KB LDS; 2 ds_read_b128 per offset replaces 16 scalar HBM
// loads (round-7: 637M scalar loads, VALUBusy 34%, 350us). Packed output.
__global__ __launch_bounds__(256, 2) void k_cv2_t(bf16* __restrict__ xin2,
                                                  const double* __restrict__ red) {
    __shared__ bf16 lds[6][18][18][16];
    const int tid = threadIdx.x;
    const int xyt = (int)(blockIdx.x % 30u);     // 6 x-tiles * 5 y-tiles
    const int zg  = (int)(blockIdx.x / 30u);     // 24 z-groups
    const int x0 = (xyt % 6) * 16;
    const int y0 = (xyt / 6) * 16;
    const int z0 = zg * 4;
    const u16* src16 = (const u16*)xin2;

    for (int f = tid; f < 6 * 324; f += 256) {
        int pl = f / 324, r = f - pl * 324;
        int yy = r / 18, xx = r - yy * 18;
        int z2 = z0 - 1 + pl, y2 = y0 - 1 + yy, x2 = x0 - 1 + xx;
        u32 pk[8];
        #pragma unroll
        for (int c = 0; c < 8; ++c) pk[c] = 0;
        if ((unsigned)z2 < (unsigned)D2c && (unsigned)y2 < (unsigned)H2c && (unsigned)x2 < (unsigned)W2c) {
            long rb = (((long)z2 * H2c + y2) * W2c + x2) * S2 + 43;
            #pragma unroll
            for (int c = 0; c < 8; ++c)
                pk[c] = (u32)src16[rb + 2 * c] | ((u32)src16[rb + 2 * c + 1] << 16);
        }
        uint4 q0 = { pk[0], pk[1], pk[2], pk[3] };
        uint4 q1 = { pk[4], pk[5], pk[6], pk[7] };
        *(uint4*)&lds[pl][yy][xx][0] = q0;
        *(uint4*)&lds[pl][yy][xx][8] = q1;
    }
    __syncthreads();

    const float m = sf((float)red[2]), mult = sf((float)red[3]);
    const int tx = tid & 15, ty = tid >> 4;
    const int x = x0 + tx, y = y0 + ty;

    #pragma unroll 1
    for (int zz = 0; zz < 4; ++zz) {
        const int z = z0 + zz;
        const long p = ((long)z * H2c + y) * W2c + x;
        float fm[16], S = 0.f;
        #pragma unroll
        for (int c = 0; c < 16; ++c) {
            fm[c] = sf(bf2f(xin2[p * (long)S2 + 27 + c])) - m;
            S += fm[c];
        }
        union { u16 h[28]; uint4 q[3]; u32 w[14]; } r;
        #pragma unroll
        for (int o = 0; o < 27; ++o) {
            const int dz = o / 9, dy = (o / 3) % 3, dx = o % 3;
            const int z2 = z + dz - 1, y2 = y + dy - 1, x2 = x + dx - 1;
            float cost = 0.f;
            if ((unsigned)z2 < (unsigned)D2c && (unsigned)y2 < (unsigned)H2c && (unsigned)x2 < (unsigned)W2c) {
                union { uint4 u[2]; bf16 h[16]; } wv;
                wv.u[0] = *(const uint4*)&lds[zz + dz][ty + dy][tx + dx][0];
                wv.u[1] = *(const uint4*)&lds[zz + dz][ty + dy][tx + dx][8];
                float dot = 0.f;
                #pragma unroll
                for (int c = 0; c < 16; ++c) dot += fm[c] * sf(bf2f(wv.h[c]));
                dot -= m * S;
                cost = dot * mult;
                cost = cost >= 0.f ? cost : 0.05f * cost;
            }
            r.h[o] = f2bfu(cost);
        }
        r.h[27] = 0;
        u16* dstp = (u16*)(xin2 + p * (long)S2);
        *(uint4*)dstp        = r.q[0];
        *(uint4*)(dstp + 8)  = r.q[1];
        *(uint4*)(dstp + 16) = r.q[2];
        *(u32*)(dstp + 24)   = r.w[12];
        dstp[26] = r.h[26];
    }
}

// ------- MFMA implicit-GEMM 3x3x3 conv, channel-last, LDS-staged -----------
// Round-7: block = 4 waves = 4 consecutive y-rows x one 16-voxel x-segment x
// M z-planes. Per ch-chunk: barrier -> 256 threads stage the block's FULL
// A-halo [M+2 planes][6 rows][18 voxels][32ch] into LDS -> barrier -> waves
// consume via ds_read_b128 with clamped-address + zero-mask semantics.
template<int NT, int NCH, int COUT, int M, int SS, int DD, int HH, int WW>
__global__ __launch_bounds__(256, 2) void k_conv_mfma(
        const bf16* __restrict__ src,
        const bf16* __restrict__ wtb, const void* __restrict__ bias,
        bf16* __restrict__ dst, int dstride, int dcol0,
        float slope, const int* __restrict__ bmodep) {
    const int bmode = *bmodep;
    const int tid = threadIdx.x;
    const int wave = tid >> 6, lane = tid & 63;
    const int quad = lane >> 4, nlo = lane & 15;
    constexpr long HW = (long)HH * WW;
    constexpr int PL = M + 2;            // staged planes
    constexpr int NXB = WW / 16;
    constexpr int NYB = HH / 4;          // 4 rows per block (one per wave)
    constexpr int NXY = NXB * NYB;
    __shared__ bf16 lds[PL][6][18][32];  // M=4: 41472 B, M=2: 27648 B

    // bijective chunked swizzle (gridDim.x % 8 == 0 by construction)
    const u32 per = gridDim.x >> 3;
    const u32 bid = (blockIdx.x & 7u) * per + (blockIdx.x >> 3);
    const int xyb = (int)(bid % (u32)NXY);
    const int zg  = (int)(bid / (u32)NXY);
    const int x0 = (xyb % NXB) * 16;
    const int y0 = (xyb / NXB) * 4;
    const int z0 = zg * M;

    f4v acc[M][NT];
    #pragma unroll
    for (int m = 0; m < M; ++m) {
        #pragma unroll
        for (int nt = 0; nt < NT; ++nt) {
            float bv = gld(bias, nt * 16 + nlo, bmode);
            acc[m][nt][0] = bv; acc[m][nt][1] = bv; acc[m][nt][2] = bv; acc[m][nt][3] = bv;
        }
    }

    const u32 selLo = (x0 == 0       && nlo == 0)  ? 0u : 0xFFFFFFFFu;
    const u32 selHi = (x0 == WW - 16 && nlo == 15) ? 0u : 0xFFFFFFFFu;

    u32 zm[PL];
    #pragma unroll
    for (int p = 0; p < PL; ++p) {
        const int z2 = z0 - 1 + p;
        zm[p] = ((unsigned)z2 < (unsigned)DD) ? 0xFFFFFFFFu : 0u;
    }
    u32 ym[3];
    #pragma unroll
    for (int dyi = 0; dyi < 3; ++dyi) {
        const int y2 = y0 + wave + dyi - 1;
        ym[dyi] = ((unsigned)y2 < (unsigned)HH) ? 0xFFFFFFFFu : 0u;
    }

    constexpr int NQ = PL * 6 * 18 * 4;      // 16B quarters to stage per ch
    constexpr int KQ = (NQ + 255) / 256;

    const bf16* bp = wtb + (long)nlo * 32 + quad * 8;

    #pragma unroll 1
    for (int ch = 0; ch < NCH; ++ch) {
        __syncthreads();                     // previous consume done
        #pragma unroll
        for (int k = 0; k < KQ; ++k) {
            const int q = tid + k * 256;
            if (q < NQ) {
                const int qs = q & 3;
                const int f = q >> 2;
                const int vx = f % 18;
                const int rest = f / 18;
                const int r = rest % 6;
                const int lp = rest / 6;
                int zc = z0 - 1 + lp; zc = zc < 0 ? 0 : (zc >= DD ? DD - 1 : zc);
                int yc = y0 - 1 + r;  yc = yc < 0 ? 0 : (yc >= HH ? HH - 1 : yc);
                int xc = x0 - 1 + vx; xc = xc < 0 ? 0 : (xc >= WW ? WW - 1 : xc);
                const bf16* gp = src + ((long)zc * HW + (long)yc * WW + xc) * (long)SS + ch * 32 + qs * 8;
                *(uint4*)&lds[lp][r][vx][qs * 8] = *(const uint4*)gp;
            }
        }
        __syncthreads();                     // stage visible to all waves

        #pragma unroll 1
        for (int dyi = 0; dyi < 3; ++dyi) {
            if (!ym[dyi]) continue;          // wave-uniform; no barriers inside
            const int rr = wave + dyi;
            #pragma unroll
            for (int dxi = 0; dxi < 3; ++dxi) {
                union U { uint4 u; s8v v; } b[3][NT];
                #pragma unroll
                for (int dz = 0; dz < 3; ++dz)
                    #pragma unroll
                    for (int nt = 0; nt < NT; ++nt)
                        b[dz][nt].u = *(const uint4*)(bp +
                            (((long)(dz * 9 + dyi * 3 + dxi) * NCH + ch) * COUT) * 32 + nt * 512);
                const u32 sx = (dxi == 0) ? selLo : (dxi == 2 ? selHi : 0xFFFFFFFFu);
                #pragma unroll
                for (int p = 0; p < PL; ++p) {
                    union U2 { uint4 u; s8v v; } a;
                    a.u = *(const uint4*)&lds[p][rr][nlo + dxi][quad * 8];
                    const u32 mm = zm[p] & sx;
                    a.u.x &= mm; a.u.y &= mm; a.u.z &= mm; a.u.w &= mm;
                    #pragma unroll
                    for (int dz = 0; dz < 3; ++dz) {
                        const int m = p - dz;
                        if (m < 0 || m >= M) continue;   // compile-time prune
                        #pragma unroll
                        for (int nt = 0; nt < NT; ++nt)
                            acc[m][nt] = __builtin_amdgcn_mfma_f32_16x16x32_bf16(a.v, b[dz][nt].v, acc[m][nt], 0, 0, 0);
                    }
                }
            }
        }
    }

    const int yw = y0 + wave;
    #pragma unroll
    for (int m = 0; m < M; ++m) {
        const long vbase = (long)(z0 + m) * HW + (long)yw * WW + x0 + quad * 4;
        #pragma unroll
        for (int nt = 0; nt < NT; ++nt) {
            #pragma unroll
            for (int reg = 0; reg < 4; ++reg) {
                float v = acc[m][nt][reg];
                v = v >= 0.f ? v : v * slope;
                dst[(vbase + reg) * (long)dstride + dcol0 + nt * 16 + nlo] = f2bf(v);
            }
        }
    }
}

// ------- tiled small conv: Cin=16 -> Cout=3, linear, f32 out ---------------
template<int ZS>
__global__ __launch_bounds__(256, 2) void k_conv_small_t(
        const bf16* __restrict__ src, int sstride, int scol0,
        const float* __restrict__ wt, const void* __restrict__ bias,
        float* __restrict__ dst, int D, int H, int W,
        const int* __restrict__ bmodep) {
    const int bmode = *bmodep;
    __shared__ bf16 lds[ZS + 2][18][18][16];   // ZS=4: 62208 B
    const int tid = threadIdx.x;
    const int gx = W >> 4;                      // W % 16 == 0
    const int gy = (H + 15) >> 4;
    const int xyt = (int)(blockIdx.x % (u32)(gx * gy));
    const int zg  = (int)(blockIdx.x / (u32)(gx * gy));
    const int x0 = (xyt % gx) << 4;
    const int y0 = (xyt / gx) << 4;
    const int z0 = zg * ZS;

    // ---- stage (ZS+2) planes of 18x18 fragments (zeros outside volume) ----
    const int NFRAG = (ZS + 2) * 324;
    for (int f = tid; f < NFRAG; f += 256) {
        int pl = f / 324, r = f - pl * 324;
        int yy = r / 18, xx = r - yy * 18;
        int z2 = z0 - 1 + pl, y2 = y0 - 1 + yy, x2 = x0 - 1 + xx;
        uint4 lo = {0, 0, 0, 0}, hi = {0, 0, 0, 0};
        if ((unsigned)z2 < (unsigned)D && (unsigned)y2 < (unsigned)H && (unsigned)x2 < (unsigned)W) {
            const bf16* p = src + ((long)(z2 * H + y2) * W + x2) * (long)sstride + scol0;
            lo = *(const uint4*)p;
            hi = *(const uint4*)(p + 8);
        }
        *(uint4*)&lds[pl][yy][xx][0] = lo;
        *(uint4*)&lds[pl][yy][xx][8] = hi;
    }
    __syncthreads();

    const int ty = tid >> 4, tx = tid & 15;
    const bool live = (y0 + ty) < H;

    float a0[ZS], a1[ZS], a2[ZS];
    {
        float b0 = gld(bias, 0, bmode), b1 = gld(bias, 1, bmode), b2 = gld(bias, 2, bmode);
        #pragma unroll
        for (int zz = 0; zz < ZS; ++zz) { a0[zz] = b0; a1[zz] = b1; a2[zz] = b2; }
    }

    #pragma unroll 1
    for (int tap = 0; tap < 27; ++tap) {
        const int dz = tap / 9, dy = (tap / 3) % 3, dx = tap % 3;
        const float* w = wt + tap * 48;          // uniform -> scalar loads
        float wv[48];
        #pragma unroll
        for (int k = 0; k < 48; ++k) wv[k] = w[k];
        #pragma unroll
        for (int zz = 0; zz < ZS; ++zz) {
            union { uint4 u[2]; bf16 h[16]; } fr;
            fr.u[0] = *(const uint4*)&lds[zz + dz][ty + dy][tx + dx][0];
            fr.u[1] = *(const uint4*)&lds[zz + dz][ty + dy][tx + dx][8];
            #pragma unroll
            for (int c = 0; c < 16; ++c) {
                float f = bf2f(fr.h[c]);
                a0[zz] += f * wv[c * 3];
                a1[zz] += f * wv[c * 3 + 1];
                a2[zz] += f * wv[c * 3 + 2];
            }
        }
    }

    if (!live) return;
    #pragma unroll
    for (int zz = 0; zz < ZS; ++zz) {
        long p = ((long)(z0 + zz) * H + (y0 + ty)) * W + (x0 + tx);
        dst[p * 3]     = sf(a0[zz]);
        dst[p * 3 + 1] = sf(a1[zz]);
        dst[p * 3 + 2] = sf(a2[zz]);
    }
}

// ------- x2 upsample taps ---------------------------------------------------
__device__ __forceinline__ void up_taps(int i, int n, int& j0, int& j1, float& w0, float& w1) {
    if (i & 1) { j0 = i >> 1; j1 = j0 + 1; w0 = 0.75f; w1 = 0.25f; if (j1 >= n) { j1 = j0; w0 = 1.f; w1 = 0.f; } }
    else { j1 = i >> 1; j0 = j1 - 1; w0 = 0.25f; w1 = 0.75f; if (j0 < 0) { j0 = j1; w0 = 0.f; w1 = 1.f; } }
}

// ctx16 [NHALF][16] -> xin2 cols 59..74
__global__ void k_up_ctx(const bf16* __restrict__ in, bf16* __restrict__ xin2) {
    long p = (long)blockIdx.x * 256 + threadIdx.x;
    if (p >= NFULL) return;
    int x = (int)(p % W2c), y = (int)((p / W2c) % H2c), z = (int)(p / (W2c * H2c));
    int jz0, jz1, jy0, jy1, jx0, jx1; float wz0, wz1, wy0, wy1, wx0, wx1;
    up_taps(z, D1c, jz0, jz1, wz0, wz1);
    up_taps(y, H1c, jy0, jy1, wy0, wy1);
    up_taps(x, W1c, jx0, jx1, wx0, wx1);
    float acc[16];
    for (int c = 0; c < 16; ++c) acc[c] = 0.f;
    int jzs[2] = { jz0, jz1 }; float wzs[2] = { wz0, wz1 };
    int jys[2] = { jy0, jy1 }; float wys[2] = { wy0, wy1 };
    int jxs[2] = { jx0, jx1 }; float wxs[2] = { wx0, wx1 };
    for (int a = 0; a < 2; ++a) {
        if (wzs[a] == 0.f) continue;
        for (int b = 0; b < 2; ++b) {
            if (wys[b] == 0.f) continue;
            float wzy = wzs[a] * wys[b];
            for (int d = 0; d < 2; ++d) {
                if (wxs[d] == 0.f) continue;
                float w = wzy * wxs[d];
                long rb = ((long)(jzs[a] * H1c + jys[b]) * W1c + jxs[d]) * 16;
                for (int c = 0; c < 16; ++c) acc[c] += w * bf2f(in[cl(rb + c, NCTX16)]);
            }
        }
    }
    for (int c = 0; c < 16; ++c) xin2[cl(p * (long)S2 + 59 + c, NX2)] = f2bf(acc[c]);
}

// fused: velup = 2*up(vel1); du2 = warp(disp_up, velup) + velup; xin2 75..77
__global__ void k_warp_dispup(const void* __restrict__ dispup, const float* __restrict__ vel1,
                              float* __restrict__ du2, bf16* __restrict__ xin2,
                              const int* __restrict__ modep) {
    int mode = *modep;
    long p = (long)blockIdx.x * 256 + threadIdx.x;
    if (p >= NFULL) return;
    int x = (int)(p % W2c), y = (int)((p / W2c) % H2c), z = (int)(p / (W2c * H2c));
    int jz0, jz1, jy0, jy1, jx0, jx1; float wz0, wz1, wy0, wy1, wx0, wx1;
    up_taps(z, D1c, jz0, jz1, wz0, wz1);
    up_taps(y, H1c, jy0, jy1, wy0, wy1);
    up_taps(x, W1c, jx0, jx1, wx0, wx1);
    int jzs[2] = { jz0, jz1 }; float wzs[2] = { wz0, wz1 };
    int jys[2] = { jy0, jy1 }; float wys[2] = { wy0, wy1 };
    int jxs[2] = { jx0, jx1 }; float wxs[2] = { wx0, wx1 };
    float vu[3] = { 0.f, 0.f, 0.f };
    for (int a = 0; a < 2; ++a) {
        if (wzs[a] == 0.f) continue;
        for (int b = 0; b < 2; ++b) {
            if (wys[b] == 0.f) continue;
            float wzy = wzs[a] * wys[b];
            for (int d = 0; d < 2; ++d) {
                if (wxs[d] == 0.f) continue;
                float w = wzy * wxs[d];
                long rb = ((long)(jzs[a] * H1c + jys[b]) * W1c + jxs[d]) * 3;
                for (int c = 0; c < 3; ++c) vu[c] += w * sf(vel1[cl(rb + c, N3H)]);
            }
        }
    }
    for (int c = 0; c < 3; ++c) vu[c] = sf(vu[c] * 2.f);
    float cz = z + vu[0], cy = y + vu[1], cx = x + vu[2];
    float acc[3] = { 0.f, 0.f, 0.f };
    float z0f = floorf(cz), y0f = floorf(cy), x0f = floorf(cx);
    int z0 = (int)z0f, y0 = (int)y0f, x0 = (int)x0f;
    float fz = cz - z0f, fy = cy - y0f, fx = cx - x0f;
    for (int dz = 0; dz < 2; ++dz) {
        int zi = z0 + dz; if (zi < 0 || zi >= D2c) continue;
        float wz = dz ? fz : 1.f - fz;
        for (int dy = 0; dy < 2; ++dy) {
            int yi = y0 + dy; if (yi < 0 || yi >= H2c) continue;
            float wzy = wz * (dy ? fy : 1.f - fy);
            for (int dx = 0; dx < 2; ++dx) {
                int xi = x0 + dx; if (xi < 0 || xi >= W2c) continue;
                float w = wzy * (dx ? fx : 1.f - fx);
                long idx = (long)(zi * H2c + yi) * W2c + xi;
                for (int c = 0; c < 3; ++c) acc[c] += w * gld(dispup, cl((long)c * NFULL + idx, 3 * NFULL), mode);
            }
        }
    }
    for (int c = 0; c < 3; ++c) {
        float v = sf(acc[c] + vu[c]);
        du2[cl(p * 3 + c, N3F)] = v;
        xin2[cl(p * (long)S2 + 75 + c, NX2)] = f2bf(v);
    }
}

// robust t decode (handles bf16-stored or f32-stored scalar)
__device__ __forceinline__ float decode_t(const u16* tp) {
    u16 b0 = tp[0], b1 = tp[1];
    union { u32 i; float f; } a, b;
    a.i = ((u32)b0) << 16;
    b.i = ((u32)b1 << 16) | b0;
    float ta = a.f, tb = b.f;
    bool okA = (ta == ta) && ta >= 0.f && ta < 0.75f;
    bool okB = (tb == tb) && tb >= 0.f && tb < 0.75f;
    return okB ? tb : (okA ? ta : 0.f);
}

// vf = (warp(du2, vu2) + vu2 - disp_up) / (1 - t); out mode-dispatched
__global__ void k_final(const float* __restrict__ du2, const float* __restrict__ vu2,
                        const void* __restrict__ dispup, const u16* __restrict__ tptr,
                        void* __restrict__ out, long out_n, const int* __restrict__ modep) {
    int mode = *modep;
    long p = (long)blockIdx.x * 256 + threadIdx.x;
    if (p >= NFULL) return;
    float t = decode_t(tptr);
    float den = 1.f - t;
    if (fabsf(den) < 1e-6f) den = 1e-6f;
    float inv = 1.f / den;
    int x = (int)(p % W2c), y = (int)((p / W2c) % H2c), z = (int)(p / (W2c * H2c));
    float cz = z + sf(vu2[cl(p * 3, N3F)]);
    float cy = y + sf(vu2[cl(p * 3 + 1, N3F)]);
    float cx = x + sf(vu2[cl(p * 3 + 2, N3F)]);
    float acc[3] = { 0.f, 0.f, 0.f };
    float z0f = floorf(cz), y0f = floorf(cy), x0f = floorf(cx);
    int z0 = (int)z0f, y0 = (int)y0f, x0 = (int)x0f;
    float fz = cz - z0f, fy = cy - y0f, fx = cx - x0f;
    for (int dz = 0; dz < 2; ++dz) {
        int zi = z0 + dz; if (zi < 0 || zi >= D2c) continue;
        float wz = dz ? fz : 1.f - fz;
        for (int dy = 0; dy < 2; ++dy) {
            int yi = y0 + dy; if (yi < 0 || yi >= H2c) continue;
            float wzy = wz * (dy ? fy : 1.f - fy);
            for (int dx = 0; dx < 2; ++dx) {
                int xi = x0 + dx; if (xi < 0 || xi >= W2c) continue;
                float w = wzy * (dx ? fx : 1.f - fx);
                long rb = ((long)(zi * H2c + yi) * W2c + xi) * 3;
                for (int c = 0; c < 3; ++c) acc[c] += w * sf(du2[cl(rb + c, N3F)]);
            }
        }
    }
    for (int c = 0; c < 3; ++c) {
        float v = (acc[c] + sf(vu2[cl(p * 3 + c, N3F)]) - gld(dispup, cl((long)c * NFULL + p, 3 * NFULL), mode)) * inv;
        long oi = cl((long)c * NFULL + p, out_n);
        if (mode) ((float*)out)[oi] = sf(v);
        else      ((bf16*)out)[oi] = f2bf(v);
    }
}

static inline int cdiv(long a, long b) { return (int)((a + b - 1) / b); }

extern "C" void kernel_launch(void* const* d_in, const int* in_sizes, int n_in,
                              void* d_out, int out_size, void* d_ws, size_t ws_size,
                              hipStream_t stream) {
    const u16* t_in = (const u16*)d_in[0];
    const void* disp_up = d_in[1];
    const void* fx  = d_in[2];
    const void* fy  = d_in[3];
    const void* fxu = d_in[4];
    const void* fyu = d_in[5];
    const void* ctx = d_in[6];

    const size_t XIN1_B = (size_t)NX1 * 2;
    const size_t XIN2_B = (size_t)NX2 * 2;
    // guards before/after the xin region so any residual halo addressing
    // stays inside the allocation
    const size_t base_need = XIN1_B + XIN2_B + 2 * (size_t)GUARD;
    const size_t base_pad = (base_need + 255) & ~(size_t)255;
    const size_t vf_elems = 3UL * NFULL;

    // wtb sizes (bf16 elements): 27 * nchunk * Cout * 32
    const long WTB0 = 387072;  // 224->64, 7ch
    const long WTB1 = 373248;  // 288->48, 9ch
    const long WTB2 = 304128;  // 336->32, 11ch
    const long WTB3 = 165888;  // 368->16, 12ch
    const long WTB5 = 82944;   // 78->32, 3ch
    const long WTB6 = 55296;   // 110->16, 4ch
    const long WTB_TOT = WTB0 + WTB1 + WTB2 + WTB3 + WTB5 + WTB6; // 1,368,576

    size_t scro[11];
    {
        size_t o = 0;
        auto al = [&](size_t bytes) { size_t r = o; o = (o + bytes + 255) & ~(size_t)255; return r; };
        scro[0] = al((size_t)WTB_TOT * 2);      // WTB (bf16, mfma layout)
        scro[1] = al(2UL * 1296 * 4);           // WT f32 (two small convs)
        scro[2] = al((size_t)NCTX16 * 2);       // CTX16
        scro[3] = al((size_t)N3H * 4);          // VEL1
        scro[4] = al((size_t)N3H * 4);          // DISPH
        scro[5] = al((size_t)N3F * 4);          // DU2
        scro[6] = al((size_t)N3F * 4);          // VU2
        scro[7] = al(4UL * RG * 2 * 8);         // partials
        scro[8] = al(16 * 8);                   // RED
        scro[9] = al(32 * 4);                   // MODES
        scro[10] = o;
    }
    const size_t scratch_need = scro[10];
    const size_t tail_avail = ((size_t)out_size > vf_elems) ? ((size_t)out_size - vf_elems) * 2 : 0;

    char* scr = nullptr;
    if (ws_size >= base_pad + scratch_need) {
        scr = (char*)d_ws + base_pad;
    } else if (ws_size >= base_need && tail_avail >= scratch_need) {
        scr = (char*)d_out + vf_elems * 2;
    }
    if (scr == nullptr) {
        k_fill<<<2048, 256, 0, stream>>>((u16*)d_out, (long)out_size, 0x49A0);
        return;
    }

    char* ws = (char*)d_ws;
    bf16*  xin1  = (bf16*)(ws + GUARD);
    bf16*  xin2  = (bf16*)(ws + GUARD + XIN1_B);
    bf16*  wtball = (bf16*)(scr + scro[0]);
    float* wtf   = (float*)(scr + scro[1]);
    bf16*  ctx16 = (bf16*)(scr + scro[2]);
    float* vel1  = (float*)(scr + scro[3]);
    float* disph = (float*)(scr + scro[4]);
    float* du2   = (float*)(scr + scro[5]);
    float* vu2   = (float*)(scr + scro[6]);
    double* part = (double*)(scr + scro[7]);
    double* red  = (double*)(scr + scro[8]);
    int*   modes = (int*)(scr + scro[9]);
    double* pA = part;
    double* pB = part + RG * 2;
    double* pC = part + RG * 4;
    double* pD = part + RG * 6;

    bf16* wtb0 = wtball;
    bf16* wtb1 = wtb0 + WTB0;
    bf16* wtb2 = wtb1 + WTB1;
    bf16* wtb3 = wtb2 + WTB2;
    bf16* wtb5 = wtb3 + WTB3;
    bf16* wtb6 = wtb5 + WTB5;
    float* wt4 = wtf;
    float* wt7 = wtf + 1296;

    // zero-init big buffers (incl. guards) and scratch (modes default 0 = bf16)
    k_fill<<<4096, 256, 0, stream>>>((u16*)ws, (long)(base_need / 2), 0);
    k_fill<<<4096, 256, 0, stream>>>((u16*)scr, (long)(scratch_need / 2), 0);

    // dtype detection for all tensor inputs
    for (int i = 1; i < 23 && i < n_in; ++i) {
        k_detect<<<1, 256, 0, stream>>>(d_in[i], (long)in_sizes[i], modes + i);
    }

    // MFMA weight repack (bf16, zero-padded K tails)
    k_wtb<<<cdiv(WTB0, 256), 256, 0, stream>>>(d_in[7],  wtb0, 224, 64, 7,  modes + 7);
    k_wtb<<<cdiv(WTB1, 256), 256, 0, stream>>>(d_in[9],  wtb1, 288, 48, 9,  modes + 9);
    k_wtb<<<cdiv(WTB2, 256), 256, 0, stream>>>(d_in[11], wtb2, 336, 32, 11, modes + 11);
    k_wtb<<<cdiv(WTB3, 256), 256, 0, stream>>>(d_in[13], wtb3, 368, 16, 12, modes + 13);
    k_wtb<<<cdiv(WTB5, 256), 256, 0, stream>>>(d_in[17], wtb5, 78,  32, 3,  modes + 17);
    k_wtb<<<cdiv(WTB6, 256), 256, 0, stream>>>(d_in[19], wtb6, 110, 16, 4,  modes + 19);
    // f32 weights for the two small convs
    k_wt<<<cdiv(1296, 256), 256, 0, stream>>>(d_in[15], wt4, 16, 3, modes + 15);
    k_wt<<<cdiv(1296, 256), 256, 0, stream>>>(d_in[21], wt7, 16, 3, modes + 21);

    k_tcl<<<cdiv(NHALF, 256), 256, 0, stream>>>(fy,  32L * NHALF, xin1, NX1, 125, 32, NHALF, S1, modes + 3);
    k_tcl<<<cdiv(NHALF, 256), 256, 0, stream>>>(ctx, 32L * NHALF, xin1, NX1, 189, 32, NHALF, S1, modes + 6);
    k_tcl<<<cdiv(NFULL, 256), 256, 0, stream>>>(fyu, 16L * NFULL, xin2, NX2, 27, 16, NFULL, S2, modes + 5);

    k_down<<<cdiv(NHALF, 256), 256, 0, stream>>>(disp_up, disph, xin1, modes + 1);

    k_warp_cf<32><<<cdiv(NHALF, 256), 256, 0, stream>>>(fx, 32L * NHALF, disph, N3H, xin1, NX1, S1, 157, D1c, H1c, W1c, modes + 2);
    k_reduce_cl<<<RG, 256, 0, stream>>>(xin1, NX1, NHALF, S1, 157, 32, pA, modes + 31);
    k_reduce_cl<<<RG, 256, 0, stream>>>(fy, 32L * NHALF, 32L * NHALF, 1, 0, 1, pB, modes + 3);
    k_stats2<<<1, 256, 0, stream>>>(pA, pB, (double)(32L * NHALF), 32.0, red);

    // LDS-tiled cost volume 1: grid = 60 xy-tiles (8x4) x 12 zgroups = 720
    k_cv1_t<<<720, 128, 0, stream>>>(xin1, red);

    // fl1 dense block — LDS-staged MFMA conv (4 rows x M=2 z-planes / block)
    // grid = (48/16 x 40/4 = 30 xy-blocks) x (48/2 = 24 zgroups) = 720 (%8==0)
    k_conv_mfma<4, 7, 64, 2, S1, D1c, H1c, W1c><<<720, 256, 0, stream>>>(xin1, wtb0, d_in[8],  xin1, S1, 224, 0.02f, modes + 8);
    k_conv_mfma<3, 9, 48, 2, S1, D1c, H1c, W1c><<<720, 256, 0, stream>>>(xin1, wtb1, d_in[10], xin1, S1, 288, 0.02f, modes + 10);
    k_conv_mfma<2, 11, 32, 2, S1, D1c, H1c, W1c><<<720, 256, 0, stream>>>(xin1, wtb2, d_in[12], xin1, S1, 336, 0.02f, modes + 12);
    k_conv_mfma<1, 12, 16, 2, S1, D1c, H1c, W1c><<<720, 256, 0, stream>>>(xin1, wtb3, d_in[14], ctx16, 16, 0, 0.02f, modes + 14);
    // tiled small conv (NHALF): grid = 3x3 xy-tiles x 12 zgroups = 108
    k_conv_small_t<4><<<108, 256, 0, stream>>>(ctx16, 16, 0, wt4, d_in[16], vel1, D1c, H1c, W1c, modes + 16);

    k_up_ctx<<<cdiv(NFULL, 256), 256, 0, stream>>>(ctx16, xin2);
    k_warp_dispup<<<cdiv(NFULL, 256), 256, 0, stream>>>(disp_up, vel1, du2, xin2, modes + 1);

    k_warp_cf<16><<<cdiv(NFULL, 256), 256, 0, stream>>>(fxu, 16L * NFULL, du2, N3F, xin2, NX2, S2, 43, D2c, H2c, W2c, modes + 4);
    k_reduce_cl<<<RG, 256, 0, stream>>>(xin2, NX2, NFULL, S2, 43, 16, pC, modes + 31);
    k_reduce_cl<<<RG, 256, 0, stream>>>(fyu, 16L * NFULL, 16L * NFULL, 1, 0, 1, pD, modes + 5);
    k_stats2<<<1, 256, 0, stream>>>(pC, pD, (double)(16L * NFULL), 16.0, red + 2);

    // LDS-tiled cost volume 2: grid = 30 xy-tiles (16x16) x 24 zgroups = 720
    k_cv2_t<<<720, 256, 0, stream>>>(xin2, red);

    // fl2 block — LDS-staged MFMA conv (4 rows x M=4 z-planes / block)
    // grid = (96/16 x 80/4 = 120 xy-blocks) x (96/4 = 24 zgroups) = 2880 (%8==0)
    k_conv_mfma<2, 3, 32, 4, S2, D2c, H2c, W2c><<<2880, 256, 0, stream>>>(xin2, wtb5, d_in[18], xin2, S2, 78,  0.02f, modes + 18);
    k_conv_mfma<1, 4, 16, 4, S2, D2c, H2c, W2c><<<2880, 256, 0, stream>>>(xin2, wtb6, d_in[20], xin2, S2, 110, 0.02f, modes + 20);
    // tiled small conv (NFULL): grid = 6x5 xy-tiles x 24 zgroups = 720
    k_conv_small_t<4><<<720, 256, 0, stream>>>(xin2, S2, 110, wt7, d_in[22], vu2, D2c, H2c, W2c, modes + 22);

    // out dtype follows disp_up's detected mode
    k_final<<<cdiv(NFULL, 256), 256, 0, stream>>>(du2, vu2, disp_up, t_in, d_out, (long)out_size, modes + 1);
    k_fill_tail<<<2048, 256, 0, stream>>>(d_out, (long)vf_elems, (long)out_size, modes + 1);
}

// Round 9
// 2509.053 us; speedup vs baseline: 1.4369x; 1.0246x over previous
//
#include <hip/hip_runtime.h>
#include <hip/hip_bf16.h>

typedef __hip_bfloat16 bf16;
typedef unsigned short u16;
typedef unsigned int u32;

#define D1c 48
#define H1c 40
#define W1c 48
#define NHALF 92160L
#define D2c 96
#define H2c 80
#define W2c 96
#define NFULL 737280L
#define S1 368
#define S2 128
#define RG 512

#define NX1 (NHALF * S1)
#define NX2 (NFULL * S2)
#define NCTX16 (NHALF * 16)
#define N3H (NHALF * 3)
#define N3F (NFULL * 3)
#define GUARD 1024

typedef __attribute__((ext_vector_type(8))) short s8v;
typedef __attribute__((ext_vector_type(4))) float f4v;

__device__ __forceinline__ float bf2f(bf16 v){ return __bfloat162float(v); }
__device__ __forceinline__ float sf(float v){ return (v == v && fabsf(v) < 1e30f) ? v : 0.f; }
__device__ __forceinline__ bf16 f2bf(float v){ return __float2bfloat16(sf(v)); }
__device__ __forceinline__ u16 f2bfu(float v){ bf16 b = f2bf(v); return *(u16*)&b; }
__device__ __forceinline__ long cl(long i, long n){ i = i < 0 ? 0 : i; return i >= n ? n - 1 : i; }
// mode-dispatched input load: 0 = bf16, 1 = f32
__device__ __forceinline__ float gld(const void* p, long i, int mode){
    return mode ? sf(((const float*)p)[i]) : sf(bf2f(((const bf16*)p)[i]));
}

// ---------------- dtype detection: one block per input ---------------------
__global__ void k_detect(const void* p, long nelem, int* flag) {
    long N = nelem < 4096 ? nelem : 4096;
    int tid = threadIdx.x;
    int nb = 0, nf = 0;
    for (long i = tid; i < N; i += 256) {
        float v = bf2f(((const bf16*)p)[i]);
        if (v == v && fabsf(v) <= 1e4f) nb++;
    }
    long M = N / 2;
    for (long i = tid; i < M; i += 256) {
        float v = ((const float*)p)[i];
        if (v == v && fabsf(v) <= 1e4f) nf += 2;
    }
    __shared__ int sb[256], sq[256];
    sb[tid] = nb; sq[tid] = nf;
    __syncthreads();
    for (int t = 128; t; t >>= 1) {
        if (tid < t) { sb[tid] += sb[tid + t]; sq[tid] += sq[tid + t]; }
        __syncthreads();
    }
    if (tid == 0) *flag = (sb[0] >= sq[0]) ? 0 : 1;
}

// ---------------- fills -----------------------------------------------------
__global__ void k_fill(u16* __restrict__ p, long n, u16 val) {
    long i = (long)blockIdx.x * 256 + threadIdx.x;
    long stride = (long)gridDim.x * 256;
    for (; i < n; i += stride) p[i] = val;
}
__global__ void k_fill_tail(void* out, long vf, long out_n, const int* __restrict__ modep) {
    int mode = *modep;
    long n = out_n - vf;
    if (n <= 0) return;
    long i = (long)blockIdx.x * 256 + threadIdx.x;
    long stride = (long)gridDim.x * 256;
    if (mode) { float* p = (float*)out + vf; for (; i < n; i += stride) p[i] = 0.f; }
    else      { u16*   p = (u16*)out + vf;   for (; i < n; i += stride) p[i] = 0; }
}

// ------- weight transpose: (co,ci,tap) -> (tap,ci,co) f32 (small convs) ----
__global__ void k_wt(const void* __restrict__ w, float* __restrict__ wt,
                     int Cin, int Cout, const int* __restrict__ modep) {
    int mode = *modep;
    long n = (long)Cin * Cout * 27;
    long i = (long)blockIdx.x * 256 + threadIdx.x;
    if (i >= n) return;
    int tap = (int)(i % 27); long r = i / 27;
    int ci = (int)(r % Cin); int co = (int)(r / Cin);
    wt[cl(((long)tap * Cin + ci) * Cout + co, n)] = gld(w, cl(i, n), mode);
}

// ------- MFMA weight repack: (co,ci,tap) -> [tap][chunk][co][32] bf16 ------
// zero-padded for ci >= Cin (Cin tails)
__global__ void k_wtb(const void* __restrict__ w, bf16* __restrict__ wtb,
                      int Cin, int Cout, int nchunk, const int* __restrict__ modep) {
    int mode = *modep;
    long n = 27L * nchunk * Cout * 32;
    long i = (long)blockIdx.x * 256 + threadIdx.x;
    if (i >= n) return;
    int kk = (int)(i & 31);
    long r = i >> 5;
    int co = (int)(r % Cout); r /= Cout;
    int ch = (int)(r % nchunk); int tap = (int)(r / nchunk);
    int ci = ch * 32 + kk;
    float v = (ci < Cin) ? gld(w, ((long)co * Cin + ci) * 27 + tap, mode) : 0.f;
    wtb[i] = f2bf(v);
}

// ------- channel-first [C][N] -> channel-last columns ----------------------
__global__ void k_tcl(const void* __restrict__ in, long nin,
                      bf16* __restrict__ out, long nout, int col0,
                      int C, long N, int stride, const int* __restrict__ modep) {
    int mode = *modep;
    long n = (long)blockIdx.x * 256 + threadIdx.x;
    if (n >= N) return;
    for (int c = 0; c < C; ++c)
        out[cl(n * stride + col0 + c, nout)] = f2bf(gld(in, cl((long)c * N + n, nin), mode));
}

// ------- channel-first [C][N] -> dense channel-last f32 [N][C] -------------
// (coalesced per-channel reads; preserves f32 values exactly for the warp)
__global__ void k_tclf(const void* __restrict__ in, float* __restrict__ out,
                       int C, long N, const int* __restrict__ modep) {
    int mode = *modep;
    long n = (long)blockIdx.x * 256 + threadIdx.x;
    if (n >= N) return;
    for (int c = 0; c < C; ++c)
        out[n * C + c] = gld(in, (long)c * N + n, mode);
}

// ------- antialiased x0.5 downsample taps ----------------------------------
__device__ __forceinline__ void down_taps(int i, int n_in, int j[4], float w[4]) {
    float s = 0.f;
    for (int k = 0; k < 4; ++k) {
        int jj = 2 * i - 1 + k;
        bool valid = (jj >= 0 && jj < n_in);
        j[k] = valid ? jj : 0;
        float b = (k == 0 || k == 3) ? 1.f : 3.f;
        w[k] = valid ? b : 0.f;
        s += w[k];
    }
    float inv = 1.f / fmaxf(s, 1e-6f);
    for (int k = 0; k < 4; ++k) w[k] *= inv;
}

// disp = resize(disp_up,0.5)*0.5 -> disph f32 + xin1 cols 221..223
__global__ void k_down(const void* __restrict__ dispup, float* __restrict__ disph,
                       bf16* __restrict__ xin1, const int* __restrict__ modep) {
    int mode = *modep;
    long p = (long)blockIdx.x * 256 + threadIdx.x;
    if (p >= NHALF) return;
    int x = (int)(p % W1c), y = (int)((p / W1c) % H1c), z = (int)(p / (W1c * H1c));
    int jz[4], jy[4], jx[4]; float wz[4], wy[4], wx[4];
    down_taps(z, D2c, jz, wz); down_taps(y, H2c, jy, wy); down_taps(x, W2c, jx, wx);
    for (int c = 0; c < 3; ++c) {
        float acc = 0.f;
        for (int a = 0; a < 4; ++a) {
            if (wz[a] == 0.f) continue;
            for (int b = 0; b < 4; ++b) {
                if (wy[b] == 0.f) continue;
                float wzy = wz[a] * wy[b];
                long base = (long)c * NFULL + ((long)jz[a] * H2c + jy[b]) * W2c;
                for (int d = 0; d < 4; ++d) {
                    if (wx[d] == 0.f) continue;
                    acc += wzy * wx[d] * gld(dispup, cl(base + jx[d], 3 * NFULL), mode);
                }
            }
        }
        acc = sf(acc * 0.5f);
        disph[cl(p * 3 + c, N3H)] = acc;
        xin1[cl(p * (long)S1 + 221 + c, NX1)] = f2bf(acc);
    }
}

// ------- trilinear warp, channel-first INPUT volume, zero pad --------------
template<int C>
__global__ void k_warp_cf(const void* __restrict__ vol, long nvol,
                          const float* __restrict__ coords, long ncoords,
                          bf16* __restrict__ dst, long ndst, int dstride, int col0,
                          int D, int H, int W, const int* __restrict__ modep) {
    int mode = *modep;
    const long N = (long)D * H * W;
    long p = (long)blockIdx.x * 256 + threadIdx.x;
    if (p >= N) return;
    int x = (int)(p % W), y = (int)((p / W) % H), z = (int)(p / ((long)W * H));
    float cz = z + sf(coords[cl(p * 3, ncoords)]);
    float cy = y + sf(coords[cl(p * 3 + 1, ncoords)]);
    float cx = x + sf(coords[cl(p * 3 + 2, ncoords)]);
    float acc[C];
    for (int c = 0; c < C; ++c) acc[c] = 0.f;
    float z0f = floorf(cz), y0f = floorf(cy), x0f = floorf(cx);
    int z0 = (int)z0f, y0 = (int)y0f, x0 = (int)x0f;
    float fz = cz - z0f, fy = cy - y0f, fx = cx - x0f;
    for (int dz = 0; dz < 2; ++dz) {
        int zi = z0 + dz; if (zi < 0 || zi >= D) continue;
        float wz = dz ? fz : 1.f - fz;
        for (int dy = 0; dy < 2; ++dy) {
            int yi = y0 + dy; if (yi < 0 || yi >= H) continue;
            float wzy = wz * (dy ? fy : 1.f - fy);
            for (int dx = 0; dx < 2; ++dx) {
                int xi = x0 + dx; if (xi < 0 || xi >= W) continue;
                float w = wzy * (dx ? fx : 1.f - fx);
                long idx = (long)(zi * H + yi) * W + xi;
                for (int c = 0; c < C; ++c) acc[c] += w * gld(vol, cl((long)c * N + idx, nvol), mode);
            }
        }
    }
    for (int c = 0; c < C; ++c) dst[cl(p * (long)dstride + col0 + c, ndst)] = f2bf(acc[c]);
}

// ------- trilinear warp, dense channel-last f32 source (C=16) --------------
// Round-9: k_warp_cf<16> fetched 871MB vs 23.6MB unique (channel-first source
// -> every (corner,channel) a separate line; 128 scalar loads/voxel). With a
// [N][16] f32 source each corner is 4x float4 (64B contiguous); corner order
// and accumulation order match k_warp_cf exactly (bit-identical in f32 mode).
__global__ void k_warp_cl16(const float* __restrict__ vol,
                            const float* __restrict__ coords,
                            bf16* __restrict__ dst) {
    long p = (long)blockIdx.x * 256 + threadIdx.x;
    if (p >= NFULL) return;
    int x = (int)(p % W2c), y = (int)((p / W2c) % H2c), z = (int)(p / (W2c * H2c));
    float cz = z + sf(coords[p * 3]);
    float cy = y + sf(coords[p * 3 + 1]);
    float cx = x + sf(coords[p * 3 + 2]);
    float acc[16];
    #pragma unroll
    for (int c = 0; c < 16; ++c) acc[c] = 0.f;
    float z0f = floorf(cz), y0f = floorf(cy), x0f = floorf(cx);
    int z0 = (int)z0f, y0 = (int)y0f, x0 = (int)x0f;
    float fz = cz - z0f, fy = cy - y0f, fx = cx - x0f;
    for (int dz = 0; dz < 2; ++dz) {
        int zi = z0 + dz; if (zi < 0 || zi >= D2c) continue;
        float wz = dz ? fz : 1.f - fz;
        for (int dy = 0; dy < 2; ++dy) {
            int yi = y0 + dy; if (yi < 0 || yi >= H2c) continue;
            float wzy = wz * (dy ? fy : 1.f - fy);
            for (int dx = 0; dx < 2; ++dx) {
                int xi = x0 + dx; if (xi < 0 || xi >= W2c) continue;
                float w = wzy * (dx ? fx : 1.f - fx);
                const float4* q = (const float4*)(vol + ((long)(zi * H2c + yi) * W2c + xi) * 16);
                float4 a0 = q[0], a1 = q[1], a2 = q[2], a3 = q[3];
                acc[0]  += w * a0.x; acc[1]  += w * a0.y; acc[2]  += w * a0.z; acc[3]  += w * a0.w;
                acc[4]  += w * a1.x; acc[5]  += w * a1.y; acc[6]  += w * a1.z; acc[7]  += w * a1.w;
                acc[8]  += w * a2.x; acc[9]  += w * a2.y; acc[10] += w * a2.z; acc[11] += w * a2.w;
                acc[12] += w * a3.x; acc[13] += w * a3.y; acc[14] += w * a3.z; acc[15] += w * a3.w;
            }
        }
    }
    #pragma unroll
    for (int c = 0; c < 16; ++c) dst[p * (long)S2 + 43 + c] = f2bf(acc[c]);
}

// ------- two-stage deterministic reduction (sum, sumsq) --------------------
__global__ void k_reduce_cl(const void* __restrict__ base, long nbase, long rows,
                            int stride, int col0, int cn, double* __restrict__ part,
                            const int* __restrict__ modep) {
    int mode = *modep;
    long total = rows * cn;
    double s = 0.0, q = 0.0;
    long i = (long)blockIdx.x * 256 + threadIdx.x;
    long gs = (long)gridDim.x * 256;
    for (; i < total; i += gs) {
        long r = i / cn; int c = (int)(i - r * cn);
        float f = gld(base, cl(r * (long)stride + col0 + c, nbase), mode);
        s += f; q += (double)f * f;
    }
    __shared__ double ls[256], lq[256];
    ls[threadIdx.x] = s; lq[threadIdx.x] = q;
    __syncthreads();
    for (int t = 128; t; t >>= 1) {
        if (threadIdx.x < t) { ls[threadIdx.x] += ls[threadIdx.x + t]; lq[threadIdx.x] += lq[threadIdx.x + t]; }
        __syncthreads();
    }
    if (threadIdx.x == 0) { part[cl(blockIdx.x * 2, RG * 2)] = ls[0]; part[cl(blockIdx.x * 2 + 1, RG * 2)] = lq[0]; }
}

__global__ void k_stats2(const double* __restrict__ pa, const double* __restrict__ pb,
                         double n, double C, double* __restrict__ outm) {
    __shared__ double ls[256], lq[256];
    double s = 0.0, q = 0.0;
    for (int i = threadIdx.x; i < RG; i += 256) { s += pa[i * 2]; q += pa[i * 2 + 1]; }
    ls[threadIdx.x] = s; lq[threadIdx.x] = q;
    __syncthreads();
    for (int t = 128; t; t >>= 1) {
        if (threadIdx.x < t) { ls[threadIdx.x] += ls[threadIdx.x + t]; lq[threadIdx.x] += lq[threadIdx.x + t]; }
        __syncthreads();
    }
    double sa = ls[0], qa = lq[0];
    __syncthreads();
    s = 0.0; q = 0.0;
    for (int i = threadIdx.x; i < RG; i += 256) { s += pb[i * 2]; q += pb[i * 2 + 1]; }
    ls[threadIdx.x] = s; lq[threadIdx.x] = q;
    __syncthreads();
    for (int t = 128; t; t >>= 1) {
        if (threadIdx.x < t) { ls[threadIdx.x] += ls[threadIdx.x + t]; lq[threadIdx.x] += lq[threadIdx.x + t]; }
        __syncthreads();
    }
    if (threadIdx.x == 0) {
        double sb = ls[0], qb = lq[0];
        double va = (qa - sa * sa / n) / (n - 1.0);
        double vb = (qb - sb * sb / n) / (n - 1.0);
        va = va > 0.0 ? va : 0.0;
        vb = vb > 0.0 ? vb : 0.0;
        double sd = 0.5 * (sqrt(va) + sqrt(vb));
        sd = sd < 1e-6 ? 1e-6 : (sd > 1e9 ? 1e9 : sd);
        outm[0] = 0.5 * (sa / n + sb / n);
        outm[1] = 1.0 / (sd * sd * C);
    }
}

// ------- cost volume 1 (md=2, C=32), LDS-tiled -> xin1 cols 0..124 ---------
__global__ __launch_bounds__(128, 2) void k_cv1_t(bf16* __restrict__ xin1,
                                                  const double* __restrict__ red) {
    __shared__ bf16 lds[8][8][12][32];   // [plane z0-2..z0+5][row y0-2..y0+5][x0-2..x0+9][ch]
    const int tid = threadIdx.x;
    const int xyt = (int)(blockIdx.x % 60u);     // 6 x-tiles * 10 y-tiles
    const int zg  = (int)(blockIdx.x / 60u);     // 12 z-groups
    const int x0 = (xyt % 6) * 8;
    const int y0 = (xyt / 6) * 4;
    const int z0 = zg * 4;
    const u16* src16 = (const u16*)xin1;

    for (int f = tid; f < 8 * 8 * 12; f += 128) {
        int xx = f % 12, rest = f / 12;
        int yy = rest % 8, pl = rest / 8;
        int z2 = z0 - 2 + pl, y2 = y0 - 2 + yy, x2 = x0 - 2 + xx;
        u32 pk[16];
        #pragma unroll
        for (int c = 0; c < 16; ++c) pk[c] = 0;
        if ((unsigned)z2 < (unsigned)D1c && (unsigned)y2 < (unsigned)H1c && (unsigned)x2 < (unsigned)W1c) {
            long rb = (((long)z2 * H1c + y2) * W1c + x2) * S1 + 157;
            #pragma unroll
            for (int c = 0; c < 16; ++c)
                pk[c] = (u32)src16[rb + 2 * c] | ((u32)src16[rb + 2 * c + 1] << 16);
        }
        #pragma unroll
        for (int qq = 0; qq < 4; ++qq) {
            uint4 q = { pk[qq * 4], pk[qq * 4 + 1], pk[qq * 4 + 2], pk[qq * 4 + 3] };
            *(uint4*)&lds[pl][yy][xx][qq * 8] = q;
        }
    }
    __syncthreads();

    const float m = sf((float)red[0]), mult = sf((float)red[1]);
    const int tx = tid & 7, ty = (tid >> 3) & 3, tz = tid >> 5;
    const int x = x0 + tx, y = y0 + ty, z = z0 + tz;
    const long p = ((long)z * H1c + y) * W1c + x;

    float fm[32], S = 0.f;
    #pragma unroll
    for (int c = 0; c < 32; ++c) { fm[c] = sf(bf2f(xin1[p * (long)S1 + 125 + c])) - m; S += fm[c]; }

    #pragma unroll 1
    for (int dz = 0; dz < 5; ++dz) {
        const int z2 = z + dz - 2;
        u16 hg[25];
        #pragma unroll
        for (int oo = 0; oo < 25; ++oo) {
            const int dy = oo / 5, dx = oo % 5;
            const int y2 = y + dy - 2, x2 = x + dx - 2;
            float cost = 0.f;
            if ((unsigned)z2 < (unsigned)D1c && (unsigned)y2 < (unsigned)H1c && (unsigned)x2 < (unsigned)W1c) {
                union { uint4 u[4]; bf16 h[32]; } wv;
                #pragma unroll
                for (int qq = 0; qq < 4; ++qq)
                    wv.u[qq] = *(const uint4*)&lds[tz + dz][ty + dy][tx + dx][qq * 8];
                float dot = 0.f;
                #pragma unroll
                for (int c = 0; c < 32; ++c) dot += fm[c] * sf(bf2f(wv.h[c]));
                dot -= m * S;
                cost = dot * mult;
                cost = cost >= 0.f ? cost : 0.05f * cost;
            }
            hg[oo] = f2bfu(cost);
        }
        u16* dstp = (u16*)(xin1 + p * (long)S1) + dz * 25;
        #pragma unroll
        for (int oo = 0; oo < 25; ++oo) dstp[oo] = hg[oo];
    }
}

// ------- cost volume 2 (md=1, C=16), LDS-tiled -> xin2 cols 0..26 ----------
__global__ __launch_bounds__(256, 2) void k_cv2_t(bf16* __restrict__ xin2,
                                                  const double* __restrict__ red) {
    __shared__ bf16 lds[6][18][18][16];
    const int tid = threadIdx.x;
    const int xyt = (int)(blockIdx.x % 30u);     // 6 x-tiles * 5 y-tiles
    const int zg  = (int)(blockIdx.x / 30u);     // 24 z-groups
    const int x0 = (xyt % 6) * 16;
    const int y0 = (xyt / 6) * 16;
    const int z0 = zg * 4;
    const u16* src16 = (const u16*)xin2;

    for (int f = tid; f < 6 * 324; f += 256) {
        int pl = f / 324, r = f - pl * 324;
        int yy = r / 18, xx = r - yy * 18;
        int z2 = z0 - 1 + pl, y2 = y0 - 1 + yy, x2 = x0 - 1 + xx;
        u32 pk[8];
        #pragma unroll
        for (int c = 0; c < 8; ++c) pk[c] = 0;
        if ((unsigned)z2 < (unsigned)D2c && (unsigned)y2 < (unsigned)H2c && (unsigned)x2 < (unsigned)W2c) {
            long rb = (((long)z2 * H2c + y2) * W2c + x2) * S2 + 43;
            #pragma unroll
            for (int c = 0; c < 8; ++c)
                pk[c] = (u32)src16[rb + 2 * c] | ((u32)src16[rb + 2 * c + 1] << 16);
        }
        uint4 q0 = { pk[0], pk[1], pk[2], pk[3] };
        uint4 q1 = { pk[4], pk[5], pk[6], pk[7] };
        *(uint4*)&lds[pl][yy][xx][0] = q0;
        *(uint4*)&lds[pl][yy][xx][8] = q1;
    }
    __syncthreads();

    const float m = sf((float)red[2]), mult = sf((float)red[3]);
    const int tx = tid & 15, ty = tid >> 4;
    const int x = x0 + tx, y = y0 + ty;

    #pragma unroll 1
    for (int zz = 0; zz < 4; ++zz) {
        const int z = z0 + zz;
        const long p = ((long)z * H2c + y) * W2c + x;
        float fm[16], S = 0.f;
        #pragma unroll
        for (int c = 0; c < 16; ++c) {
            fm[c] = sf(bf2f(xin2[p * (long)S2 + 27 + c])) - m;
            S += fm[c];
        }
        union { u16 h[28]; uint4 q[3]; u32 w[14]; } r;
        #pragma unroll
        for (int o = 0; o < 27; ++o) {
            const int dz = o / 9, dy = (o / 3) % 3, dx = o % 3;
            const int z2 = z + dz - 1, y2 = y + dy - 1, x2 = x + dx - 1;
            float cost = 0.f;
            if ((unsigned)z2 < (unsigned)D2c && (unsigned)y2 < (unsigned)H2c && (unsigned)x2 < (unsigned)W2c) {
                union { uint4 u[2]; bf16 h[16]; } wv;
                wv.u[0] = *(const uint4*)&lds[zz + dz][ty + dy][tx + dx][0];
                wv.u[1] = *(const uint4*)&lds[zz + dz][ty + dy][tx + dx][8];
                float dot = 0.f;
                #pragma unroll
                for (int c = 0; c < 16; ++c) dot += fm[c] * sf(bf2f(wv.h[c]));
                dot -= m * S;
                cost = dot * mult;
                cost = cost >= 0.f ? cost : 0.05f * cost;
            }
            r.h[o] = f2bfu(cost);
        }
        r.h[27] = 0;
        u16* dstp = (u16*)(xin2 + p * (long)S2);
        *(uint4*)dstp        = r.q[0];
        *(uint4*)(dstp + 8)  = r.q[1];
        *(uint4*)(dstp + 16) = r.q[2];
        *(u32*)(dstp + 24)   = r.w[12];
        dstp[26] = r.h[26];
    }
}

// ------- MFMA implicit-GEMM 3x3x3 conv, channel-last, LDS-staged -----------
template<int NT, int NCH, int COUT, int M, int SS, int DD, int HH, int WW>
__global__ __launch_bounds__(256, 2) void k_conv_mfma(
        const bf16* __restrict__ src,
        const bf16* __restrict__ wtb, const void* __restrict__ bias,
        bf16* __restrict__ dst, int dstride, int dcol0,
        float slope, const int* __restrict__ bmodep) {
    const int bmode = *bmodep;
    const int tid = threadIdx.x;
    const int wave = tid >> 6, lane = tid & 63;
    const int quad = lane >> 4, nlo = lane & 15;
    constexpr long HW = (long)HH * WW;
    constexpr int PL = M + 2;            // staged planes
    constexpr int NXB = WW / 16;
    constexpr int NYB = HH / 4;          // 4 rows per block (one per wave)
    constexpr int NXY = NXB * NYB;
    __shared__ bf16 lds[PL][6][18][32];  // M=4: 41472 B, M=2: 27648 B

    // bijective chunked swizzle (gridDim.x % 8 == 0 by construction)
    const u32 per = gridDim.x >> 3;
    const u32 bid = (blockIdx.x & 7u) * per + (blockIdx.x >> 3);
    const int xyb = (int)(bid % (u32)NXY);
    const int zg  = (int)(bid / (u32)NXY);
    const int x0 = (xyb % NXB) * 16;
    const int y0 = (xyb / NXB) * 4;
    const int z0 = zg * M;

    f4v acc[M][NT];
    #pragma unroll
    for (int m = 0; m < M; ++m) {
        #pragma unroll
        for (int nt = 0; nt < NT; ++nt) {
            float bv = gld(bias, nt * 16 + nlo, bmode);
            acc[m][nt][0] = bv; acc[m][nt][1] = bv; acc[m][nt][2] = bv; acc[m][nt][3] = bv;
        }
    }

    const u32 selLo = (x0 == 0       && nlo == 0)  ? 0u : 0xFFFFFFFFu;
    const u32 selHi = (x0 == WW - 16 && nlo == 15) ? 0u : 0xFFFFFFFFu;

    u32 zm[PL];
    #pragma unroll
    for (int p = 0; p < PL; ++p) {
        const int z2 = z0 - 1 + p;
        zm[p] = ((unsigned)z2 < (unsigned)DD) ? 0xFFFFFFFFu : 0u;
    }
    u32 ym[3];
    #pragma unroll
    for (int dyi = 0; dyi < 3; ++dyi) {
        const int y2 = y0 + wave + dyi - 1;
        ym[dyi] = ((unsigned)y2 < (unsigned)HH) ? 0xFFFFFFFFu : 0u;
    }

    constexpr int NQ = PL * 6 * 18 * 4;      // 16B quarters to stage per ch
    constexpr int KQ = (NQ + 255) / 256;

    const bf16* bp = wtb + (long)nlo * 32 + quad * 8;

    #pragma unroll 1
    for (int ch = 0; ch < NCH; ++ch) {
        __syncthreads();                     // previous consume done
        #pragma unroll
        for (int k = 0; k < KQ; ++k) {
            const int q = tid + k * 256;
            if (q < NQ) {
                const int qs = q & 3;
                const int f = q >> 2;
                const int vx = f % 18;
                const int rest = f / 18;
                const int r = rest % 6;
                const int lp = rest / 6;
                int zc = z0 - 1 + lp; zc = zc < 0 ? 0 : (zc >= DD ? DD - 1 : zc);
                int yc = y0 - 1 + r;  yc = yc < 0 ? 0 : (yc >= HH ? HH - 1 : yc);
                int xc = x0 - 1 + vx; xc = xc < 0 ? 0 : (xc >= WW ? WW - 1 : xc);
                const bf16* gp = src + ((long)zc * HW + (long)yc * WW + xc) * (long)SS + ch * 32 + qs * 8;
                *(uint4*)&lds[lp][r][vx][qs * 8] = *(const uint4*)gp;
            }
        }
        __syncthreads();                     // stage visible to all waves

        #pragma unroll 1
        for (int dyi = 0; dyi < 3; ++dyi) {
            if (!ym[dyi]) continue;          // wave-uniform; no barriers inside
            const int rr = wave + dyi;
            #pragma unroll
            for (int dxi = 0; dxi < 3; ++dxi) {
                union U { uint4 u; s8v v; } b[3][NT];
                #pragma unroll
                for (int dz = 0; dz < 3; ++dz)
                    #pragma unroll
                    for (int nt = 0; nt < NT; ++nt)
                        b[dz][nt].u = *(const uint4*)(bp +
                            (((long)(dz * 9 + dyi * 3 + dxi) * NCH + ch) * COUT) * 32 + nt * 512);
                const u32 sx = (dxi == 0) ? selLo : (dxi == 2 ? selHi : 0xFFFFFFFFu);
                #pragma unroll
                for (int p = 0; p < PL; ++p) {
                    union U2 { uint4 u; s8v v; } a;
                    a.u = *(const uint4*)&lds[p][rr][nlo + dxi][quad * 8];
                    const u32 mm = zm[p] & sx;
                    a.u.x &= mm; a.u.y &= mm; a.u.z &= mm; a.u.w &= mm;
                    #pragma unroll
                    for (int dz = 0; dz < 3; ++dz) {
                        const int m = p - dz;
                        if (m < 0 || m >= M) continue;   // compile-time prune
                        #pragma unroll
                        for (int nt = 0; nt < NT; ++nt)
                            acc[m][nt] = __builtin_amdgcn_mfma_f32_16x16x32_bf16(a.v, b[dz][nt].v, acc[m][nt], 0, 0, 0);
                    }
                }
            }
        }
    }

    const int yw = y0 + wave;
    #pragma unroll
    for (int m = 0; m < M; ++m) {
        const long vbase = (long)(z0 + m) * HW + (long)yw * WW + x0 + quad * 4;
        #pragma unroll
        for (int nt = 0; nt < NT; ++nt) {
            #pragma unroll
            for (int reg = 0; reg < 4; ++reg) {
                float v = acc[m][nt][reg];
                v = v >= 0.f ? v : v * slope;
                dst[(vbase + reg) * (long)dstride + dcol0 + nt * 16 + nlo] = f2bf(v);
            }
        }
    }
}

// ------- tiled small conv: Cin=16 -> Cout=3, linear, f32 out ---------------
template<int ZS>
__global__ __launch_bounds__(256, 2) void k_conv_small_t(
        const bf16* __restrict__ src, int sstride, int scol0,
        const float* __restrict__ wt, const void* __restrict__ bias,
        float* __restrict__ dst, int D, int H, int W,
        const int* __restrict__ bmodep) {
    const int bmode = *bmodep;
    __shared__ bf16 lds[ZS + 2][18][18][16];   // ZS=4: 62208 B
    const int tid = threadIdx.x;
    const int gx = W >> 4;                      // W % 16 == 0
    const int gy = (H + 15) >> 4;
    const int xyt = (int)(blockIdx.x % (u32)(gx * gy));
    const int zg  = (int)(blockIdx.x / (u32)(gx * gy));
    const int x0 = (xyt % gx) << 4;
    const int y0 = (xyt / gx) << 4;
    const int z0 = zg * ZS;

    // ---- stage (ZS+2) planes of 18x18 fragments (zeros outside volume) ----
    const int NFRAG = (ZS + 2) * 324;
    for (int f = tid; f < NFRAG; f += 256) {
        int pl = f / 324, r = f - pl * 324;
        int yy = r / 18, xx = r - yy * 18;
        int z2 = z0 - 1 + pl, y2 = y0 - 1 + yy, x2 = x0 - 1 + xx;
        uint4 lo = {0, 0, 0, 0}, hi = {0, 0, 0, 0};
        if ((unsigned)z2 < (unsigned)D && (unsigned)y2 < (unsigned)H && (unsigned)x2 < (unsigned)W) {
            const bf16* p = src + ((long)(z2 * H + y2) * W + x2) * (long)sstride + scol0;
            lo = *(const uint4*)p;
            hi = *(const uint4*)(p + 8);
        }
        *(uint4*)&lds[pl][yy][xx][0] = lo;
        *(uint4*)&lds[pl][yy][xx][8] = hi;
    }
    __syncthreads();

    const int ty = tid >> 4, tx = tid & 15;
    const bool live = (y0 + ty) < H;

    float a0[ZS], a1[ZS], a2[ZS];
    {
        float b0 = gld(bias, 0, bmode), b1 = gld(bias, 1, bmode), b2 = gld(bias, 2, bmode);
        #pragma unroll
        for (int zz = 0; zz < ZS; ++zz) { a0[zz] = b0; a1[zz] = b1; a2[zz] = b2; }
    }

    #pragma unroll 1
    for (int tap = 0; tap < 27; ++tap) {
        const int dz = tap / 9, dy = (tap / 3) % 3, dx = tap % 3;
        const float* w = wt + tap * 48;          // uniform -> scalar loads
        float wv[48];
        #pragma unroll
        for (int k = 0; k < 48; ++k) wv[k] = w[k];
        #pragma unroll
        for (int zz = 0; zz < ZS; ++zz) {
            union { uint4 u[2]; bf16 h[16]; } fr;
            fr.u[0] = *(const uint4*)&lds[zz + dz][ty + dy][tx + dx][0];
            fr.u[1] = *(const uint4*)&lds[zz + dz][ty + dy][tx + dx][8];
            #pragma unroll
            for (int c = 0; c < 16; ++c) {
                float f = bf2f(fr.h[c]);
                a0[zz] += f * wv[c * 3];
                a1[zz] += f * wv[c * 3 + 1];
                a2[zz] += f * wv[c * 3 + 2];
            }
        }
    }

    if (!live) return;
    #pragma unroll
    for (int zz = 0; zz < ZS; ++zz) {
        long p = ((long)(z0 + zz) * H + (y0 + ty)) * W + (x0 + tx);
        dst[p * 3]     = sf(a0[zz]);
        dst[p * 3 + 1] = sf(a1[zz]);
        dst[p * 3 + 2] = sf(a2[zz]);
    }
}

// ------- x2 upsample taps ---------------------------------------------------
__device__ __forceinline__ void up_taps(int i, int n, int& j0, int& j1, float& w0, float& w1) {
    if (i & 1) { j0 = i >> 1; j1 = j0 + 1; w0 = 0.75f; w1 = 0.25f; if (j1 >= n) { j1 = j0; w0 = 1.f; w1 = 0.f; } }
    else { j1 = i >> 1; j0 = j1 - 1; w0 = 0.25f; w1 = 0.75f; if (j0 < 0) { j0 = j1; w0 = 0.f; w1 = 1.f; } }
}

// ctx16 [NHALF][16] -> xin2 cols 59..74
__global__ void k_up_ctx(const bf16* __restrict__ in, bf16* __restrict__ xin2) {
    long p = (long)blockIdx.x * 256 + threadIdx.x;
    if (p >= NFULL) return;
    int x = (int)(p % W2c), y = (int)((p / W2c) % H2c), z = (int)(p / (W2c * H2c));
    int jz0, jz1, jy0, jy1, jx0, jx1; float wz0, wz1, wy0, wy1, wx0, wx1;
    up_taps(z, D1c, jz0, jz1, wz0, wz1);
    up_taps(y, H1c, jy0, jy1, wy0, wy1);
    up_taps(x, W1c, jx0, jx1, wx0, wx1);
    float acc[16];
    for (int c = 0; c < 16; ++c) acc[c] = 0.f;
    int jzs[2] = { jz0, jz1 }; float wzs[2] = { wz0, wz1 };
    int jys[2] = { jy0, jy1 }; float wys[2] = { wy0, wy1 };
    int jxs[2] = { jx0, jx1 }; float wxs[2] = { wx0, wx1 };
    for (int a = 0; a < 2; ++a) {
        if (wzs[a] == 0.f) continue;
        for (int b = 0; b < 2; ++b) {
            if (wys[b] == 0.f) continue;
            float wzy = wzs[a] * wys[b];
            for (int d = 0; d < 2; ++d) {
                if (wxs[d] == 0.f) continue;
                float w = wzy * wxs[d];
                long rb = ((long)(jzs[a] * H1c + jys[b]) * W1c + jxs[d]) * 16;
                for (int c = 0; c < 16; ++c) acc[c] += w * bf2f(in[cl(rb + c, NCTX16)]);
            }
        }
    }
    for (int c = 0; c < 16; ++c) xin2[cl(p * (long)S2 + 59 + c, NX2)] = f2bf(acc[c]);
}

// fused: velup = 2*up(vel1); du2 = warp(disp_up, velup) + velup; xin2 75..77
__global__ void k_warp_dispup(const void* __restrict__ dispup, const float* __restrict__ vel1,
                              float* __restrict__ du2, bf16* __restrict__ xin2,
                              const int* __restrict__ modep) {
    int mode = *modep;
    long p = (long)blockIdx.x * 256 + threadIdx.x;
    if (p >= NFULL) return;
    int x = (int)(p % W2c), y = (int)((p / W2c) % H2c), z = (int)(p / (W2c * H2c));
    int jz0, jz1, jy0, jy1, jx0, jx1; float wz0, wz1, wy0, wy1, wx0, wx1;
    up_taps(z, D1c, jz0, jz1, wz0, wz1);
    up_taps(y, H1c, jy0, jy1, wy0, wy1);
    up_taps(x, W1c, jx0, jx1, wx0, wx1);
    int jzs[2] = { jz0, jz1 }; float wzs[2] = { wz0, wz1 };
    int jys[2] = { jy0, jy1 }; float wys[2] = { wy0, wy1 };
    int jxs[2] = { jx0, jx1 }; float wxs[2] = { wx0, wx1 };
    float vu[3] = { 0.f, 0.f, 0.f };
    for (int a = 0; a < 2; ++a) {
        if (wzs[a] == 0.f) continue;
        for (int b = 0; b < 2; ++b) {
            if (wys[b] == 0.f) continue;
            float wzy = wzs[a] * wys[b];
            for (int d = 0; d < 2; ++d) {
                if (wxs[d] == 0.f) continue;
                float w = wzy * wxs[d];
                long rb = ((long)(jzs[a] * H1c + jys[b]) * W1c + jxs[d]) * 3;
                for (int c = 0; c < 3; ++c) vu[c] += w * sf(vel1[cl(rb + c, N3H)]);
            }
        }
    }
    for (int c = 0; c < 3; ++c) vu[c] = sf(vu[c] * 2.f);
    float cz = z + vu[0], cy = y + vu[1], cx = x + vu[2];
    float acc[3] = { 0.f, 0.f, 0.f };
    float z0f = floorf(cz), y0f = floorf(cy), x0f = floorf(cx);
    int z0 = (int)z0f, y0 = (int)y0f, x0 = (int)x0f;
    float fz = cz - z0f, fy = cy - y0f, fx = cx - x0f;
    for (int dz = 0; dz < 2; ++dz) {
        int zi = z0 + dz; if (zi < 0 || zi >= D2c) continue;
        float wz = dz ? fz : 1.f - fz;
        for (int dy = 0; dy < 2; ++dy) {
            int yi = y0 + dy; if (yi < 0 || yi >= H2c) continue;
            float wzy = wz * (dy ? fy : 1.f - fy);
            for (int dx = 0; dx < 2; ++dx) {
                int xi = x0 + dx; if (xi < 0 || xi >= W2c) continue;
                float w = wzy * (dx ? fx : 1.f - fx);
                long idx = (long)(zi * H2c + yi) * W2c + xi;
                for (int c = 0; c < 3; ++c) acc[c] += w * gld(dispup, cl((long)c * NFULL + idx, 3 * NFULL), mode);
            }
        }
    }
    for (int c = 0; c < 3; ++c) {
        float v = sf(acc[c] + vu[c]);
        du2[cl(p * 3 + c, N3F)] = v;
        xin2[cl(p * (long)S2 + 75 + c, NX2)] = f2bf(v);
    }
}

// robust t decode (handles bf16-stored or f32-stored scalar)
__device__ __forceinline__ float decode_t(const u16* tp) {
    u16 b0 = tp[0], b1 = tp[1];
    union { u32 i; float f; } a, b;
    a.i = ((u32)b0) << 16;
    b.i = ((u32)b1 << 16) | b0;
    float ta = a.f, tb = b.f;
    bool okA = (ta == ta) && ta >= 0.f && ta < 0.75f;
    bool okB = (tb == tb) && tb >= 0.f && tb < 0.75f;
    return okB ? tb : (okA ? ta : 0.f);
}

// vf = (warp(du2, vu2) + vu2 - disp_up) / (1 - t); out mode-dispatched
__global__ void k_final(const float* __restrict__ du2, const float* __restrict__ vu2,
                        const void* __restrict__ dispup, const u16* __restrict__ tptr,
                        void* __restrict__ out, long out_n, const int* __restrict__ modep) {
    int mode = *modep;
    long p = (long)blockIdx.x * 256 + threadIdx.x;
    if (p >= NFULL) return;
    float t = decode_t(tptr);
    float den = 1.f - t;
    if (fabsf(den) < 1e-6f) den = 1e-6f;
    float inv = 1.f / den;
    int x = (int)(p % W2c), y = (int)((p / W2c) % H2c), z = (int)(p / (W2c * H2c));
    float cz = z + sf(vu2[cl(p * 3, N3F)]);
    float cy = y + sf(vu2[cl(p * 3 + 1, N3F)]);
    float cx = x + sf(vu2[cl(p * 3 + 2, N3F)]);
    float acc[3] = { 0.f, 0.f, 0.f };
    float z0f = floorf(cz), y0f = floorf(cy), x0f = floorf(cx);
    int z0 = (int)z0f, y0 = (int)y0f, x0 = (int)x0f;
    float fz = cz - z0f, fy = cy - y0f, fx = cx - x0f;
    for (int dz = 0; dz < 2; ++dz) {
        int zi = z0 + dz; if (zi < 0 || zi >= D2c) continue;
        float wz = dz ? fz : 1.f - fz;
        for (int dy = 0; dy < 2; ++dy) {
            int yi = y0 + dy; if (yi < 0 || yi >= H2c) continue;
            float wzy = wz * (dy ? fy : 1.f - fy);
            for (int dx = 0; dx < 2; ++dx) {
                int xi = x0 + dx; if (xi < 0 || xi >= W2c) continue;
                float w = wzy * (dx ? fx : 1.f - fx);
                long rb = ((long)(zi * H2c + yi) * W2c + xi) * 3;
                for (int c = 0; c < 3; ++c) acc[c] += w * sf(du2[cl(rb + c, N3F)]);
            }
        }
    }
    for (int c = 0; c < 3; ++c) {
        float v = (acc[c] + sf(vu2[cl(p * 3 + c, N3F)]) - gld(dispup, cl((long)c * NFULL + p, 3 * NFULL), mode)) * inv;
        long oi = cl((long)c * NFULL + p, out_n);
        if (mode) ((float*)out)[oi] = sf(v);
        else      ((bf16*)out)[oi] = f2bf(v);
    }
}

static inline int cdiv(long a, long b) { return (int)((a + b - 1) / b); }

extern "C" void kernel_launch(void* const* d_in, const int* in_sizes, int n_in,
                              void* d_out, int out_size, void* d_ws, size_t ws_size,
                              hipStream_t stream) {
    const u16* t_in = (const u16*)d_in[0];
    const void* disp_up = d_in[1];
    const void* fx  = d_in[2];
    const void* fy  = d_in[3];
    const void* fxu = d_in[4];
    const void* fyu = d_in[5];
    const void* ctx = d_in[6];

    const size_t XIN1_B = (size_t)NX1 * 2;
    const size_t XIN2_B = (size_t)NX2 * 2;
    const size_t base_need = XIN1_B + XIN2_B + 2 * (size_t)GUARD;
    const size_t base_pad = (base_need + 255) & ~(size_t)255;
    const size_t vf_elems = 3UL * NFULL;

    // wtb sizes (bf16 elements): 27 * nchunk * Cout * 32
    const long WTB0 = 387072;  // 224->64, 7ch
    const long WTB1 = 373248;  // 288->48, 9ch
    const long WTB2 = 304128;  // 336->32, 11ch
    const long WTB3 = 165888;  // 368->16, 12ch
    const long WTB5 = 82944;   // 78->32, 3ch
    const long WTB6 = 55296;   // 110->16, 4ch
    const long WTB_TOT = WTB0 + WTB1 + WTB2 + WTB3 + WTB5 + WTB6; // 1,368,576

    size_t scro[11];
    {
        size_t o = 0;
        auto al = [&](size_t bytes) { size_t r = o; o = (o + bytes + 255) & ~(size_t)255; return r; };
        scro[0] = al((size_t)WTB_TOT * 2);      // WTB (bf16, mfma layout)
        scro[1] = al(2UL * 1296 * 4);           // WT f32 (two small convs)
        scro[2] = al((size_t)NCTX16 * 2);       // CTX16
        scro[3] = al((size_t)N3H * 4);          // VEL1
        scro[4] = al((size_t)N3H * 4);          // DISPH
        scro[5] = al((size_t)N3F * 4);          // DU2
        scro[6] = al((size_t)N3F * 4);          // VU2
        scro[7] = al(4UL * RG * 2 * 8);         // partials
        scro[8] = al(16 * 8);                   // RED
        scro[9] = al(32 * 4);                   // MODES
        scro[10] = o;
    }
    const size_t scratch_need = scro[10];
    const size_t tail_avail = ((size_t)out_size > vf_elems) ? ((size_t)out_size - vf_elems) * 2 : 0;

    char* scr = nullptr;
    if (ws_size >= base_pad + scratch_need) {
        scr = (char*)d_ws + base_pad;
    } else if (ws_size >= base_need && tail_avail >= scratch_need) {
        scr = (char*)d_out + vf_elems * 2;
    }
    if (scr == nullptr) {
        k_fill<<<2048, 256, 0, stream>>>((u16*)d_out, (long)out_size, 0x49A0);
        return;
    }

    char* ws = (char*)d_ws;
    bf16*  xin1  = (bf16*)(ws + GUARD);
    bf16*  xin2  = (bf16*)(ws + GUARD + XIN1_B);
    bf16*  wtball = (bf16*)(scr + scro[0]);
    float* wtf   = (float*)(scr + scro[1]);
    bf16*  ctx16 = (bf16*)(scr + scro[2]);
    float* vel1  = (float*)(scr + scro[3]);
    float* disph = (float*)(scr + scro[4]);
    float* du2   = (float*)(scr + scro[5]);
    float* vu2   = (float*)(scr + scro[6]);
    double* part = (double*)(scr + scro[7]);
    double* red  = (double*)(scr + scro[8]);
    int*   modes = (int*)(scr + scro[9]);
    double* pA = part;
    double* pB = part + RG * 2;
    double* pC = part + RG * 4;
    double* pD = part + RG * 6;

    bf16* wtb0 = wtball;
    bf16* wtb1 = wtb0 + WTB0;
    bf16* wtb2 = wtb1 + WTB1;
    bf16* wtb3 = wtb2 + WTB2;
    bf16* wtb5 = wtb3 + WTB3;
    bf16* wtb6 = wtb5 + WTB5;
    float* wt4 = wtf;
    float* wt7 = wtf + 1296;

    // fxu channel-last f32 copy reuses xin1's memory (dead after fl1 conv3):
    // NFULL*16*4 = 47.2MB <= XIN1_B = 67.8MB
    float* fxucl = (float*)xin1;

    // zero-init big buffers and scratch (modes default 0 = bf16)
    k_fill<<<4096, 256, 0, stream>>>((u16*)ws, (long)(base_need / 2), 0);
    k_fill<<<4096, 256, 0, stream>>>((u16*)scr, (long)(scratch_need / 2), 0);

    // dtype detection for all tensor inputs
    for (int i = 1; i < 23 && i < n_in; ++i) {
        k_detect<<<1, 256, 0, stream>>>(d_in[i], (long)in_sizes[i], modes + i);
    }

    // MFMA weight repack (bf16, zero-padded K tails)
    k_wtb<<<cdiv(WTB0, 256), 256, 0, stream>>>(d_in[7],  wtb0, 224, 64, 7,  modes + 7);
    k_wtb<<<cdiv(WTB1, 256), 256, 0, stream>>>(d_in[9],  wtb1, 288, 48, 9,  modes + 9);
    k_wtb<<<cdiv(WTB2, 256), 256, 0, stream>>>(d_in[11], wtb2, 336, 32, 11, modes + 11);
    k_wtb<<<cdiv(WTB3, 256), 256, 0, stream>>>(d_in[13], wtb3, 368, 16, 12, modes + 13);
    k_wtb<<<cdiv(WTB5, 256), 256, 0, stream>>>(d_in[17], wtb5, 78,  32, 3,  modes + 17);
    k_wtb<<<cdiv(WTB6, 256), 256, 0, stream>>>(d_in[19], wtb6, 110, 16, 4,  modes + 19);
    // f32 weights for the two small convs
    k_wt<<<cdiv(1296, 256), 256, 0, stream>>>(d_in[15], wt4, 16, 3, modes + 15);
    k_wt<<<cdiv(1296, 256), 256, 0, stream>>>(d_in[21], wt7, 16, 3, modes + 21);

    k_tcl<<<cdiv(NHALF, 256), 256, 0, stream>>>(fy,  32L * NHALF, xin1, NX1, 125, 32, NHALF, S1, modes + 3);
    k_tcl<<<cdiv(NHALF, 256), 256, 0, stream>>>(ctx, 32L * NHALF, xin1, NX1, 189, 32, NHALF, S1, modes + 6);
    k_tcl<<<cdiv(NFULL, 256), 256, 0, stream>>>(fyu, 16L * NFULL, xin2, NX2, 27, 16, NFULL, S2, modes + 5);

    k_down<<<cdiv(NHALF, 256), 256, 0, stream>>>(disp_up, disph, xin1, modes + 1);

    k_warp_cf<32><<<cdiv(NHALF, 256), 256, 0, stream>>>(fx, 32L * NHALF, disph, N3H, xin1, NX1, S1, 157, D1c, H1c, W1c, modes + 2);
    k_reduce_cl<<<RG, 256, 0, stream>>>(xin1, NX1, NHALF, S1, 157, 32, pA, modes + 31);
    k_reduce_cl<<<RG, 256, 0, stream>>>(fy, 32L * NHALF, 32L * NHALF, 1, 0, 1, pB, modes + 3);
    k_stats2<<<1, 256, 0, stream>>>(pA, pB, (double)(32L * NHALF), 32.0, red);

    // LDS-tiled cost volume 1: grid = 60 xy-tiles (8x4) x 12 zgroups = 720
    k_cv1_t<<<720, 128, 0, stream>>>(xin1, red);

    // fl1 dense block — LDS-staged MFMA conv (4 rows x M=2 z-planes / block)
    k_conv_mfma<4, 7, 64, 2, S1, D1c, H1c, W1c><<<720, 256, 0, stream>>>(xin1, wtb0, d_in[8],  xin1, S1, 224, 0.02f, modes + 8);
    k_conv_mfma<3, 9, 48, 2, S1, D1c, H1c, W1c><<<720, 256, 0, stream>>>(xin1, wtb1, d_in[10], xin1, S1, 288, 0.02f, modes + 10);
    k_conv_mfma<2, 11, 32, 2, S1, D1c, H1c, W1c><<<720, 256, 0, stream>>>(xin1, wtb2, d_in[12], xin1, S1, 336, 0.02f, modes + 12);
    k_conv_mfma<1, 12, 16, 2, S1, D1c, H1c, W1c><<<720, 256, 0, stream>>>(xin1, wtb3, d_in[14], ctx16, 16, 0, 0.02f, modes + 14);
    // tiled small conv (NHALF): grid = 3x3 xy-tiles x 12 zgroups = 108
    k_conv_small_t<4><<<108, 256, 0, stream>>>(ctx16, 16, 0, wt4, d_in[16], vel1, D1c, H1c, W1c, modes + 16);

    // xin1 is now dead -> transpose fxu into its memory as [NFULL][16] f32
    k_tclf<<<cdiv(NFULL, 256), 256, 0, stream>>>(fxu, fxucl, 16, NFULL, modes + 4);

    k_up_ctx<<<cdiv(NFULL, 256), 256, 0, stream>>>(ctx16, xin2);
    k_warp_dispup<<<cdiv(NFULL, 256), 256, 0, stream>>>(disp_up, vel1, du2, xin2, modes + 1);

    // vectorized warp from the dense channel-last f32 copy
    k_warp_cl16<<<cdiv(NFULL, 256), 256, 0, stream>>>(fxucl, du2, xin2);
    k_reduce_cl<<<RG, 256, 0, stream>>>(xin2, NX2, NFULL, S2, 43, 16, pC, modes + 31);
    k_reduce_cl<<<RG, 256, 0, stream>>>(fyu, 16L * NFULL, 16L * NFULL, 1, 0, 1, pD, modes + 5);
    k_stats2<<<1, 256, 0, stream>>>(pC, pD, (double)(16L * NFULL), 16.0, red + 2);

    // LDS-tiled cost volume 2: grid = 30 xy-tiles (16x16) x 24 zgroups = 720
    k_cv2_t<<<720, 256, 0, stream>>>(xin2, red);

    // fl2 block — LDS-staged MFMA conv (4 rows x M=4 z-planes / block)
    k_conv_mfma<2, 3, 32, 4, S2, D2c, H2c, W2c><<<2880, 256, 0, stream>>>(xin2, wtb5, d_in[18], xin2, S2, 78,  0.02f, modes + 18);
    k_conv_mfma<1, 4, 16, 4, S2, D2c, H2c, W2c><<<2880, 256, 0, stream>>>(xin2, wtb6, d_in[20], xin2, S2, 110, 0.02f, modes + 20);
    // tiled small conv (NFULL): grid = 6x5 xy-tiles x 24 zgroups = 720
    k_conv_small_t<4><<<720, 256, 0, stream>>>(xin2, S2, 110, wt7, d_in[22], vu2, D2c, H2c, W2c, modes + 22);

    // out dtype follows disp_up's detected mode
    k_final<<<cdiv(NFULL, 256), 256, 0, stream>>>(du2, vu2, disp_up, t_in, d_out, (long)out_size, modes + 1);
    k_fill_tail<<<2048, 256, 0, stream>>>(d_out, (long)vf_elems, (long)out_size, modes + 1);
}

// Round 10
// 2370.754 us; speedup vs baseline: 1.5207x; 1.0583x over previous
//
#include <hip/hip_runtime.h>
#include <hip/hip_bf16.h>

typedef __hip_bfloat16 bf16;
typedef unsigned short u16;
typedef unsigned int u32;

#define D1c 48
#define H1c 40
#define W1c 48
#define NHALF 92160L
#define D2c 96
#define H2c 80
#define W2c 96
#define NFULL 737280L
#define S1 368
#define S2 128
#define RG 512

#define NX1 (NHALF * S1)
#define NX2 (NFULL * S2)
#define NCTX16 (NHALF * 16)
#define N3H (NHALF * 3)
#define N3F (NFULL * 3)
#define GUARD 1024

typedef __attribute__((ext_vector_type(8))) short s8v;
typedef __attribute__((ext_vector_type(4))) float f4v;

__device__ __forceinline__ float bf2f(bf16 v){ return __bfloat162float(v); }
__device__ __forceinline__ float sf(float v){ return (v == v && fabsf(v) < 1e30f) ? v : 0.f; }
__device__ __forceinline__ bf16 f2bf(float v){ return __float2bfloat16(sf(v)); }
__device__ __forceinline__ u16 f2bfu(float v){ bf16 b = f2bf(v); return *(u16*)&b; }
__device__ __forceinline__ long cl(long i, long n){ i = i < 0 ? 0 : i; return i >= n ? n - 1 : i; }
// mode-dispatched input load: 0 = bf16, 1 = f32
__device__ __forceinline__ float gld(const void* p, long i, int mode){
    return mode ? sf(((const float*)p)[i]) : sf(bf2f(((const bf16*)p)[i]));
}

// ---------------- dtype detection: one block per input ---------------------
__global__ void k_detect(const void* p, long nelem, int* flag) {
    long N = nelem < 4096 ? nelem : 4096;
    int tid = threadIdx.x;
    int nb = 0, nf = 0;
    for (long i = tid; i < N; i += 256) {
        float v = bf2f(((const bf16*)p)[i]);
        if (v == v && fabsf(v) <= 1e4f) nb++;
    }
    long M = N / 2;
    for (long i = tid; i < M; i += 256) {
        float v = ((const float*)p)[i];
        if (v == v && fabsf(v) <= 1e4f) nf += 2;
    }
    __shared__ int sb[256], sq[256];
    sb[tid] = nb; sq[tid] = nf;
    __syncthreads();
    for (int t = 128; t; t >>= 1) {
        if (tid < t) { sb[tid] += sb[tid + t]; sq[tid] += sq[tid + t]; }
        __syncthreads();
    }
    if (tid == 0) *flag = (sb[0] >= sq[0]) ? 0 : 1;
}

// ---------------- fills -----------------------------------------------------
__global__ void k_fill(u16* __restrict__ p, long n, u16 val) {
    long i = (long)blockIdx.x * 256 + threadIdx.x;
    long stride = (long)gridDim.x * 256;
    for (; i < n; i += stride) p[i] = val;
}
__global__ void k_fill_tail(void* out, long vf, long out_n, const int* __restrict__ modep) {
    int mode = *modep;
    long n = out_n - vf;
    if (n <= 0) return;
    long i = (long)blockIdx.x * 256 + threadIdx.x;
    long stride = (long)gridDim.x * 256;
    if (mode) { float* p = (float*)out + vf; for (; i < n; i += stride) p[i] = 0.f; }
    else      { u16*   p = (u16*)out + vf;   for (; i < n; i += stride) p[i] = 0; }
}

// ------- weight transpose: (co,ci,tap) -> (tap,ci,co) f32 (small convs) ----
__global__ void k_wt(const void* __restrict__ w, float* __restrict__ wt,
                     int Cin, int Cout, const int* __restrict__ modep) {
    int mode = *modep;
    long n = (long)Cin * Cout * 27;
    long i = (long)blockIdx.x * 256 + threadIdx.x;
    if (i >= n) return;
    int tap = (int)(i % 27); long r = i / 27;
    int ci = (int)(r % Cin); int co = (int)(r / Cin);
    wt[cl(((long)tap * Cin + ci) * Cout + co, n)] = gld(w, cl(i, n), mode);
}

// ------- MFMA weight repack: (co,ci,tap) -> [tap][chunk][co][32] bf16 ------
// zero-padded for ci >= Cin (Cin tails)
__global__ void k_wtb(const void* __restrict__ w, bf16* __restrict__ wtb,
                      int Cin, int Cout, int nchunk, const int* __restrict__ modep) {
    int mode = *modep;
    long n = 27L * nchunk * Cout * 32;
    long i = (long)blockIdx.x * 256 + threadIdx.x;
    if (i >= n) return;
    int kk = (int)(i & 31);
    long r = i >> 5;
    int co = (int)(r % Cout); r /= Cout;
    int ch = (int)(r % nchunk); int tap = (int)(r / nchunk);
    int ci = ch * 32 + kk;
    float v = (ci < Cin) ? gld(w, ((long)co * Cin + ci) * 27 + tap, mode) : 0.f;
    wtb[i] = f2bf(v);
}

// ------- channel-first [C][N] -> channel-last columns, LDS-transposed ------
// Round-10: the old per-thread scalar writes (16 consecutive u16 in a 256B-
// strided row) caused 16x write amplification (372MB vs 23.6MB useful --
// each lane's 2B store hit a distinct line -> full 32B sector writeback).
// Stage results in LDS, then sweep row*C+col linearly so consecutive LANES
// write consecutive bytes (wave-coalesced 32B chunks, ~1x writes).
// Requires N % 256 == 0 (true: NHALF=360*256, NFULL=2880*256).
template<int C>
__global__ __launch_bounds__(256) void k_tcl_t(const void* __restrict__ in,
                                               u16* __restrict__ out, long nout,
                                               int col0, long N, int stride,
                                               const int* __restrict__ modep) {
    __shared__ u16 lds[256 * C];
    const int mode = *modep;
    const int tid = threadIdx.x;
    const long n0 = (long)blockIdx.x * 256;
    #pragma unroll
    for (int c = 0; c < C; ++c)
        lds[tid * C + c] = f2bfu(gld(in, (long)c * N + n0 + tid, mode));
    __syncthreads();
    #pragma unroll
    for (int k = 0; k < C; ++k) {
        const int e = tid + k * 256;
        const int row = e / C, col = e - row * C;
        out[cl((n0 + row) * (long)stride + col0 + col, nout)] = lds[e];
    }
}

// ------- channel-first [C][N] -> dense channel-last f32 [N][C] -------------
// (coalesced per-channel reads; preserves f32 values exactly for the warp)
__global__ void k_tclf(const void* __restrict__ in, float* __restrict__ out,
                       int C, long N, const int* __restrict__ modep) {
    int mode = *modep;
    long n = (long)blockIdx.x * 256 + threadIdx.x;
    if (n >= N) return;
    for (int c = 0; c < C; ++c)
        out[n * C + c] = gld(in, (long)c * N + n, mode);
}

// ------- antialiased x0.5 downsample taps ----------------------------------
__device__ __forceinline__ void down_taps(int i, int n_in, int j[4], float w[4]) {
    float s = 0.f;
    for (int k = 0; k < 4; ++k) {
        int jj = 2 * i - 1 + k;
        bool valid = (jj >= 0 && jj < n_in);
        j[k] = valid ? jj : 0;
        float b = (k == 0 || k == 3) ? 1.f : 3.f;
        w[k] = valid ? b : 0.f;
        s += w[k];
    }
    float inv = 1.f / fmaxf(s, 1e-6f);
    for (int k = 0; k < 4; ++k) w[k] *= inv;
}

// disp = resize(disp_up,0.5)*0.5 -> disph f32 + xin1 cols 221..223
__global__ void k_down(const void* __restrict__ dispup, float* __restrict__ disph,
                       bf16* __restrict__ xin1, const int* __restrict__ modep) {
    int mode = *modep;
    long p = (long)blockIdx.x * 256 + threadIdx.x;
    if (p >= NHALF) return;
    int x = (int)(p % W1c), y = (int)((p / W1c) % H1c), z = (int)(p / (W1c * H1c));
    int jz[4], jy[4], jx[4]; float wz[4], wy[4], wx[4];
    down_taps(z, D2c, jz, wz); down_taps(y, H2c, jy, wy); down_taps(x, W2c, jx, wx);
    for (int c = 0; c < 3; ++c) {
        float acc = 0.f;
        for (int a = 0; a < 4; ++a) {
            if (wz[a] == 0.f) continue;
            for (int b = 0; b < 4; ++b) {
                if (wy[b] == 0.f) continue;
                float wzy = wz[a] * wy[b];
                long base = (long)c * NFULL + ((long)jz[a] * H2c + jy[b]) * W2c;
                for (int d = 0; d < 4; ++d) {
                    if (wx[d] == 0.f) continue;
                    acc += wzy * wx[d] * gld(dispup, cl(base + jx[d], 3 * NFULL), mode);
                }
            }
        }
        acc = sf(acc * 0.5f);
        disph[cl(p * 3 + c, N3H)] = acc;
        xin1[cl(p * (long)S1 + 221 + c, NX1)] = f2bf(acc);
    }
}

// ------- trilinear warp, channel-first INPUT volume, zero pad --------------
// LDS-transposed write phase (round-10). Requires N % 256 == 0.
template<int C>
__global__ __launch_bounds__(256) void k_warp_cf(
        const void* __restrict__ vol, long nvol,
        const float* __restrict__ coords, long ncoords,
        u16* __restrict__ dst, long ndst, int dstride, int col0,
        int D, int H, int W, const int* __restrict__ modep) {
    __shared__ u16 lw[256 * C];
    int mode = *modep;
    const long p0 = (long)blockIdx.x * 256;
    const long p = p0 + threadIdx.x;
    int x = (int)(p % W), y = (int)((p / W) % H), z = (int)(p / ((long)W * H));
    float cz = z + sf(coords[cl(p * 3, ncoords)]);
    float cy = y + sf(coords[cl(p * 3 + 1, ncoords)]);
    float cx = x + sf(coords[cl(p * 3 + 2, ncoords)]);
    const long N = (long)D * H * W;
    float acc[C];
    for (int c = 0; c < C; ++c) acc[c] = 0.f;
    float z0f = floorf(cz), y0f = floorf(cy), x0f = floorf(cx);
    int z0 = (int)z0f, y0 = (int)y0f, x0 = (int)x0f;
    float fz = cz - z0f, fy = cy - y0f, fx = cx - x0f;
    for (int dz = 0; dz < 2; ++dz) {
        int zi = z0 + dz; if (zi < 0 || zi >= D) continue;
        float wz = dz ? fz : 1.f - fz;
        for (int dy = 0; dy < 2; ++dy) {
            int yi = y0 + dy; if (yi < 0 || yi >= H) continue;
            float wzy = wz * (dy ? fy : 1.f - fy);
            for (int dx = 0; dx < 2; ++dx) {
                int xi = x0 + dx; if (xi < 0 || xi >= W) continue;
                float w = wzy * (dx ? fx : 1.f - fx);
                long idx = (long)(zi * H + yi) * W + xi;
                for (int c = 0; c < C; ++c) acc[c] += w * gld(vol, cl((long)c * N + idx, nvol), mode);
            }
        }
    }
    #pragma unroll
    for (int c = 0; c < C; ++c) lw[threadIdx.x * C + c] = f2bfu(acc[c]);
    __syncthreads();
    #pragma unroll
    for (int k = 0; k < C; ++k) {
        const int e = threadIdx.x + k * 256;
        const int row = e / C, col = e - row * C;
        dst[cl((p0 + row) * (long)dstride + col0 + col, ndst)] = lw[e];
    }
}

// ------- trilinear warp, dense channel-last f32 source (C=16) --------------
// Round-9 read fix (channel-last f32, float4 corner loads) + round-10
// LDS-transposed coalesced writes.
__global__ __launch_bounds__(256) void k_warp_cl16(const float* __restrict__ vol,
                                                   const float* __restrict__ coords,
                                                   u16* __restrict__ dst) {
    __shared__ u16 lw[256 * 16];
    const long p0 = (long)blockIdx.x * 256;
    const long p = p0 + threadIdx.x;
    int x = (int)(p % W2c), y = (int)((p / W2c) % H2c), z = (int)(p / (W2c * H2c));
    float cz = z + sf(coords[p * 3]);
    float cy = y + sf(coords[p * 3 + 1]);
    float cx = x + sf(coords[p * 3 + 2]);
    float acc[16];
    #pragma unroll
    for (int c = 0; c < 16; ++c) acc[c] = 0.f;
    float z0f = floorf(cz), y0f = floorf(cy), x0f = floorf(cx);
    int z0 = (int)z0f, y0 = (int)y0f, x0 = (int)x0f;
    float fz = cz - z0f, fy = cy - y0f, fx = cx - x0f;
    for (int dz = 0; dz < 2; ++dz) {
        int zi = z0 + dz; if (zi < 0 || zi >= D2c) continue;
        float wz = dz ? fz : 1.f - fz;
        for (int dy = 0; dy < 2; ++dy) {
            int yi = y0 + dy; if (yi < 0 || yi >= H2c) continue;
            float wzy = wz * (dy ? fy : 1.f - fy);
            for (int dx = 0; dx < 2; ++dx) {
                int xi = x0 + dx; if (xi < 0 || xi >= W2c) continue;
                float w = wzy * (dx ? fx : 1.f - fx);
                const float4* q = (const float4*)(vol + ((long)(zi * H2c + yi) * W2c + xi) * 16);
                float4 a0 = q[0], a1 = q[1], a2 = q[2], a3 = q[3];
                acc[0]  += w * a0.x; acc[1]  += w * a0.y; acc[2]  += w * a0.z; acc[3]  += w * a0.w;
                acc[4]  += w * a1.x; acc[5]  += w * a1.y; acc[6]  += w * a1.z; acc[7]  += w * a1.w;
                acc[8]  += w * a2.x; acc[9]  += w * a2.y; acc[10] += w * a2.z; acc[11] += w * a2.w;
                acc[12] += w * a3.x; acc[13] += w * a3.y; acc[14] += w * a3.z; acc[15] += w * a3.w;
            }
        }
    }
    #pragma unroll
    for (int c = 0; c < 16; ++c) lw[threadIdx.x * 16 + c] = f2bfu(acc[c]);
    __syncthreads();
    #pragma unroll
    for (int k = 0; k < 16; ++k) {
        const int e = threadIdx.x + k * 256;
        const int row = e >> 4, col = e & 15;
        dst[(p0 + row) * (long)S2 + 43 + col] = lw[e];
    }
}

// ------- two-stage deterministic reduction (sum, sumsq) --------------------
__global__ void k_reduce_cl(const void* __restrict__ base, long nbase, long rows,
                            int stride, int col0, int cn, double* __restrict__ part,
                            const int* __restrict__ modep) {
    int mode = *modep;
    long total = rows * cn;
    double s = 0.0, q = 0.0;
    long i = (long)blockIdx.x * 256 + threadIdx.x;
    long gs = (long)gridDim.x * 256;
    for (; i < total; i += gs) {
        long r = i / cn; int c = (int)(i - r * cn);
        float f = gld(base, cl(r * (long)stride + col0 + c, nbase), mode);
        s += f; q += (double)f * f;
    }
    __shared__ double ls[256], lq[256];
    ls[threadIdx.x] = s; lq[threadIdx.x] = q;
    __syncthreads();
    for (int t = 128; t; t >>= 1) {
        if (threadIdx.x < t) { ls[threadIdx.x] += ls[threadIdx.x + t]; lq[threadIdx.x] += lq[threadIdx.x + t]; }
        __syncthreads();
    }
    if (threadIdx.x == 0) { part[cl(blockIdx.x * 2, RG * 2)] = ls[0]; part[cl(blockIdx.x * 2 + 1, RG * 2)] = lq[0]; }
}

__global__ void k_stats2(const double* __restrict__ pa, const double* __restrict__ pb,
                         double n, double C, double* __restrict__ outm) {
    __shared__ double ls[256], lq[256];
    double s = 0.0, q = 0.0;
    for (int i = threadIdx.x; i < RG; i += 256) { s += pa[i * 2]; q += pa[i * 2 + 1]; }
    ls[threadIdx.x] = s; lq[threadIdx.x] = q;
    __syncthreads();
    for (int t = 128; t; t >>= 1) {
        if (threadIdx.x < t) { ls[threadIdx.x] += ls[threadIdx.x + t]; lq[threadIdx.x] += lq[threadIdx.x + t]; }
        __syncthreads();
    }
    double sa = ls[0], qa = lq[0];
    __syncthreads();
    s = 0.0; q = 0.0;
    for (int i = threadIdx.x; i < RG; i += 256) { s += pb[i * 2]; q += pb[i * 2 + 1]; }
    ls[threadIdx.x] = s; lq[threadIdx.x] = q;
    __syncthreads();
    for (int t = 128; t; t >>= 1) {
        if (threadIdx.x < t) { ls[threadIdx.x] += ls[threadIdx.x + t]; lq[threadIdx.x] += lq[threadIdx.x + t]; }
        __syncthreads();
    }
    if (threadIdx.x == 0) {
        double sb = ls[0], qb = lq[0];
        double va = (qa - sa * sa / n) / (n - 1.0);
        double vb = (qb - sb * sb / n) / (n - 1.0);
        va = va > 0.0 ? va : 0.0;
        vb = vb > 0.0 ? vb : 0.0;
        double sd = 0.5 * (sqrt(va) + sqrt(vb));
        sd = sd < 1e-6 ? 1e-6 : (sd > 1e9 ? 1e9 : sd);
        outm[0] = 0.5 * (sa / n + sb / n);
        outm[1] = 1.0 / (sd * sd * C);
    }
}

// ------- cost volume 1 (md=2, C=32), LDS-tiled -> xin1 cols 0..124 ---------
__global__ __launch_bounds__(128, 2) void k_cv1_t(bf16* __restrict__ xin1,
                                                  const double* __restrict__ red) {
    __shared__ bf16 lds[8][8][12][32];   // [plane z0-2..z0+5][row y0-2..y0+5][x0-2..x0+9][ch]
    const int tid = threadIdx.x;
    const int xyt = (int)(blockIdx.x % 60u);     // 6 x-tiles * 10 y-tiles
    const int zg  = (int)(blockIdx.x / 60u);     // 12 z-groups
    const int x0 = (xyt % 6) * 8;
    const int y0 = (xyt / 6) * 4;
    const int z0 = zg * 4;
    const u16* src16 = (const u16*)xin1;

    for (int f = tid; f < 8 * 8 * 12; f += 128) {
        int xx = f % 12, rest = f / 12;
        int yy = rest % 8, pl = rest / 8;
        int z2 = z0 - 2 + pl, y2 = y0 - 2 + yy, x2 = x0 - 2 + xx;
        u32 pk[16];
        #pragma unroll
        for (int c = 0; c < 16; ++c) pk[c] = 0;
        if ((unsigned)z2 < (unsigned)D1c && (unsigned)y2 < (unsigned)H1c && (unsigned)x2 < (unsigned)W1c) {
            long rb = (((long)z2 * H1c + y2) * W1c + x2) * S1 + 157;
            #pragma unroll
            for (int c = 0; c < 16; ++c)
                pk[c] = (u32)src16[rb + 2 * c] | ((u32)src16[rb + 2 * c + 1] << 16);
        }
        #pragma unroll
        for (int qq = 0; qq < 4; ++qq) {
            uint4 q = { pk[qq * 4], pk[qq * 4 + 1], pk[qq * 4 + 2], pk[qq * 4 + 3] };
            *(uint4*)&lds[pl][yy][xx][qq * 8] = q;
        }
    }
    __syncthreads();

    const float m = sf((float)red[0]), mult = sf((float)red[1]);
    const int tx = tid & 7, ty = (tid >> 3) & 3, tz = tid >> 5;
    const int x = x0 + tx, y = y0 + ty, z = z0 + tz;
    const long p = ((long)z * H1c + y) * W1c + x;

    float fm[32], S = 0.f;
    #pragma unroll
    for (int c = 0; c < 32; ++c) { fm[c] = sf(bf2f(xin1[p * (long)S1 + 125 + c])) - m; S += fm[c]; }

    #pragma unroll 1
    for (int dz = 0; dz < 5; ++dz) {
        const int z2 = z + dz - 2;
        u16 hg[25];
        #pragma unroll
        for (int oo = 0; oo < 25; ++oo) {
            const int dy = oo / 5, dx = oo % 5;
            const int y2 = y + dy - 2, x2 = x + dx - 2;
            float cost = 0.f;
            if ((unsigned)z2 < (unsigned)D1c && (unsigned)y2 < (unsigned)H1c && (unsigned)x2 < (unsigned)W1c) {
                union { uint4 u[4]; bf16 h[32]; } wv;
                #pragma unroll
                for (int qq = 0; qq < 4; ++qq)
                    wv.u[qq] = *(const uint4*)&lds[tz + dz][ty + dy][tx + dx][qq * 8];
                float dot = 0.f;
                #pragma unroll
                for (int c = 0; c < 32; ++c) dot += fm[c] * sf(bf2f(wv.h[c]));
                dot -= m * S;
                cost = dot * mult;
                cost = cost >= 0.f ? cost : 0.05f * cost;
            }
            hg[oo] = f2bfu(cost);
        }
        u16* dstp = (u16*)(xin1 + p * (long)S1) + dz * 25;
        #pragma unroll
        for (int oo = 0; oo < 25; ++oo) dstp[oo] = hg[oo];
    }
}

// ------- cost volume 2 (md=1, C=16), LDS-tiled -> xin2 cols 0..26 ----------
__global__ __launch_bounds__(256, 2) void k_cv2_t(bf16* __restrict__ xin2,
                                                  const double* __restrict__ red) {
    __shared__ bf16 lds[6][18][18][16];
    const int tid = threadIdx.x;
    const int xyt = (int)(blockIdx.x % 30u);     // 6 x-tiles * 5 y-tiles
    const int zg  = (int)(blockIdx.x / 30u);     // 24 z-groups
    const int x0 = (xyt % 6) * 16;
    const int y0 = (xyt / 6) * 16;
    const int z0 = zg * 4;
    const u16* src16 = (const u16*)xin2;

    for (int f = tid; f < 6 * 324; f += 256) {
        int pl = f / 324, r = f - pl * 324;
        int yy = r / 18, xx = r - yy * 18;
        int z2 = z0 - 1 + pl, y2 = y0 - 1 + yy, x2 = x0 - 1 + xx;
        u32 pk[8];
        #pragma unroll
        for (int c = 0; c < 8; ++c) pk[c] = 0;
        if ((unsigned)z2 < (unsigned)D2c && (unsigned)y2 < (unsigned)H2c && (unsigned)x2 < (unsigned)W2c) {
            long rb = (((long)z2 * H2c + y2) * W2c + x2) * S2 + 43;
            #pragma unroll
            for (int c = 0; c < 8; ++c)
                pk[c] = (u32)src16[rb + 2 * c] | ((u32)src16[rb + 2 * c + 1] << 16);
        }
        uint4 q0 = { pk[0], pk[1], pk[2], pk[3] };
        uint4 q1 = { pk[4], pk[5], pk[6], pk[7] };
        *(uint4*)&lds[pl][yy][xx][0] = q0;
        *(uint4*)&lds[pl][yy][xx][8] = q1;
    }
    __syncthreads();

    const float m = sf((float)red[2]), mult = sf((float)red[3]);
    const int tx = tid & 15, ty = tid >> 4;
    const int x = x0 + tx, y = y0 + ty;

    #pragma unroll 1
    for (int zz = 0; zz < 4; ++zz) {
        const int z = z0 + zz;
        const long p = ((long)z * H2c + y) * W2c + x;
        float fm[16], S = 0.f;
        #pragma unroll
        for (int c = 0; c < 16; ++c) {
            fm[c] = sf(bf2f(xin2[p * (long)S2 + 27 + c])) - m;
            S += fm[c];
        }
        union { u16 h[28]; uint4 q[3]; u32 w[14]; } r;
        #pragma unroll
        for (int o = 0; o < 27; ++o) {
            const int dz = o / 9, dy = (o / 3) % 3, dx = o % 3;
            const int z2 = z + dz - 1, y2 = y + dy - 1, x2 = x + dx - 1;
            float cost = 0.f;
            if ((unsigned)z2 < (unsigned)D2c && (unsigned)y2 < (unsigned)H2c && (unsigned)x2 < (unsigned)W2c) {
                union { uint4 u[2]; bf16 h[16]; } wv;
                wv.u[0] = *(const uint4*)&lds[zz + dz][ty + dy][tx + dx][0];
                wv.u[1] = *(const uint4*)&lds[zz + dz][ty + dy][tx + dx][8];
                float dot = 0.f;
                #pragma unroll
                for (int c = 0; c < 16; ++c) dot += fm[c] * sf(bf2f(wv.h[c]));
                dot -= m * S;
                cost = dot * mult;
                cost = cost >= 0.f ? cost : 0.05f * cost;
            }
            r.h[o] = f2bfu(cost);
        }
        r.h[27] = 0;
        u16* dstp = (u16*)(xin2 + p * (long)S2);
        *(uint4*)dstp        = r.q[0];
        *(uint4*)(dstp + 8)  = r.q[1];
        *(uint4*)(dstp + 16) = r.q[2];
        *(u32*)(dstp + 24)   = r.w[12];
        dstp[26] = r.h[26];
    }
}

// ------- MFMA implicit-GEMM 3x3x3 conv, channel-last, LDS-staged -----------
template<int NT, int NCH, int COUT, int M, int SS, int DD, int HH, int WW>
__global__ __launch_bounds__(256, 2) void k_conv_mfma(
        const bf16* __restrict__ src,
        const bf16* __restrict__ wtb, const void* __restrict__ bias,
        bf16* __restrict__ dst, int dstride, int dcol0,
        float slope, const int* __restrict__ bmodep) {
    const int bmode = *bmodep;
    const int tid = threadIdx.x;
    const int wave = tid >> 6, lane = tid & 63;
    const int quad = lane >> 4, nlo = lane & 15;
    constexpr long HW = (long)HH * WW;
    constexpr int PL = M + 2;            // staged planes
    constexpr int NXB = WW / 16;
    constexpr int NYB = HH / 4;          // 4 rows per block (one per wave)
    constexpr int NXY = NXB * NYB;
    __shared__ bf16 lds[PL][6][18][32];  // M=4: 41472 B, M=2: 27648 B

    // bijective chunked swizzle (gridDim.x % 8 == 0 by construction)
    const u32 per = gridDim.x >> 3;
    const u32 bid = (blockIdx.x & 7u) * per + (blockIdx.x >> 3);
    const int xyb = (int)(bid % (u32)NXY);
    const int zg  = (int)(bid / (u32)NXY);
    const int x0 = (xyb % NXB) * 16;
    const int y0 = (xyb / NXB) * 4;
    const int z0 = zg * M;

    f4v acc[M][NT];
    #pragma unroll
    for (int m = 0; m < M; ++m) {
        #pragma unroll
        for (int nt = 0; nt < NT; ++nt) {
            float bv = gld(bias, nt * 16 + nlo, bmode);
            acc[m][nt][0] = bv; acc[m][nt][1] = bv; acc[m][nt][2] = bv; acc[m][nt][3] = bv;
        }
    }

    const u32 selLo = (x0 == 0       && nlo == 0)  ? 0u : 0xFFFFFFFFu;
    const u32 selHi = (x0 == WW - 16 && nlo == 15) ? 0u : 0xFFFFFFFFu;

    u32 zm[PL];
    #pragma unroll
    for (int p = 0; p < PL; ++p) {
        const int z2 = z0 - 1 + p;
        zm[p] = ((unsigned)z2 < (unsigned)DD) ? 0xFFFFFFFFu : 0u;
    }
    u32 ym[3];
    #pragma unroll
    for (int dyi = 0; dyi < 3; ++dyi) {
        const int y2 = y0 + wave + dyi - 1;
        ym[dyi] = ((unsigned)y2 < (unsigned)HH) ? 0xFFFFFFFFu : 0u;
    }

    constexpr int NQ = PL * 6 * 18 * 4;      // 16B quarters to stage per ch
    constexpr int KQ = (NQ + 255) / 256;

    const bf16* bp = wtb + (long)nlo * 32 + quad * 8;

    #pragma unroll 1
    for (int ch = 0; ch < NCH; ++ch) {
        __syncthreads();                     // previous consume done
        #pragma unroll
        for (int k = 0; k < KQ; ++k) {
            const int q = tid + k * 256;
            if (q < NQ) {
                const int qs = q & 3;
                const int f = q >> 2;
                const int vx = f % 18;
                const int rest = f / 18;
                const int r = rest % 6;
                const int lp = rest / 6;
                int zc = z0 - 1 + lp; zc = zc < 0 ? 0 : (zc >= DD ? DD - 1 : zc);
                int yc = y0 - 1 + r;  yc = yc < 0 ? 0 : (yc >= HH ? HH - 1 : yc);
                int xc = x0 - 1 + vx; xc = xc < 0 ? 0 : (xc >= WW ? WW - 1 : xc);
                const bf16* gp = src + ((long)zc * HW + (long)yc * WW + xc) * (long)SS + ch * 32 + qs * 8;
                *(uint4*)&lds[lp][r][vx][qs * 8] = *(const uint4*)gp;
            }
        }
        __syncthreads();                     // stage visible to all waves

        #pragma unroll 1
        for (int dyi = 0; dyi < 3; ++dyi) {
            if (!ym[dyi]) continue;          // wave-uniform; no barriers inside
            const int rr = wave + dyi;
            #pragma unroll
            for (int dxi = 0; dxi < 3; ++dxi) {
                union U { uint4 u; s8v v; } b[3][NT];
                #pragma unroll
                for (int dz = 0; dz < 3; ++dz)
                    #pragma unroll
                    for (int nt = 0; nt < NT; ++nt)
                        b[dz][nt].u = *(const uint4*)(bp +
                            (((long)(dz * 9 + dyi * 3 + dxi) * NCH + ch) * COUT) * 32 + nt * 512);
                const u32 sx = (dxi == 0) ? selLo : (dxi == 2 ? selHi : 0xFFFFFFFFu);
                #pragma unroll
                for (int p = 0; p < PL; ++p) {
                    union U2 { uint4 u; s8v v; } a;
                    a.u = *(const uint4*)&lds[p][rr][nlo + dxi][quad * 8];
                    const u32 mm = zm[p] & sx;
                    a.u.x &= mm; a.u.y &= mm; a.u.z &= mm; a.u.w &= mm;
                    #pragma unroll
                    for (int dz = 0; dz < 3; ++dz) {
                        const int m = p - dz;
                        if (m < 0 || m >= M) continue;   // compile-time prune
                        #pragma unroll
                        for (int nt = 0; nt < NT; ++nt)
                            acc[m][nt] = __builtin_amdgcn_mfma_f32_16x16x32_bf16(a.v, b[dz][nt].v, acc[m][nt], 0, 0, 0);
                    }
                }
            }
        }
    }

    const int yw = y0 + wave;
    #pragma unroll
    for (int m = 0; m < M; ++m) {
        const long vbase = (long)(z0 + m) * HW + (long)yw * WW + x0 + quad * 4;
        #pragma unroll
        for (int nt = 0; nt < NT; ++nt) {
            #pragma unroll
            for (int reg = 0; reg < 4; ++reg) {
                float v = acc[m][nt][reg];
                v = v >= 0.f ? v : v * slope;
                dst[(vbase + reg) * (long)dstride + dcol0 + nt * 16 + nlo] = f2bf(v);
            }
        }
    }
}

// ------- tiled small conv: Cin=16 -> Cout=3, linear, f32 out ---------------
template<int ZS>
__global__ __launch_bounds__(256, 2) void k_conv_small_t(
        const bf16* __restrict__ src, int sstride, int scol0,
        const float* __restrict__ wt, const void* __restrict__ bias,
        float* __restrict__ dst, int D, int H, int W,
        const int* __restrict__ bmodep) {
    const int bmode = *bmodep;
    __shared__ bf16 lds[ZS + 2][18][18][16];   // ZS=4: 62208 B
    const int tid = threadIdx.x;
    const int gx = W >> 4;                      // W % 16 == 0
    const int gy = (H + 15) >> 4;
    const int xyt = (int)(blockIdx.x % (u32)(gx * gy));
    const int zg  = (int)(blockIdx.x / (u32)(gx * gy));
    const int x0 = (xyt % gx) << 4;
    const int y0 = (xyt / gx) << 4;
    const int z0 = zg * ZS;

    // ---- stage (ZS+2) planes of 18x18 fragments (zeros outside volume) ----
    const int NFRAG = (ZS + 2) * 324;
    for (int f = tid; f < NFRAG; f += 256) {
        int pl = f / 324, r = f - pl * 324;
        int yy = r / 18, xx = r - yy * 18;
        int z2 = z0 - 1 + pl, y2 = y0 - 1 + yy, x2 = x0 - 1 + xx;
        uint4 lo = {0, 0, 0, 0}, hi = {0, 0, 0, 0};
        if ((unsigned)z2 < (unsigned)D && (unsigned)y2 < (unsigned)H && (unsigned)x2 < (unsigned)W) {
            const bf16* p = src + ((long)(z2 * H + y2) * W + x2) * (long)sstride + scol0;
            lo = *(const uint4*)p;
            hi = *(const uint4*)(p + 8);
        }
        *(uint4*)&lds[pl][yy][xx][0] = lo;
        *(uint4*)&lds[pl][yy][xx][8] = hi;
    }
    __syncthreads();

    const int ty = tid >> 4, tx = tid & 15;
    const bool live = (y0 + ty) < H;

    float a0[ZS], a1[ZS], a2[ZS];
    {
        float b0 = gld(bias, 0, bmode), b1 = gld(bias, 1, bmode), b2 = gld(bias, 2, bmode);
        #pragma unroll
        for (int zz = 0; zz < ZS; ++zz) { a0[zz] = b0; a1[zz] = b1; a2[zz] = b2; }
    }

    #pragma unroll 1
    for (int tap = 0; tap < 27; ++tap) {
        const int dz = tap / 9, dy = (tap / 3) % 3, dx = tap % 3;
        const float* w = wt + tap * 48;          // uniform -> scalar loads
        float wv[48];
        #pragma unroll
        for (int k = 0; k < 48; ++k) wv[k] = w[k];
        #pragma unroll
        for (int zz = 0; zz < ZS; ++zz) {
            union { uint4 u[2]; bf16 h[16]; } fr;
            fr.u[0] = *(const uint4*)&lds[zz + dz][ty + dy][tx + dx][0];
            fr.u[1] = *(const uint4*)&lds[zz + dz][ty + dy][tx + dx][8];
            #pragma unroll
            for (int c = 0; c < 16; ++c) {
                float f = bf2f(fr.h[c]);
                a0[zz] += f * wv[c * 3];
                a1[zz] += f * wv[c * 3 + 1];
                a2[zz] += f * wv[c * 3 + 2];
            }
        }
    }

    if (!live) return;
    #pragma unroll
    for (int zz = 0; zz < ZS; ++zz) {
        long p = ((long)(z0 + zz) * H + (y0 + ty)) * W + (x0 + tx);
        dst[p * 3]     = sf(a0[zz]);
        dst[p * 3 + 1] = sf(a1[zz]);
        dst[p * 3 + 2] = sf(a2[zz]);
    }
}

// ------- x2 upsample taps ---------------------------------------------------
__device__ __forceinline__ void up_taps(int i, int n, int& j0, int& j1, float& w0, float& w1) {
    if (i & 1) { j0 = i >> 1; j1 = j0 + 1; w0 = 0.75f; w1 = 0.25f; if (j1 >= n) { j1 = j0; w0 = 1.f; w1 = 0.f; } }
    else { j1 = i >> 1; j0 = j1 - 1; w0 = 0.25f; w1 = 0.75f; if (j0 < 0) { j0 = j1; w0 = 0.f; w1 = 1.f; } }
}

// ctx16 [NHALF][16] -> xin2 cols 59..74 (LDS-transposed coalesced writes)
__global__ __launch_bounds__(256) void k_up_ctx(const bf16* __restrict__ in,
                                                u16* __restrict__ xin2) {
    __shared__ u16 lw[256 * 16];
    const long p0 = (long)blockIdx.x * 256;
    const long p = p0 + threadIdx.x;
    int x = (int)(p % W2c), y = (int)((p / W2c) % H2c), z = (int)(p / (W2c * H2c));
    int jz0, jz1, jy0, jy1, jx0, jx1; float wz0, wz1, wy0, wy1, wx0, wx1;
    up_taps(z, D1c, jz0, jz1, wz0, wz1);
    up_taps(y, H1c, jy0, jy1, wy0, wy1);
    up_taps(x, W1c, jx0, jx1, wx0, wx1);
    float acc[16];
    for (int c = 0; c < 16; ++c) acc[c] = 0.f;
    int jzs[2] = { jz0, jz1 }; float wzs[2] = { wz0, wz1 };
    int jys[2] = { jy0, jy1 }; float wys[2] = { wy0, wy1 };
    int jxs[2] = { jx0, jx1 }; float wxs[2] = { wx0, wx1 };
    for (int a = 0; a < 2; ++a) {
        if (wzs[a] == 0.f) continue;
        for (int b = 0; b < 2; ++b) {
            if (wys[b] == 0.f) continue;
            float wzy = wzs[a] * wys[b];
            for (int d = 0; d < 2; ++d) {
                if (wxs[d] == 0.f) continue;
                float w = wzy * wxs[d];
                long rb = ((long)(jzs[a] * H1c + jys[b]) * W1c + jxs[d]) * 16;
                for (int c = 0; c < 16; ++c) acc[c] += w * bf2f(in[cl(rb + c, NCTX16)]);
            }
        }
    }
    #pragma unroll
    for (int c = 0; c < 16; ++c) lw[threadIdx.x * 16 + c] = f2bfu(acc[c]);
    __syncthreads();
    #pragma unroll
    for (int k = 0; k < 16; ++k) {
        const int e = threadIdx.x + k * 256;
        const int row = e >> 4, col = e & 15;
        xin2[(p0 + row) * (long)S2 + 59 + col] = lw[e];
    }
}

// fused: velup = 2*up(vel1); du2 = warp(disp_up, velup) + velup; xin2 75..77
__global__ void k_warp_dispup(const void* __restrict__ dispup, const float* __restrict__ vel1,
                              float* __restrict__ du2, bf16* __restrict__ xin2,
                              const int* __restrict__ modep) {
    int mode = *modep;
    long p = (long)blockIdx.x * 256 + threadIdx.x;
    if (p >= NFULL) return;
    int x = (int)(p % W2c), y = (int)((p / W2c) % H2c), z = (int)(p / (W2c * H2c));
    int jz0, jz1, jy0, jy1, jx0, jx1; float wz0, wz1, wy0, wy1, wx0, wx1;
    up_taps(z, D1c, jz0, jz1, wz0, wz1);
    up_taps(y, H1c, jy0, jy1, wy0, wy1);
    up_taps(x, W1c, jx0, jx1, wx0, wx1);
    int jzs[2] = { jz0, jz1 }; float wzs[2] = { wz0, wz1 };
    int jys[2] = { jy0, jy1 }; float wys[2] = { wy0, wy1 };
    int jxs[2] = { jx0, jx1 }; float wxs[2] = { wx0, wx1 };
    float vu[3] = { 0.f, 0.f, 0.f };
    for (int a = 0; a < 2; ++a) {
        if (wzs[a] == 0.f) continue;
        for (int b = 0; b < 2; ++b) {
            if (wys[b] == 0.f) continue;
            float wzy = wzs[a] * wys[b];
            for (int d = 0; d < 2; ++d) {
                if (wxs[d] == 0.f) continue;
                float w = wzy * wxs[d];
                long rb = ((long)(jzs[a] * H1c + jys[b]) * W1c + jxs[d]) * 3;
                for (int c = 0; c < 3; ++c) vu[c] += w * sf(vel1[cl(rb + c, N3H)]);
            }
        }
    }
    for (int c = 0; c < 3; ++c) vu[c] = sf(vu[c] * 2.f);
    float cz = z + vu[0], cy = y + vu[1], cx = x + vu[2];
    float acc[3] = { 0.f, 0.f, 0.f };
    float z0f = floorf(cz), y0f = floorf(cy), x0f = floorf(cx);
    int z0 = (int)z0f, y0 = (int)y0f, x0 = (int)x0f;
    float fz = cz - z0f, fy = cy - y0f, fx = cx - x0f;
    for (int dz = 0; dz < 2; ++dz) {
        int zi = z0 + dz; if (zi < 0 || zi >= D2c) continue;
        float wz = dz ? fz : 1.f - fz;
        for (int dy = 0; dy < 2; ++dy) {
            int yi = y0 + dy; if (yi < 0 || yi >= H2c) continue;
            float wzy = wz * (dy ? fy : 1.f - fy);
            for (int dx = 0; dx < 2; ++dx) {
                int xi = x0 + dx; if (xi < 0 || xi >= W2c) continue;
                float w = wzy * (dx ? fx : 1.f - fx);
                long idx = (long)(zi * H2c + yi) * W2c + xi;
                for (int c = 0; c < 3; ++c) acc[c] += w * gld(dispup, cl((long)c * NFULL + idx, 3 * NFULL), mode);
            }
        }
    }
    for (int c = 0; c < 3; ++c) {
        float v = sf(acc[c] + vu[c]);
        du2[cl(p * 3 + c, N3F)] = v;
        xin2[cl(p * (long)S2 + 75 + c, NX2)] = f2bf(v);
    }
}

// robust t decode (handles bf16-stored or f32-stored scalar)
__device__ __forceinline__ float decode_t(const u16* tp) {
    u16 b0 = tp[0], b1 = tp[1];
    union { u32 i; float f; } a, b;
    a.i = ((u32)b0) << 16;
    b.i = ((u32)b1 << 16) | b0;
    float ta = a.f, tb = b.f;
    bool okA = (ta == ta) && ta >= 0.f && ta < 0.75f;
    bool okB = (tb == tb) && tb >= 0.f && tb < 0.75f;
    return okB ? tb : (okA ? ta : 0.f);
}

// vf = (warp(du2, vu2) + vu2 - disp_up) / (1 - t); out mode-dispatched
__global__ void k_final(const float* __restrict__ du2, const float* __restrict__ vu2,
                        const void* __restrict__ dispup, const u16* __restrict__ tptr,
                        void* __restrict__ out, long out_n, const int* __restrict__ modep) {
    int mode = *modep;
    long p = (long)blockIdx.x * 256 + threadIdx.x;
    if (p >= NFULL) return;
    float t = decode_t(tptr);
    float den = 1.f - t;
    if (fabsf(den) < 1e-6f) den = 1e-6f;
    float inv = 1.f / den;
    int x = (int)(p % W2c), y = (int)((p / W2c) % H2c), z = (int)(p / (W2c * H2c));
    float cz = z + sf(vu2[cl(p * 3, N3F)]);
    float cy = y + sf(vu2[cl(p * 3 + 1, N3F)]);
    float cx = x + sf(vu2[cl(p * 3 + 2, N3F)]);
    float acc[3] = { 0.f, 0.f, 0.f };
    float z0f = floorf(cz), y0f = floorf(cy), x0f = floorf(cx);
    int z0 = (int)z0f, y0 = (int)y0f, x0 = (int)x0f;
    float fz = cz - z0f, fy = cy - y0f, fx = cx - x0f;
    for (int dz = 0; dz < 2; ++dz) {
        int zi = z0 + dz; if (zi < 0 || zi >= D2c) continue;
        float wz = dz ? fz : 1.f - fz;
        for (int dy = 0; dy < 2; ++dy) {
            int yi = y0 + dy; if (yi < 0 || yi >= H2c) continue;
            float wzy = wz * (dy ? fy : 1.f - fy);
            for (int dx = 0; dx < 2; ++dx) {
                int xi = x0 + dx; if (xi < 0 || xi >= W2c) continue;
                float w = wzy * (dx ? fx : 1.f - fx);
                long rb = ((long)(zi * H2c + yi) * W2c + xi) * 3;
                for (int c = 0; c < 3; ++c) acc[c] += w * sf(du2[cl(rb + c, N3F)]);
            }
        }
    }
    for (int c = 0; c < 3; ++c) {
        float v = (acc[c] + sf(vu2[cl(p * 3 + c, N3F)]) - gld(dispup, cl((long)c * NFULL + p, 3 * NFULL), mode)) * inv;
        long oi = cl((long)c * NFULL + p, out_n);
        if (mode) ((float*)out)[oi] = sf(v);
        else      ((bf16*)out)[oi] = f2bf(v);
    }
}

static inline int cdiv(long a, long b) { return (int)((a + b - 1) / b); }

extern "C" void kernel_launch(void* const* d_in, const int* in_sizes, int n_in,
                              void* d_out, int out_size, void* d_ws, size_t ws_size,
                              hipStream_t stream) {
    const u16* t_in = (const u16*)d_in[0];
    const void* disp_up = d_in[1];
    const void* fx  = d_in[2];
    const void* fy  = d_in[3];
    const void* fxu = d_in[4];
    const void* fyu = d_in[5];
    const void* ctx = d_in[6];

    const size_t XIN1_B = (size_t)NX1 * 2;
    const size_t XIN2_B = (size_t)NX2 * 2;
    const size_t base_need = XIN1_B + XIN2_B + 2 * (size_t)GUARD;
    const size_t base_pad = (base_need + 255) & ~(size_t)255;
    const size_t vf_elems = 3UL * NFULL;

    // wtb sizes (bf16 elements): 27 * nchunk * Cout * 32
    const long WTB0 = 387072;  // 224->64, 7ch
    const long WTB1 = 373248;  // 288->48, 9ch
    const long WTB2 = 304128;  // 336->32, 11ch
    const long WTB3 = 165888;  // 368->16, 12ch
    const long WTB5 = 82944;   // 78->32, 3ch
    const long WTB6 = 55296;   // 110->16, 4ch
    const long WTB_TOT = WTB0 + WTB1 + WTB2 + WTB3 + WTB5 + WTB6; // 1,368,576

    size_t scro[11];
    {
        size_t o = 0;
        auto al = [&](size_t bytes) { size_t r = o; o = (o + bytes + 255) & ~(size_t)255; return r; };
        scro[0] = al((size_t)WTB_TOT * 2);      // WTB (bf16, mfma layout)
        scro[1] = al(2UL * 1296 * 4);           // WT f32 (two small convs)
        scro[2] = al((size_t)NCTX16 * 2);       // CTX16
        scro[3] = al((size_t)N3H * 4);          // VEL1
        scro[4] = al((size_t)N3H * 4);          // DISPH
        scro[5] = al((size_t)N3F * 4);          // DU2
        scro[6] = al((size_t)N3F * 4);          // VU2
        scro[7] = al(4UL * RG * 2 * 8);         // partials
        scro[8] = al(16 * 8);                   // RED
        scro[9] = al(32 * 4);                   // MODES
        scro[10] = o;
    }
    const size_t scratch_need = scro[10];
    const size_t tail_avail = ((size_t)out_size > vf_elems) ? ((size_t)out_size - vf_elems) * 2 : 0;

    char* scr = nullptr;
    if (ws_size >= base_pad + scratch_need) {
        scr = (char*)d_ws + base_pad;
    } else if (ws_size >= base_need && tail_avail >= scratch_need) {
        scr = (char*)d_out + vf_elems * 2;
    }
    if (scr == nullptr) {
        k_fill<<<2048, 256, 0, stream>>>((u16*)d_out, (long)out_size, 0x49A0);
        return;
    }

    char* ws = (char*)d_ws;
    bf16*  xin1  = (bf16*)(ws + GUARD);
    bf16*  xin2  = (bf16*)(ws + GUARD + XIN1_B);
    bf16*  wtball = (bf16*)(scr + scro[0]);
    float* wtf   = (float*)(scr + scro[1]);
    bf16*  ctx16 = (bf16*)(scr + scro[2]);
    float* vel1  = (float*)(scr + scro[3]);
    float* disph = (float*)(scr + scro[4]);
    float* du2   = (float*)(scr + scro[5]);
    float* vu2   = (float*)(scr + scro[6]);
    double* part = (double*)(scr + scro[7]);
    double* red  = (double*)(scr + scro[8]);
    int*   modes = (int*)(scr + scro[9]);
    double* pA = part;
    double* pB = part + RG * 2;
    double* pC = part + RG * 4;
    double* pD = part + RG * 6;

    bf16* wtb0 = wtball;
    bf16* wtb1 = wtb0 + WTB0;
    bf16* wtb2 = wtb1 + WTB1;
    bf16* wtb3 = wtb2 + WTB2;
    bf16* wtb5 = wtb3 + WTB3;
    bf16* wtb6 = wtb5 + WTB5;
    float* wt4 = wtf;
    float* wt7 = wtf + 1296;

    // fxu channel-last f32 copy reuses xin1's memory (dead after fl1 conv3):
    // NFULL*16*4 = 47.2MB <= XIN1_B = 67.8MB
    float* fxucl = (float*)xin1;

    // zero-init big buffers and scratch (modes default 0 = bf16)
    k_fill<<<4096, 256, 0, stream>>>((u16*)ws, (long)(base_need / 2), 0);
    k_fill<<<4096, 256, 0, stream>>>((u16*)scr, (long)(scratch_need / 2), 0);

    // dtype detection for all tensor inputs
    for (int i = 1; i < 23 && i < n_in; ++i) {
        k_detect<<<1, 256, 0, stream>>>(d_in[i], (long)in_sizes[i], modes + i);
    }

    // MFMA weight repack (bf16, zero-padded K tails)
    k_wtb<<<cdiv(WTB0, 256), 256, 0, stream>>>(d_in[7],  wtb0, 224, 64, 7,  modes + 7);
    k_wtb<<<cdiv(WTB1, 256), 256, 0, stream>>>(d_in[9],  wtb1, 288, 48, 9,  modes + 9);
    k_wtb<<<cdiv(WTB2, 256), 256, 0, stream>>>(d_in[11], wtb2, 336, 32, 11, modes + 11);
    k_wtb<<<cdiv(WTB3, 256), 256, 0, stream>>>(d_in[13], wtb3, 368, 16, 12, modes + 13);
    k_wtb<<<cdiv(WTB5, 256), 256, 0, stream>>>(d_in[17], wtb5, 78,  32, 3,  modes + 17);
    k_wtb<<<cdiv(WTB6, 256), 256, 0, stream>>>(d_in[19], wtb6, 110, 16, 4,  modes + 19);
    // f32 weights for the two small convs
    k_wt<<<cdiv(1296, 256), 256, 0, stream>>>(d_in[15], wt4, 16, 3, modes + 15);
    k_wt<<<cdiv(1296, 256), 256, 0, stream>>>(d_in[21], wt7, 16, 3, modes + 21);

    // channel-last transposes with coalesced (LDS-staged) writes
    k_tcl_t<32><<<360, 256, 0, stream>>>(fy,  (u16*)xin1, NX1, 125, NHALF, S1, modes + 3);
    k_tcl_t<32><<<360, 256, 0, stream>>>(ctx, (u16*)xin1, NX1, 189, NHALF, S1, modes + 6);
    k_tcl_t<16><<<2880, 256, 0, stream>>>(fyu, (u16*)xin2, NX2, 27, NFULL, S2, modes + 5);

    k_down<<<cdiv(NHALF, 256), 256, 0, stream>>>(disp_up, disph, xin1, modes + 1);

    k_warp_cf<32><<<360, 256, 0, stream>>>(fx, 32L * NHALF, disph, N3H, (u16*)xin1, NX1, S1, 157, D1c, H1c, W1c, modes + 2);
    k_reduce_cl<<<RG, 256, 0, stream>>>(xin1, NX1, NHALF, S1, 157, 32, pA, modes + 31);
    k_reduce_cl<<<RG, 256, 0, stream>>>(fy, 32L * NHALF, 32L * NHALF, 1, 0, 1, pB, modes + 3);
    k_stats2<<<1, 256, 0, stream>>>(pA, pB, (double)(32L * NHALF), 32.0, red);

    // LDS-tiled cost volume 1: grid = 60 xy-tiles (8x4) x 12 zgroups = 720
    k_cv1_t<<<720, 128, 0, stream>>>(xin1, red);

    // fl1 dense block — LDS-staged MFMA conv (4 rows x M=2 z-planes / block)
    k_conv_mfma<4, 7, 64, 2, S1, D1c, H1c, W1c><<<720, 256, 0, stream>>>(xin1, wtb0, d_in[8],  xin1, S1, 224, 0.02f, modes + 8);
    k_conv_mfma<3, 9, 48, 2, S1, D1c, H1c, W1c><<<720, 256, 0, stream>>>(xin1, wtb1, d_in[10], xin1, S1, 288, 0.02f, modes + 10);
    k_conv_mfma<2, 11, 32, 2, S1, D1c, H1c, W1c><<<720, 256, 0, stream>>>(xin1, wtb2, d_in[12], xin1, S1, 336, 0.02f, modes + 12);
    k_conv_mfma<1, 12, 16, 2, S1, D1c, H1c, W1c><<<720, 256, 0, stream>>>(xin1, wtb3, d_in[14], ctx16, 16, 0, 0.02f, modes + 14);
    // tiled small conv (NHALF): grid = 3x3 xy-tiles x 12 zgroups = 108
    k_conv_small_t<4><<<108, 256, 0, stream>>>(ctx16, 16, 0, wt4, d_in[16], vel1, D1c, H1c, W1c, modes + 16);

    // xin1 is now dead -> transpose fxu into its memory as [NFULL][16] f32
    k_tclf<<<cdiv(NFULL, 256), 256, 0, stream>>>(fxu, fxucl, 16, NFULL, modes + 4);

    k_up_ctx<<<2880, 256, 0, stream>>>(ctx16, (u16*)xin2);
    k_warp_dispup<<<cdiv(NFULL, 256), 256, 0, stream>>>(disp_up, vel1, du2, xin2, modes + 1);

    // vectorized warp from the dense channel-last f32 copy
    k_warp_cl16<<<2880, 256, 0, stream>>>(fxucl, du2, (u16*)xin2);
    k_reduce_cl<<<RG, 256, 0, stream>>>(xin2, NX2, NFULL, S2, 43, 16, pC, modes + 31);
    k_reduce_cl<<<RG, 256, 0, stream>>>(fyu, 16L * NFULL, 16L * NFULL, 1, 0, 1, pD, modes + 5);
    k_stats2<<<1, 256, 0, stream>>>(pC, pD, (double)(16L * NFULL), 16.0, red + 2);

    // LDS-tiled cost volume 2: grid = 30 xy-tiles (16x16) x 24 zgroups = 720
    k_cv2_t<<<720, 256, 0, stream>>>(xin2, red);

    // fl2 block — LDS-staged MFMA conv (4 rows x M=4 z-planes / block)
    k_conv_mfma<2, 3, 32, 4, S2, D2c, H2c, W2c><<<2880, 256, 0, stream>>>(xin2, wtb5, d_in[18], xin2, S2, 78,  0.02f, modes + 18);
    k_conv_mfma<1, 4, 16, 4, S2, D2c, H2c, W2c><<<2880, 256, 0, stream>>>(xin2, wtb6, d_in[20], xin2, S2, 110, 0.02f, modes + 20);
    // tiled small conv (NFULL): grid = 6x5 xy-tiles x 24 zgroups = 720
    k_conv_small_t<4><<<720, 256, 0, stream>>>(xin2, S2, 110, wt7, d_in[22], vu2, D2c, H2c, W2c, modes + 22);

    // out dtype follows disp_up's detected mode
    k_final<<<cdiv(NFULL, 256), 256, 0, stream>>>(du2, vu2, disp_up, t_in, d_out, (long)out_size, modes + 1);
    k_fill_tail<<<2048, 256, 0, stream>>>(d_out, (long)vf_elems, (long)out_size, modes + 1);
}

// Round 11
// 2205.614 us; speedup vs baseline: 1.6346x; 1.0749x over previous
//
#include <hip/hip_runtime.h>
#include <hip/hip_bf16.h>

typedef __hip_bfloat16 bf16;
typedef unsigned short u16;
typedef unsigned int u32;

#define D1c 48
#define H1c 40
#define W1c 48
#define NHALF 92160L
#define D2c 96
#define H2c 80
#define W2c 96
#define NFULL 737280L
#define S1 368
#define S2 128
#define RG 512

#define NX1 (NHALF * S1)
#define NX2 (NFULL * S2)
#define NCTX16 (NHALF * 16)
#define N3H (NHALF * 3)
#define N3F (NFULL * 3)
#define GUARD 1024

typedef __attribute__((ext_vector_type(8))) short s8v;
typedef __attribute__((ext_vector_type(4))) float f4v;

__device__ __forceinline__ float bf2f(bf16 v){ return __bfloat162float(v); }
__device__ __forceinline__ float sf(float v){ return (v == v && fabsf(v) < 1e30f) ? v : 0.f; }
__device__ __forceinline__ bf16 f2bf(float v){ return __float2bfloat16(sf(v)); }
__device__ __forceinline__ u16 f2bfu(float v){ bf16 b = f2bf(v); return *(u16*)&b; }
__device__ __forceinline__ long cl(long i, long n){ i = i < 0 ? 0 : i; return i >= n ? n - 1 : i; }
// mode-dispatched input load: 0 = bf16, 1 = f32
__device__ __forceinline__ float gld(const void* p, long i, int mode){
    return mode ? sf(((const float*)p)[i]) : sf(bf2f(((const bf16*)p)[i]));
}

// ---------------- dtype detection: one block per input ---------------------
__global__ void k_detect(const void* p, long nelem, int* flag) {
    long N = nelem < 4096 ? nelem : 4096;
    int tid = threadIdx.x;
    int nb = 0, nf = 0;
    for (long i = tid; i < N; i += 256) {
        float v = bf2f(((const bf16*)p)[i]);
        if (v == v && fabsf(v) <= 1e4f) nb++;
    }
    long M = N / 2;
    for (long i = tid; i < M; i += 256) {
        float v = ((const float*)p)[i];
        if (v == v && fabsf(v) <= 1e4f) nf += 2;
    }
    __shared__ int sb[256], sq[256];
    sb[tid] = nb; sq[tid] = nf;
    __syncthreads();
    for (int t = 128; t; t >>= 1) {
        if (tid < t) { sb[tid] += sb[tid + t]; sq[tid] += sq[tid + t]; }
        __syncthreads();
    }
    if (tid == 0) *flag = (sb[0] >= sq[0]) ? 0 : 1;
}

// ---------------- fills -----------------------------------------------------
__global__ void k_fill(u16* __restrict__ p, long n, u16 val) {
    long i = (long)blockIdx.x * 256 + threadIdx.x;
    long stride = (long)gridDim.x * 256;
    for (; i < n; i += stride) p[i] = val;
}
__global__ void k_fill_tail(void* out, long vf, long out_n, const int* __restrict__ modep) {
    int mode = *modep;
    long n = out_n - vf;
    if (n <= 0) return;
    long i = (long)blockIdx.x * 256 + threadIdx.x;
    long stride = (long)gridDim.x * 256;
    if (mode) { float* p = (float*)out + vf; for (; i < n; i += stride) p[i] = 0.f; }
    else      { u16*   p = (u16*)out + vf;   for (; i < n; i += stride) p[i] = 0; }
}

// ------- weight transpose: (co,ci,tap) -> (tap,ci,co) f32 (small convs) ----
__global__ void k_wt(const void* __restrict__ w, float* __restrict__ wt,
                     int Cin, int Cout, const int* __restrict__ modep) {
    int mode = *modep;
    long n = (long)Cin * Cout * 27;
    long i = (long)blockIdx.x * 256 + threadIdx.x;
    if (i >= n) return;
    int tap = (int)(i % 27); long r = i / 27;
    int ci = (int)(r % Cin); int co = (int)(r / Cin);
    wt[cl(((long)tap * Cin + ci) * Cout + co, n)] = gld(w, cl(i, n), mode);
}

// ------- MFMA weight repack: (co,ci,tap) -> [tap][chunk][co][32] bf16 ------
// zero-padded for ci >= Cin (Cin tails)
__global__ void k_wtb(const void* __restrict__ w, bf16* __restrict__ wtb,
                      int Cin, int Cout, int nchunk, const int* __restrict__ modep) {
    int mode = *modep;
    long n = 27L * nchunk * Cout * 32;
    long i = (long)blockIdx.x * 256 + threadIdx.x;
    if (i >= n) return;
    int kk = (int)(i & 31);
    long r = i >> 5;
    int co = (int)(r % Cout); r /= Cout;
    int ch = (int)(r % nchunk); int tap = (int)(r / nchunk);
    int ci = ch * 32 + kk;
    float v = (ci < Cin) ? gld(w, ((long)co * Cin + ci) * 27 + tap, mode) : 0.f;
    wtb[i] = f2bf(v);
}

// ------- channel-first [C][N] -> channel-last columns, LDS-transposed ------
template<int C>
__global__ __launch_bounds__(256) void k_tcl_t(const void* __restrict__ in,
                                               u16* __restrict__ out, long nout,
                                               int col0, long N, int stride,
                                               const int* __restrict__ modep) {
    __shared__ u16 lds[256 * C];
    const int mode = *modep;
    const int tid = threadIdx.x;
    const long n0 = (long)blockIdx.x * 256;
    #pragma unroll
    for (int c = 0; c < C; ++c)
        lds[tid * C + c] = f2bfu(gld(in, (long)c * N + n0 + tid, mode));
    __syncthreads();
    #pragma unroll
    for (int k = 0; k < C; ++k) {
        const int e = tid + k * 256;
        const int row = e / C, col = e - row * C;
        out[cl((n0 + row) * (long)stride + col0 + col, nout)] = lds[e];
    }
}

// ------- channel-first [C][N] -> dense channel-last f32 [N][C] -------------
__global__ void k_tclf(const void* __restrict__ in, float* __restrict__ out,
                       int C, long N, const int* __restrict__ modep) {
    int mode = *modep;
    long n = (long)blockIdx.x * 256 + threadIdx.x;
    if (n >= N) return;
    for (int c = 0; c < C; ++c)
        out[n * C + c] = gld(in, (long)c * N + n, mode);
}

// ------- antialiased x0.5 downsample taps ----------------------------------
__device__ __forceinline__ void down_taps(int i, int n_in, int j[4], float w[4]) {
    float s = 0.f;
    for (int k = 0; k < 4; ++k) {
        int jj = 2 * i - 1 + k;
        bool valid = (jj >= 0 && jj < n_in);
        j[k] = valid ? jj : 0;
        float b = (k == 0 || k == 3) ? 1.f : 3.f;
        w[k] = valid ? b : 0.f;
        s += w[k];
    }
    float inv = 1.f / fmaxf(s, 1e-6f);
    for (int k = 0; k < 4; ++k) w[k] *= inv;
}

// disp = resize(disp_up,0.5)*0.5 -> disph f32 + xin1 cols 221..223
__global__ void k_down(const void* __restrict__ dispup, float* __restrict__ disph,
                       bf16* __restrict__ xin1, const int* __restrict__ modep) {
    int mode = *modep;
    long p = (long)blockIdx.x * 256 + threadIdx.x;
    if (p >= NHALF) return;
    int x = (int)(p % W1c), y = (int)((p / W1c) % H1c), z = (int)(p / (W1c * H1c));
    int jz[4], jy[4], jx[4]; float wz[4], wy[4], wx[4];
    down_taps(z, D2c, jz, wz); down_taps(y, H2c, jy, wy); down_taps(x, W2c, jx, wx);
    for (int c = 0; c < 3; ++c) {
        float acc = 0.f;
        for (int a = 0; a < 4; ++a) {
            if (wz[a] == 0.f) continue;
            for (int b = 0; b < 4; ++b) {
                if (wy[b] == 0.f) continue;
                float wzy = wz[a] * wy[b];
                long base = (long)c * NFULL + ((long)jz[a] * H2c + jy[b]) * W2c;
                for (int d = 0; d < 4; ++d) {
                    if (wx[d] == 0.f) continue;
                    acc += wzy * wx[d] * gld(dispup, cl(base + jx[d], 3 * NFULL), mode);
                }
            }
        }
        acc = sf(acc * 0.5f);
        disph[cl(p * 3 + c, N3H)] = acc;
        xin1[cl(p * (long)S1 + 221 + c, NX1)] = f2bf(acc);
    }
}

// ------- trilinear warp, channel-first INPUT volume, zero pad --------------
// LDS-transposed write phase (round-10). Requires N % 256 == 0.
template<int C>
__global__ __launch_bounds__(256) void k_warp_cf(
        const void* __restrict__ vol, long nvol,
        const float* __restrict__ coords, long ncoords,
        u16* __restrict__ dst, long ndst, int dstride, int col0,
        int D, int H, int W, const int* __restrict__ modep) {
    __shared__ u16 lw[256 * C];
    int mode = *modep;
    const long p0 = (long)blockIdx.x * 256;
    const long p = p0 + threadIdx.x;
    int x = (int)(p % W), y = (int)((p / W) % H), z = (int)(p / ((long)W * H));
    float cz = z + sf(coords[cl(p * 3, ncoords)]);
    float cy = y + sf(coords[cl(p * 3 + 1, ncoords)]);
    float cx = x + sf(coords[cl(p * 3 + 2, ncoords)]);
    const long N = (long)D * H * W;
    float acc[C];
    for (int c = 0; c < C; ++c) acc[c] = 0.f;
    float z0f = floorf(cz), y0f = floorf(cy), x0f = floorf(cx);
    int z0 = (int)z0f, y0 = (int)y0f, x0 = (int)x0f;
    float fz = cz - z0f, fy = cy - y0f, fx = cx - x0f;
    for (int dz = 0; dz < 2; ++dz) {
        int zi = z0 + dz; if (zi < 0 || zi >= D) continue;
        float wz = dz ? fz : 1.f - fz;
        for (int dy = 0; dy < 2; ++dy) {
            int yi = y0 + dy; if (yi < 0 || yi >= H) continue;
            float wzy = wz * (dy ? fy : 1.f - fy);
            for (int dx = 0; dx < 2; ++dx) {
                int xi = x0 + dx; if (xi < 0 || xi >= W) continue;
                float w = wzy * (dx ? fx : 1.f - fx);
                long idx = (long)(zi * H + yi) * W + xi;
                for (int c = 0; c < C; ++c) acc[c] += w * gld(vol, cl((long)c * N + idx, nvol), mode);
            }
        }
    }
    #pragma unroll
    for (int c = 0; c < C; ++c) lw[threadIdx.x * C + c] = f2bfu(acc[c]);
    __syncthreads();
    #pragma unroll
    for (int k = 0; k < C; ++k) {
        const int e = threadIdx.x + k * 256;
        const int row = e / C, col = e - row * C;
        dst[cl((p0 + row) * (long)dstride + col0 + col, ndst)] = lw[e];
    }
}

// ------- trilinear warp, dense channel-last f32 source (C=16) --------------
__global__ __launch_bounds__(256) void k_warp_cl16(const float* __restrict__ vol,
                                                   const float* __restrict__ coords,
                                                   u16* __restrict__ dst) {
    __shared__ u16 lw[256 * 16];
    const long p0 = (long)blockIdx.x * 256;
    const long p = p0 + threadIdx.x;
    int x = (int)(p % W2c), y = (int)((p / W2c) % H2c), z = (int)(p / (W2c * H2c));
    float cz = z + sf(coords[p * 3]);
    float cy = y + sf(coords[p * 3 + 1]);
    float cx = x + sf(coords[p * 3 + 2]);
    float acc[16];
    #pragma unroll
    for (int c = 0; c < 16; ++c) acc[c] = 0.f;
    float z0f = floorf(cz), y0f = floorf(cy), x0f = floorf(cx);
    int z0 = (int)z0f, y0 = (int)y0f, x0 = (int)x0f;
    float fz = cz - z0f, fy = cy - y0f, fx = cx - x0f;
    for (int dz = 0; dz < 2; ++dz) {
        int zi = z0 + dz; if (zi < 0 || zi >= D2c) continue;
        float wz = dz ? fz : 1.f - fz;
        for (int dy = 0; dy < 2; ++dy) {
            int yi = y0 + dy; if (yi < 0 || yi >= H2c) continue;
            float wzy = wz * (dy ? fy : 1.f - fy);
            for (int dx = 0; dx < 2; ++dx) {
                int xi = x0 + dx; if (xi < 0 || xi >= W2c) continue;
                float w = wzy * (dx ? fx : 1.f - fx);
                const float4* q = (const float4*)(vol + ((long)(zi * H2c + yi) * W2c + xi) * 16);
                float4 a0 = q[0], a1 = q[1], a2 = q[2], a3 = q[3];
                acc[0]  += w * a0.x; acc[1]  += w * a0.y; acc[2]  += w * a0.z; acc[3]  += w * a0.w;
                acc[4]  += w * a1.x; acc[5]  += w * a1.y; acc[6]  += w * a1.z; acc[7]  += w * a1.w;
                acc[8]  += w * a2.x; acc[9]  += w * a2.y; acc[10] += w * a2.z; acc[11] += w * a2.w;
                acc[12] += w * a3.x; acc[13] += w * a3.y; acc[14] += w * a3.z; acc[15] += w * a3.w;
            }
        }
    }
    #pragma unroll
    for (int c = 0; c < 16; ++c) lw[threadIdx.x * 16 + c] = f2bfu(acc[c]);
    __syncthreads();
    #pragma unroll
    for (int k = 0; k < 16; ++k) {
        const int e = threadIdx.x + k * 256;
        const int row = e >> 4, col = e & 15;
        dst[(p0 + row) * (long)S2 + 43 + col] = lw[e];
    }
}

// ------- two-stage deterministic reduction (sum, sumsq) --------------------
__global__ void k_reduce_cl(const void* __restrict__ base, long nbase, long rows,
                            int stride, int col0, int cn, double* __restrict__ part,
                            const int* __restrict__ modep) {
    int mode = *modep;
    long total = rows * cn;
    double s = 0.0, q = 0.0;
    long i = (long)blockIdx.x * 256 + threadIdx.x;
    long gs = (long)gridDim.x * 256;
    for (; i < total; i += gs) {
        long r = i / cn; int c = (int)(i - r * cn);
        float f = gld(base, cl(r * (long)stride + col0 + c, nbase), mode);
        s += f; q += (double)f * f;
    }
    __shared__ double ls[256], lq[256];
    ls[threadIdx.x] = s; lq[threadIdx.x] = q;
    __syncthreads();
    for (int t = 128; t; t >>= 1) {
        if (threadIdx.x < t) { ls[threadIdx.x] += ls[threadIdx.x + t]; lq[threadIdx.x] += lq[threadIdx.x + t]; }
        __syncthreads();
    }
    if (threadIdx.x == 0) { part[cl(blockIdx.x * 2, RG * 2)] = ls[0]; part[cl(blockIdx.x * 2 + 1, RG * 2)] = lq[0]; }
}

__global__ void k_stats2(const double* __restrict__ pa, const double* __restrict__ pb,
                         double n, double C, double* __restrict__ outm) {
    __shared__ double ls[256], lq[256];
    double s = 0.0, q = 0.0;
    for (int i = threadIdx.x; i < RG; i += 256) { s += pa[i * 2]; q += pa[i * 2 + 1]; }
    ls[threadIdx.x] = s; lq[threadIdx.x] = q;
    __syncthreads();
    for (int t = 128; t; t >>= 1) {
        if (threadIdx.x < t) { ls[threadIdx.x] += ls[threadIdx.x + t]; lq[threadIdx.x] += lq[threadIdx.x + t]; }
        __syncthreads();
    }
    double sa = ls[0], qa = lq[0];
    __syncthreads();
    s = 0.0; q = 0.0;
    for (int i = threadIdx.x; i < RG; i += 256) { s += pb[i * 2]; q += pb[i * 2 + 1]; }
    ls[threadIdx.x] = s; lq[threadIdx.x] = q;
    __syncthreads();
    for (int t = 128; t; t >>= 1) {
        if (threadIdx.x < t) { ls[threadIdx.x] += ls[threadIdx.x + t]; lq[threadIdx.x] += lq[threadIdx.x + t]; }
        __syncthreads();
    }
    if (threadIdx.x == 0) {
        double sb = ls[0], qb = lq[0];
        double va = (qa - sa * sa / n) / (n - 1.0);
        double vb = (qb - sb * sb / n) / (n - 1.0);
        va = va > 0.0 ? va : 0.0;
        vb = vb > 0.0 ? vb : 0.0;
        double sd = 0.5 * (sqrt(va) + sqrt(vb));
        sd = sd < 1e-6 ? 1e-6 : (sd > 1e9 ? 1e9 : sd);
        outm[0] = 0.5 * (sa / n + sb / n);
        outm[1] = 1.0 / (sd * sd * C);
    }
}

// ------- cost volume 1 (md=2, C=32), LDS-tiled -> xin1 cols 0..124 ---------
__global__ __launch_bounds__(128, 2) void k_cv1_t(bf16* __restrict__ xin1,
                                                  const double* __restrict__ red) {
    __shared__ bf16 lds[8][8][12][32];   // [plane z0-2..z0+5][row y0-2..y0+5][x0-2..x0+9][ch]
    const int tid = threadIdx.x;
    const int xyt = (int)(blockIdx.x % 60u);     // 6 x-tiles * 10 y-tiles
    const int zg  = (int)(blockIdx.x / 60u);     // 12 z-groups
    const int x0 = (xyt % 6) * 8;
    const int y0 = (xyt / 6) * 4;
    const int z0 = zg * 4;
    const u16* src16 = (const u16*)xin1;

    for (int f = tid; f < 8 * 8 * 12; f += 128) {
        int xx = f % 12, rest = f / 12;
        int yy = rest % 8, pl = rest / 8;
        int z2 = z0 - 2 + pl, y2 = y0 - 2 + yy, x2 = x0 - 2 + xx;
        u32 pk[16];
        #pragma unroll
        for (int c = 0; c < 16; ++c) pk[c] = 0;
        if ((unsigned)z2 < (unsigned)D1c && (unsigned)y2 < (unsigned)H1c && (unsigned)x2 < (unsigned)W1c) {
            long rb = (((long)z2 * H1c + y2) * W1c + x2) * S1 + 157;
            #pragma unroll
            for (int c = 0; c < 16; ++c)
                pk[c] = (u32)src16[rb + 2 * c] | ((u32)src16[rb + 2 * c + 1] << 16);
        }
        #pragma unroll
        for (int qq = 0; qq < 4; ++qq) {
            uint4 q = { pk[qq * 4], pk[qq * 4 + 1], pk[qq * 4 + 2], pk[qq * 4 + 3] };
            *(uint4*)&lds[pl][yy][xx][qq * 8] = q;
        }
    }
    __syncthreads();

    const float m = sf((float)red[0]), mult = sf((float)red[1]);
    const int tx = tid & 7, ty = (tid >> 3) & 3, tz = tid >> 5;
    const int x = x0 + tx, y = y0 + ty, z = z0 + tz;
    const long p = ((long)z * H1c + y) * W1c + x;

    float fm[32], S = 0.f;
    #pragma unroll
    for (int c = 0; c < 32; ++c) { fm[c] = sf(bf2f(xin1[p * (long)S1 + 125 + c])) - m; S += fm[c]; }

    #pragma unroll 1
    for (int dz = 0; dz < 5; ++dz) {
        const int z2 = z + dz - 2;
        u16 hg[25];
        #pragma unroll
        for (int oo = 0; oo < 25; ++oo) {
            const int dy = oo / 5, dx = oo % 5;
            const int y2 = y + dy - 2, x2 = x + dx - 2;
            float cost = 0.f;
            if ((unsigned)z2 < (unsigned)D1c && (unsigned)y2 < (unsigned)H1c && (unsigned)x2 < (unsigned)W1c) {
                union { uint4 u[4]; bf16 h[32]; } wv;
                #pragma unroll
                for (int qq = 0; qq < 4; ++qq)
                    wv.u[qq] = *(const uint4*)&lds[tz + dz][ty + dy][tx + dx][qq * 8];
                float dot = 0.f;
                #pragma unroll
                for (int c = 0; c < 32; ++c) dot += fm[c] * sf(bf2f(wv.h[c]));
                dot -= m * S;
                cost = dot * mult;
                cost = cost >= 0.f ? cost : 0.05f * cost;
            }
            hg[oo] = f2bfu(cost);
        }
        u16* dstp = (u16*)(xin1 + p * (long)S1) + dz * 25;
        #pragma unroll
        for (int oo = 0; oo < 25; ++oo) dstp[oo] = hg[oo];
    }
}

// ------- cost volume 2 (md=1, C=16), LDS-tiled -> xin2 cols 0..26 ----------
__global__ __launch_bounds__(256, 2) void k_cv2_t(bf16* __restrict__ xin2,
                                                  const double* __restrict__ red) {
    __shared__ bf16 lds[6][18][18][16];
    const int tid = threadIdx.x;
    const int xyt = (int)(blockIdx.x % 30u);     // 6 x-tiles * 5 y-tiles
    const int zg  = (int)(blockIdx.x / 30u);     // 24 z-groups
    const int x0 = (xyt % 6) * 16;
    const int y0 = (xyt / 6) * 16;
    const int z0 = zg * 4;
    const u16* src16 = (const u16*)xin2;

    for (int f = tid; f < 6 * 324; f += 256) {
        int pl = f / 324, r = f - pl * 324;
        int yy = r / 18, xx = r - yy * 18;
        int z2 = z0 - 1 + pl, y2 = y0 - 1 + yy, x2 = x0 - 1 + xx;
        u32 pk[8];
        #pragma unroll
        for (int c = 0; c < 8; ++c) pk[c] = 0;
        if ((unsigned)z2 < (unsigned)D2c && (unsigned)y2 < (unsigned)H2c && (unsigned)x2 < (unsigned)W2c) {
            long rb = (((long)z2 * H2c + y2) * W2c + x2) * S2 + 43;
            #pragma unroll
            for (int c = 0; c < 8; ++c)
                pk[c] = (u32)src16[rb + 2 * c] | ((u32)src16[rb + 2 * c + 1] << 16);
        }
        uint4 q0 = { pk[0], pk[1], pk[2], pk[3] };
        uint4 q1 = { pk[4], pk[5], pk[6], pk[7] };
        *(uint4*)&lds[pl][yy][xx][0] = q0;
        *(uint4*)&lds[pl][yy][xx][8] = q1;
    }
    __syncthreads();

    const float m = sf((float)red[2]), mult = sf((float)red[3]);
    const int tx = tid & 15, ty = tid >> 4;
    const int x = x0 + tx, y = y0 + ty;

    #pragma unroll 1
    for (int zz = 0; zz < 4; ++zz) {
        const int z = z0 + zz;
        const long p = ((long)z * H2c + y) * W2c + x;
        float fm[16], S = 0.f;
        #pragma unroll
        for (int c = 0; c < 16; ++c) {
            fm[c] = sf(bf2f(xin2[p * (long)S2 + 27 + c])) - m;
            S += fm[c];
        }
        union { u16 h[28]; uint4 q[3]; u32 w[14]; } r;
        #pragma unroll
        for (int o = 0; o < 27; ++o) {
            const int dz = o / 9, dy = (o / 3) % 3, dx = o % 3;
            const int z2 = z + dz - 1, y2 = y + dy - 1, x2 = x + dx - 1;
            float cost = 0.f;
            if ((unsigned)z2 < (unsigned)D2c && (unsigned)y2 < (unsigned)H2c && (unsigned)x2 < (unsigned)W2c) {
                union { uint4 u[2]; bf16 h[16]; } wv;
                wv.u[0] = *(const uint4*)&lds[zz + dz][ty + dy][tx + dx][0];
                wv.u[1] = *(const uint4*)&lds[zz + dz][ty + dy][tx + dx][8];
                float dot = 0.f;
                #pragma unroll
                for (int c = 0; c < 16; ++c) dot += fm[c] * sf(bf2f(wv.h[c]));
                dot -= m * S;
                cost = dot * mult;
                cost = cost >= 0.f ? cost : 0.05f * cost;
            }
            r.h[o] = f2bfu(cost);
        }
        r.h[27] = 0;
        u16* dstp = (u16*)(xin2 + p * (long)S2);
        *(uint4*)dstp        = r.q[0];
        *(uint4*)(dstp + 8)  = r.q[1];
        *(uint4*)(dstp + 16) = r.q[2];
        *(u32*)(dstp + 24)   = r.w[12];
        dstp[26] = r.h[26];
    }
}

// ------- MFMA implicit-GEMM 3x3x3 conv, channel-last, LDS-staged -----------
// Round-11: XOR bank-slot swizzle. The linear [.][.][18 rows][32ch] layout
// put a quad-group's 16 ds_read_b128 (row stride 64B) into only 2 of 8
// 16B bank-slots -> 8-way conflict (7.4M SQ_LDS_BANK_CONFLICT/dispatch).
// Store quarter qs of row vx at slot qs ^ ((vx>>1)&3); read slot
// quad ^ ((vx>>1)&3): slot = 4*(vx&1) + (quad^((vx>>1)&3)) covers all 8
// slots over 8 rows -> 2-way (free). Writes remain within-row permutations
// (still conflict-free). Both sides use the same involution (rule #21).
// Also: 3 blocks/CU (LDS 3x41.5KB < 160KB) for stage/MFMA overlap.
template<int NT, int NCH, int COUT, int M, int SS, int DD, int HH, int WW>
__global__ __launch_bounds__(256, 3) void k_conv_mfma(
        const bf16* __restrict__ src,
        const bf16* __restrict__ wtb, const void* __restrict__ bias,
        bf16* __restrict__ dst, int dstride, int dcol0,
        float slope, const int* __restrict__ bmodep) {
    const int bmode = *bmodep;
    const int tid = threadIdx.x;
    const int wave = tid >> 6, lane = tid & 63;
    const int quad = lane >> 4, nlo = lane & 15;
    constexpr long HW = (long)HH * WW;
    constexpr int PL = M + 2;            // staged planes
    constexpr int NXB = WW / 16;
    constexpr int NYB = HH / 4;          // 4 rows per block (one per wave)
    constexpr int NXY = NXB * NYB;
    __shared__ bf16 lds[PL][6][18][32];  // M=4: 41472 B, M=2: 27648 B
    bf16* lb = &lds[0][0][0][0];

    // bijective chunked swizzle (gridDim.x % 8 == 0 by construction)
    const u32 per = gridDim.x >> 3;
    const u32 bid = (blockIdx.x & 7u) * per + (blockIdx.x >> 3);
    const int xyb = (int)(bid % (u32)NXY);
    const int zg  = (int)(bid / (u32)NXY);
    const int x0 = (xyb % NXB) * 16;
    const int y0 = (xyb / NXB) * 4;
    const int z0 = zg * M;

    f4v acc[M][NT];
    #pragma unroll
    for (int m = 0; m < M; ++m) {
        #pragma unroll
        for (int nt = 0; nt < NT; ++nt) {
            float bv = gld(bias, nt * 16 + nlo, bmode);
            acc[m][nt][0] = bv; acc[m][nt][1] = bv; acc[m][nt][2] = bv; acc[m][nt][3] = bv;
        }
    }

    const u32 selLo = (x0 == 0       && nlo == 0)  ? 0u : 0xFFFFFFFFu;
    const u32 selHi = (x0 == WW - 16 && nlo == 15) ? 0u : 0xFFFFFFFFu;

    u32 zm[PL];
    #pragma unroll
    for (int p = 0; p < PL; ++p) {
        const int z2 = z0 - 1 + p;
        zm[p] = ((unsigned)z2 < (unsigned)DD) ? 0xFFFFFFFFu : 0u;
    }
    u32 ym[3];
    #pragma unroll
    for (int dyi = 0; dyi < 3; ++dyi) {
        const int y2 = y0 + wave + dyi - 1;
        ym[dyi] = ((unsigned)y2 < (unsigned)HH) ? 0xFFFFFFFFu : 0u;
    }
    // per-dxi swizzled read offsets within a (p,rr) row-block (bf16 units)
    int aoff[3];
    #pragma unroll
    for (int dxi = 0; dxi < 3; ++dxi) {
        const int vx = nlo + dxi;
        aoff[dxi] = vx * 32 + (quad ^ ((vx >> 1) & 3)) * 8;
    }

    constexpr int NQ = PL * 6 * 18 * 4;      // 16B quarters to stage per ch
    constexpr int KQ = (NQ + 255) / 256;

    const bf16* bp = wtb + (long)nlo * 32 + quad * 8;

    #pragma unroll 1
    for (int ch = 0; ch < NCH; ++ch) {
        __syncthreads();                     // previous consume done
        #pragma unroll
        for (int k = 0; k < KQ; ++k) {
            const int q = tid + k * 256;
            if (q < NQ) {
                const int qs = q & 3;
                const int f = q >> 2;
                const int vx = f % 18;
                const int rest = f / 18;
                const int r = rest % 6;
                const int lp = rest / 6;
                int zc = z0 - 1 + lp; zc = zc < 0 ? 0 : (zc >= DD ? DD - 1 : zc);
                int yc = y0 - 1 + r;  yc = yc < 0 ? 0 : (yc >= HH ? HH - 1 : yc);
                int xc = x0 - 1 + vx; xc = xc < 0 ? 0 : (xc >= WW ? WW - 1 : xc);
                const bf16* gp = src + ((long)zc * HW + (long)yc * WW + xc) * (long)SS + ch * 32 + qs * 8;
                const int wq = qs ^ ((vx >> 1) & 3);       // slot swizzle
                *(uint4*)(lb + (((lp * 6 + r) * 18 + vx) * 32) + wq * 8) = *(const uint4*)gp;
            }
        }
        __syncthreads();                     // stage visible to all waves

        #pragma unroll 1
        for (int dyi = 0; dyi < 3; ++dyi) {
            if (!ym[dyi]) continue;          // wave-uniform; no barriers inside
            const int rr = wave + dyi;
            #pragma unroll
            for (int dxi = 0; dxi < 3; ++dxi) {
                union U { uint4 u; s8v v; } b[3][NT];
                #pragma unroll
                for (int dz = 0; dz < 3; ++dz)
                    #pragma unroll
                    for (int nt = 0; nt < NT; ++nt)
                        b[dz][nt].u = *(const uint4*)(bp +
                            (((long)(dz * 9 + dyi * 3 + dxi) * NCH + ch) * COUT) * 32 + nt * 512);
                const u32 sx = (dxi == 0) ? selLo : (dxi == 2 ? selHi : 0xFFFFFFFFu);
                #pragma unroll
                for (int p = 0; p < PL; ++p) {
                    union U2 { uint4 u; s8v v; } a;
                    a.u = *(const uint4*)(lb + ((p * 6 + rr) * 18) * 32 + aoff[dxi]);
                    const u32 mm = zm[p] & sx;
                    a.u.x &= mm; a.u.y &= mm; a.u.z &= mm; a.u.w &= mm;
                    #pragma unroll
                    for (int dz = 0; dz < 3; ++dz) {
                        const int m = p - dz;
                        if (m < 0 || m >= M) continue;   // compile-time prune
                        #pragma unroll
                        for (int nt = 0; nt < NT; ++nt)
                            acc[m][nt] = __builtin_amdgcn_mfma_f32_16x16x32_bf16(a.v, b[dz][nt].v, acc[m][nt], 0, 0, 0);
                    }
                }
            }
        }
    }

    const int yw = y0 + wave;
    #pragma unroll
    for (int m = 0; m < M; ++m) {
        const long vbase = (long)(z0 + m) * HW + (long)yw * WW + x0 + quad * 4;
        #pragma unroll
        for (int nt = 0; nt < NT; ++nt) {
            #pragma unroll
            for (int reg = 0; reg < 4; ++reg) {
                float v = acc[m][nt][reg];
                v = v >= 0.f ? v : v * slope;
                dst[(vbase + reg) * (long)dstride + dcol0 + nt * 16 + nlo] = f2bf(v);
            }
        }
    }
}

// ------- tiled small conv: Cin=16 -> Cout=3, linear, f32 out ---------------
template<int ZS>
__global__ __launch_bounds__(256, 2) void k_conv_small_t(
        const bf16* __restrict__ src, int sstride, int scol0,
        const float* __restrict__ wt, const void* __restrict__ bias,
        float* __restrict__ dst, int D, int H, int W,
        const int* __restrict__ bmodep) {
    const int bmode = *bmodep;
    __shared__ bf16 lds[ZS + 2][18][18][16];   // ZS=4: 62208 B
    const int tid = threadIdx.x;
    const int gx = W >> 4;                      // W % 16 == 0
    const int gy = (H + 15) >> 4;
    const int xyt = (int)(blockIdx.x % (u32)(gx * gy));
    const int zg  = (int)(blockIdx.x / (u32)(gx * gy));
    const int x0 = (xyt % gx) << 4;
    const int y0 = (xyt / gx) << 4;
    const int z0 = zg * ZS;

    // ---- stage (ZS+2) planes of 18x18 fragments (zeros outside volume) ----
    const int NFRAG = (ZS + 2) * 324;
    for (int f = tid; f < NFRAG; f += 256) {
        int pl = f / 324, r = f - pl * 324;
        int yy = r / 18, xx = r - yy * 18;
        int z2 = z0 - 1 + pl, y2 = y0 - 1 + yy, x2 = x0 - 1 + xx;
        uint4 lo = {0, 0, 0, 0}, hi = {0, 0, 0, 0};
        if ((unsigned)z2 < (unsigned)D && (unsigned)y2 < (unsigned)H && (unsigned)x2 < (unsigned)W) {
            const bf16* p = src + ((long)(z2 * H + y2) * W + x2) * (long)sstride + scol0;
            lo = *(const uint4*)p;
            hi = *(const uint4*)(p + 8);
        }
        *(uint4*)&lds[pl][yy][xx][0] = lo;
        *(uint4*)&lds[pl][yy][xx][8] = hi;
    }
    __syncthreads();

    const int ty = tid >> 4, tx = tid & 15;
    const bool live = (y0 + ty) < H;

    float a0[ZS], a1[ZS], a2[ZS];
    {
        float b0 = gld(bias, 0, bmode), b1 = gld(bias, 1, bmode), b2 = gld(bias, 2, bmode);
        #pragma unroll
        for (int zz = 0; zz < ZS; ++zz) { a0[zz] = b0; a1[zz] = b1; a2[zz] = b2; }
    }

    #pragma unroll 1
    for (int tap = 0; tap < 27; ++tap) {
        const int dz = tap / 9, dy = (tap / 3) % 3, dx = tap % 3;
        const float* w = wt + tap * 48;          // uniform -> scalar loads
        float wv[48];
        #pragma unroll
        for (int k = 0; k < 48; ++k) wv[k] = w[k];
        #pragma unroll
        for (int zz = 0; zz < ZS; ++zz) {
            union { uint4 u[2]; bf16 h[16]; } fr;
            fr.u[0] = *(const uint4*)&lds[zz + dz][ty + dy][tx + dx][0];
            fr.u[1] = *(const uint4*)&lds[zz + dz][ty + dy][tx + dx][8];
            #pragma unroll
            for (int c = 0; c < 16; ++c) {
                float f = bf2f(fr.h[c]);
                a0[zz] += f * wv[c * 3];
                a1[zz] += f * wv[c * 3 + 1];
                a2[zz] += f * wv[c * 3 + 2];
            }
        }
    }

    if (!live) return;
    #pragma unroll
    for (int zz = 0; zz < ZS; ++zz) {
        long p = ((long)(z0 + zz) * H + (y0 + ty)) * W + (x0 + tx);
        dst[p * 3]     = sf(a0[zz]);
        dst[p * 3 + 1] = sf(a1[zz]);
        dst[p * 3 + 2] = sf(a2[zz]);
    }
}

// ------- x2 upsample taps ---------------------------------------------------
__device__ __forceinline__ void up_taps(int i, int n, int& j0, int& j1, float& w0, float& w1) {
    if (i & 1) { j0 = i >> 1; j1 = j0 + 1; w0 = 0.75f; w1 = 0.25f; if (j1 >= n) { j1 = j0; w0 = 1.f; w1 = 0.f; } }
    else { j1 = i >> 1; j0 = j1 - 1; w0 = 0.25f; w1 = 0.75f; if (j0 < 0) { j0 = j1; w0 = 0.f; w1 = 1.f; } }
}

// ctx16 [NHALF][16] -> xin2 cols 59..74 (LDS-transposed coalesced writes)
__global__ __launch_bounds__(256) void k_up_ctx(const bf16* __restrict__ in,
                                                u16* __restrict__ xin2) {
    __shared__ u16 lw[256 * 16];
    const long p0 = (long)blockIdx.x * 256;
    const long p = p0 + threadIdx.x;
    int x = (int)(p % W2c), y = (int)((p / W2c) % H2c), z = (int)(p / (W2c * H2c));
    int jz0, jz1, jy0, jy1, jx0, jx1; float wz0, wz1, wy0, wy1, wx0, wx1;
    up_taps(z, D1c, jz0, jz1, wz0, wz1);
    up_taps(y, H1c, jy0, jy1, wy0, wy1);
    up_taps(x, W1c, jx0, jx1, wx0, wx1);
    float acc[16];
    for (int c = 0; c < 16; ++c) acc[c] = 0.f;
    int jzs[2] = { jz0, jz1 }; float wzs[2] = { wz0, wz1 };
    int jys[2] = { jy0, jy1 }; float wys[2] = { wy0, wy1 };
    int jxs[2] = { jx0, jx1 }; float wxs[2] = { wx0, wx1 };
    for (int a = 0; a < 2; ++a) {
        if (wzs[a] == 0.f) continue;
        for (int b = 0; b < 2; ++b) {
            if (wys[b] == 0.f) continue;
            float wzy = wzs[a] * wys[b];
            for (int d = 0; d < 2; ++d) {
                if (wxs[d] == 0.f) continue;
                float w = wzy * wxs[d];
                long rb = ((long)(jzs[a] * H1c + jys[b]) * W1c + jxs[d]) * 16;
                for (int c = 0; c < 16; ++c) acc[c] += w * bf2f(in[cl(rb + c, NCTX16)]);
            }
        }
    }
    #pragma unroll
    for (int c = 0; c < 16; ++c) lw[threadIdx.x * 16 + c] = f2bfu(acc[c]);
    __syncthreads();
    #pragma unroll
    for (int k = 0; k < 16; ++k) {
        const int e = threadIdx.x + k * 256;
        const int row = e >> 4, col = e & 15;
        xin2[(p0 + row) * (long)S2 + 59 + col] = lw[e];
    }
}

// fused: velup = 2*up(vel1); du2 = warp(disp_up, velup) + velup; xin2 75..77
__global__ void k_warp_dispup(const void* __restrict__ dispup, const float* __restrict__ vel1,
                              float* __restrict__ du2, bf16* __restrict__ xin2,
                              const int* __restrict__ modep) {
    int mode = *modep;
    long p = (long)blockIdx.x * 256 + threadIdx.x;
    if (p >= NFULL) return;
    int x = (int)(p % W2c), y = (int)((p / W2c) % H2c), z = (int)(p / (W2c * H2c));
    int jz0, jz1, jy0, jy1, jx0, jx1; float wz0, wz1, wy0, wy1, wx0, wx1;
    up_taps(z, D1c, jz0, jz1, wz0, wz1);
    up_taps(y, H1c, jy0, jy1, wy0, wy1);
    up_taps(x, W1c, jx0, jx1, wx0, wx1);
    int jzs[2] = { jz0, jz1 }; float wzs[2] = { wz0, wz1 };
    int jys[2] = { jy0, jy1 }; float wys[2] = { wy0, wy1 };
    int jxs[2] = { jx0, jx1 }; float wxs[2] = { wx0, wx1 };
    float vu[3] = { 0.f, 0.f, 0.f };
    for (int a = 0; a < 2; ++a) {
        if (wzs[a] == 0.f) continue;
        for (int b = 0; b < 2; ++b) {
            if (wys[b] == 0.f) continue;
            float wzy = wzs[a] * wys[b];
            for (int d = 0; d < 2; ++d) {
                if (wxs[d] == 0.f) continue;
                float w = wzy * wxs[d];
                long rb = ((long)(jzs[a] * H1c + jys[b]) * W1c + jxs[d]) * 3;
                for (int c = 0; c < 3; ++c) vu[c] += w * sf(vel1[cl(rb + c, N3H)]);
            }
        }
    }
    for (int c = 0; c < 3; ++c) vu[c] = sf(vu[c] * 2.f);
    float cz = z + vu[0], cy = y + vu[1], cx = x + vu[2];
    float acc[3] = { 0.f, 0.f, 0.f };
    float z0f = floorf(cz), y0f = floorf(cy), x0f = floorf(cx);
    int z0 = (int)z0f, y0 = (int)y0f, x0 = (int)x0f;
    float fz = cz - z0f, fy = cy - y0f, fx = cx - x0f;
    for (int dz = 0; dz < 2; ++dz) {
        int zi = z0 + dz; if (zi < 0 || zi >= D2c) continue;
        float wz = dz ? fz : 1.f - fz;
        for (int dy = 0; dy < 2; ++dy) {
            int yi = y0 + dy; if (yi < 0 || yi >= H2c) continue;
            float wzy = wz * (dy ? fy : 1.f - fy);
            for (int dx = 0; dx < 2; ++dx) {
                int xi = x0 + dx; if (xi < 0 || xi >= W2c) continue;
                float w = wzy * (dx ? fx : 1.f - fx);
                long idx = (long)(zi * H2c + yi) * W2c + xi;
                for (int c = 0; c < 3; ++c) acc[c] += w * gld(dispup, cl((long)c * NFULL + idx, 3 * NFULL), mode);
            }
        }
    }
    for (int c = 0; c < 3; ++c) {
        float v = sf(acc[c] + vu[c]);
        du2[cl(p * 3 + c, N3F)] = v;
        xin2[cl(p * (long)S2 + 75 + c, NX2)] = f2bf(v);
    }
}

// robust t decode (handles bf16-stored or f32-stored scalar)
__device__ __forceinline__ float decode_t(const u16* tp) {
    u16 b0 = tp[0], b1 = tp[1];
    union { u32 i; float f; } a, b;
    a.i = ((u32)b0) << 16;
    b.i = ((u32)b1 << 16) | b0;
    float ta = a.f, tb = b.f;
    bool okA = (ta == ta) && ta >= 0.f && ta < 0.75f;
    bool okB = (tb == tb) && tb >= 0.f && tb < 0.75f;
    return okB ? tb : (okA ? ta : 0.f);
}

// vf = (warp(du2, vu2) + vu2 - disp_up) / (1 - t); out mode-dispatched
__global__ void k_final(const float* __restrict__ du2, const float* __restrict__ vu2,
                        const void* __restrict__ dispup, const u16* __restrict__ tptr,
                        void* __restrict__ out, long out_n, const int* __restrict__ modep) {
    int mode = *modep;
    long p = (long)blockIdx.x * 256 + threadIdx.x;
    if (p >= NFULL) return;
    float t = decode_t(tptr);
    float den = 1.f - t;
    if (fabsf(den) < 1e-6f) den = 1e-6f;
    float inv = 1.f / den;
    int x = (int)(p % W2c), y = (int)((p / W2c) % H2c), z = (int)(p / (W2c * H2c));
    float cz = z + sf(vu2[cl(p * 3, N3F)]);
    float cy = y + sf(vu2[cl(p * 3 + 1, N3F)]);
    float cx = x + sf(vu2[cl(p * 3 + 2, N3F)]);
    float acc[3] = { 0.f, 0.f, 0.f };
    float z0f = floorf(cz), y0f = floorf(cy), x0f = floorf(cx);
    int z0 = (int)z0f, y0 = (int)y0f, x0 = (int)x0f;
    float fz = cz - z0f, fy = cy - y0f, fx = cx - x0f;
    for (int dz = 0; dz < 2; ++dz) {
        int zi = z0 + dz; if (zi < 0 || zi >= D2c) continue;
        float wz = dz ? fz : 1.f - fz;
        for (int dy = 0; dy < 2; ++dy) {
            int yi = y0 + dy; if (yi < 0 || yi >= H2c) continue;
            float wzy = wz * (dy ? fy : 1.f - fy);
            for (int dx = 0; dx < 2; ++dx) {
                int xi = x0 + dx; if (xi < 0 || xi >= W2c) continue;
                float w = wzy * (dx ? fx : 1.f - fx);
                long rb = ((long)(zi * H2c + yi) * W2c + xi) * 3;
                for (int c = 0; c < 3; ++c) acc[c] += w * sf(du2[cl(rb + c, N3F)]);
            }
        }
    }
    for (int c = 0; c < 3; ++c) {
        float v = (acc[c] + sf(vu2[cl(p * 3 + c, N3F)]) - gld(dispup, cl((long)c * NFULL + p, 3 * NFULL), mode)) * inv;
        long oi = cl((long)c * NFULL + p, out_n);
        if (mode) ((float*)out)[oi] = sf(v);
        else      ((bf16*)out)[oi] = f2bf(v);
    }
}

static inline int cdiv(long a, long b) { return (int)((a + b - 1) / b); }

extern "C" void kernel_launch(void* const* d_in, const int* in_sizes, int n_in,
                              void* d_out, int out_size, void* d_ws, size_t ws_size,
                              hipStream_t stream) {
    const u16* t_in = (const u16*)d_in[0];
    const void* disp_up = d_in[1];
    const void* fx  = d_in[2];
    const void* fy  = d_in[3];
    const void* fxu = d_in[4];
    const void* fyu = d_in[5];
    const void* ctx = d_in[6];

    const size_t XIN1_B = (size_t)NX1 * 2;
    const size_t XIN2_B = (size_t)NX2 * 2;
    const size_t base_need = XIN1_B + XIN2_B + 2 * (size_t)GUARD;
    const size_t base_pad = (base_need + 255) & ~(size_t)255;
    const size_t vf_elems = 3UL * NFULL;

    // wtb sizes (bf16 elements): 27 * nchunk * Cout * 32
    const long WTB0 = 387072;  // 224->64, 7ch
    const long WTB1 = 373248;  // 288->48, 9ch
    const long WTB2 = 304128;  // 336->32, 11ch
    const long WTB3 = 165888;  // 368->16, 12ch
    const long WTB5 = 82944;   // 78->32, 3ch
    const long WTB6 = 55296;   // 110->16, 4ch
    const long WTB_TOT = WTB0 + WTB1 + WTB2 + WTB3 + WTB5 + WTB6; // 1,368,576

    size_t scro[11];
    {
        size_t o = 0;
        auto al = [&](size_t bytes) { size_t r = o; o = (o + bytes + 255) & ~(size_t)255; return r; };
        scro[0] = al((size_t)WTB_TOT * 2);      // WTB (bf16, mfma layout)
        scro[1] = al(2UL * 1296 * 4);           // WT f32 (two small convs)
        scro[2] = al((size_t)NCTX16 * 2);       // CTX16
        scro[3] = al((size_t)N3H * 4);          // VEL1
        scro[4] = al((size_t)N3H * 4);          // DISPH
        scro[5] = al((size_t)N3F * 4);          // DU2
        scro[6] = al((size_t)N3F * 4);          // VU2
        scro[7] = al(4UL * RG * 2 * 8);         // partials
        scro[8] = al(16 * 8);                   // RED
        scro[9] = al(32 * 4);                   // MODES
        scro[10] = o;
    }
    const size_t scratch_need = scro[10];
    const size_t tail_avail = ((size_t)out_size > vf_elems) ? ((size_t)out_size - vf_elems) * 2 : 0;

    char* scr = nullptr;
    if (ws_size >= base_pad + scratch_need) {
        scr = (char*)d_ws + base_pad;
    } else if (ws_size >= base_need && tail_avail >= scratch_need) {
        scr = (char*)d_out + vf_elems * 2;
    }
    if (scr == nullptr) {
        k_fill<<<2048, 256, 0, stream>>>((u16*)d_out, (long)out_size, 0x49A0);
        return;
    }

    char* ws = (char*)d_ws;
    bf16*  xin1  = (bf16*)(ws + GUARD);
    bf16*  xin2  = (bf16*)(ws + GUARD + XIN1_B);
    bf16*  wtball = (bf16*)(scr + scro[0]);
    float* wtf   = (float*)(scr + scro[1]);
    bf16*  ctx16 = (bf16*)(scr + scro[2]);
    float* vel1  = (float*)(scr + scro[3]);
    float* disph = (float*)(scr + scro[4]);
    float* du2   = (float*)(scr + scro[5]);
    float* vu2   = (float*)(scr + scro[6]);
    double* part = (double*)(scr + scro[7]);
    double* red  = (double*)(scr + scro[8]);
    int*   modes = (int*)(scr + scro[9]);
    double* pA = part;
    double* pB = part + RG * 2;
    double* pC = part + RG * 4;
    double* pD = part + RG * 6;

    bf16* wtb0 = wtball;
    bf16* wtb1 = wtb0 + WTB0;
    bf16* wtb2 = wtb1 + WTB1;
    bf16* wtb3 = wtb2 + WTB2;
    bf16* wtb5 = wtb3 + WTB3;
    bf16* wtb6 = wtb5 + WTB5;
    float* wt4 = wtf;
    float* wt7 = wtf + 1296;

    // fxu channel-last f32 copy reuses xin1's memory (dead after fl1 conv3):
    // NFULL*16*4 = 47.2MB <= XIN1_B = 67.8MB
    float* fxucl = (float*)xin1;

    // zero-init xin2 + scratch. xin2 must be finite everywhere (fl2 convs
    // read K-pad cols 78..127 with zero weights; NaN*0 = NaN). xin1 needs no
    // fill: every byte of cols 0..223 is produced before its first read, and
    // conv K-tail overreads land in already-written cols / zero-filled xin2.
    k_fill<<<4096, 256, 0, stream>>>((u16*)xin2, NX2, 0);
    k_fill<<<4096, 256, 0, stream>>>((u16*)scr, (long)(scratch_need / 2), 0);

    // dtype detection for all tensor inputs
    for (int i = 1; i < 23 && i < n_in; ++i) {
        k_detect<<<1, 256, 0, stream>>>(d_in[i], (long)in_sizes[i], modes + i);
    }

    // MFMA weight repack (bf16, zero-padded K tails)
    k_wtb<<<cdiv(WTB0, 256), 256, 0, stream>>>(d_in[7],  wtb0, 224, 64, 7,  modes + 7);
    k_wtb<<<cdiv(WTB1, 256), 256, 0, stream>>>(d_in[9],  wtb1, 288, 48, 9,  modes + 9);
    k_wtb<<<cdiv(WTB2, 256), 256, 0, stream>>>(d_in[11], wtb2, 336, 32, 11, modes + 11);
    k_wtb<<<cdiv(WTB3, 256), 256, 0, stream>>>(d_in[13], wtb3, 368, 16, 12, modes + 13);
    k_wtb<<<cdiv(WTB5, 256), 256, 0, stream>>>(d_in[17], wtb5, 78,  32, 3,  modes + 17);
    k_wtb<<<cdiv(WTB6, 256), 256, 0, stream>>>(d_in[19], wtb6, 110, 16, 4,  modes + 19);
    // f32 weights for the two small convs
    k_wt<<<cdiv(1296, 256), 256, 0, stream>>>(d_in[15], wt4, 16, 3, modes + 15);
    k_wt<<<cdiv(1296, 256), 256, 0, stream>>>(d_in[21], wt7, 16, 3, modes + 21);

    // channel-last transposes with coalesced (LDS-staged) writes
    k_tcl_t<32><<<360, 256, 0, stream>>>(fy,  (u16*)xin1, NX1, 125, NHALF, S1, modes + 3);
    k_tcl_t<32><<<360, 256, 0, stream>>>(ctx, (u16*)xin1, NX1, 189, NHALF, S1, modes + 6);
    k_tcl_t<16><<<2880, 256, 0, stream>>>(fyu, (u16*)xin2, NX2, 27, NFULL, S2, modes + 5);

    k_down<<<cdiv(NHALF, 256), 256, 0, stream>>>(disp_up, disph, xin1, modes + 1);

    k_warp_cf<32><<<360, 256, 0, stream>>>(fx, 32L * NHALF, disph, N3H, (u16*)xin1, NX1, S1, 157, D1c, H1c, W1c, modes + 2);
    k_reduce_cl<<<RG, 256, 0, stream>>>(xin1, NX1, NHALF, S1, 157, 32, pA, modes + 31);
    k_reduce_cl<<<RG, 256, 0, stream>>>(fy, 32L * NHALF, 32L * NHALF, 1, 0, 1, pB, modes + 3);
    k_stats2<<<1, 256, 0, stream>>>(pA, pB, (double)(32L * NHALF), 32.0, red);

    // LDS-tiled cost volume 1: grid = 60 xy-tiles (8x4) x 12 zgroups = 720
    k_cv1_t<<<720, 128, 0, stream>>>(xin1, red);

    // fl1 dense block — LDS-staged MFMA conv (4 rows x M=2 z-planes / block)
    k_conv_mfma<4, 7, 64, 2, S1, D1c, H1c, W1c><<<720, 256, 0, stream>>>(xin1, wtb0, d_in[8],  xin1, S1, 224, 0.02f, modes + 8);
    k_conv_mfma<3, 9, 48, 2, S1, D1c, H1c, W1c><<<720, 256, 0, stream>>>(xin1, wtb1, d_in[10], xin1, S1, 288, 0.02f, modes + 10);
    k_conv_mfma<2, 11, 32, 2, S1, D1c, H1c, W1c><<<720, 256, 0, stream>>>(xin1, wtb2, d_in[12], xin1, S1, 336, 0.02f, modes + 12);
    k_conv_mfma<1, 12, 16, 2, S1, D1c, H1c, W1c><<<720, 256, 0, stream>>>(xin1, wtb3, d_in[14], ctx16, 16, 0, 0.02f, modes + 14);
    // tiled small conv (NHALF): grid = 3x3 xy-tiles x 12 zgroups = 108
    k_conv_small_t<4><<<108, 256, 0, stream>>>(ctx16, 16, 0, wt4, d_in[16], vel1, D1c, H1c, W1c, modes + 16);

    // xin1 is now dead -> transpose fxu into its memory as [NFULL][16] f32
    k_tclf<<<cdiv(NFULL, 256), 256, 0, stream>>>(fxu, fxucl, 16, NFULL, modes + 4);

    k_up_ctx<<<2880, 256, 0, stream>>>(ctx16, (u16*)xin2);
    k_warp_dispup<<<cdiv(NFULL, 256), 256, 0, stream>>>(disp_up, vel1, du2, xin2, modes + 1);

    // vectorized warp from the dense channel-last f32 copy
    k_warp_cl16<<<2880, 256, 0, stream>>>(fxucl, du2, (u16*)xin2);
    k_reduce_cl<<<RG, 256, 0, stream>>>(xin2, NX2, NFULL, S2, 43, 16, pC, modes + 31);
    k_reduce_cl<<<RG, 256, 0, stream>>>(fyu, 16L * NFULL, 16L * NFULL, 1, 0, 1, pD, modes + 5);
    k_stats2<<<1, 256, 0, stream>>>(pC, pD, (double)(16L * NFULL), 16.0, red + 2);

    // LDS-tiled cost volume 2: grid = 30 xy-tiles (16x16) x 24 zgroups = 720
    k_cv2_t<<<720, 256, 0, stream>>>(xin2, red);

    // fl2 block — LDS-staged MFMA conv (4 rows x M=4 z-planes / block)
    k_conv_mfma<2, 3, 32, 4, S2, D2c, H2c, W2c><<<2880, 256, 0, stream>>>(xin2, wtb5, d_in[18], xin2, S2, 78,  0.02f, modes + 18);
    k_conv_mfma<1, 4, 16, 4, S2, D2c, H2c, W2c><<<2880, 256, 0, stream>>>(xin2, wtb6, d_in[20], xin2, S2, 110, 0.02f, modes + 20);
    // tiled small conv (NFULL): grid = 6x5 xy-tiles x 24 zgroups = 720
    k_conv_small_t<4><<<720, 256, 0, stream>>>(xin2, S2, 110, wt7, d_in[22], vu2, D2c, H2c, W2c, modes + 22);

    // out dtype follows disp_up's detected mode
    k_final<<<cdiv(NFULL, 256), 256, 0, stream>>>(du2, vu2, disp_up, t_in, d_out, (long)out_size, modes + 1);
    k_fill_tail<<<2048, 256, 0, stream>>>(d_out, (long)vf_elems, (long)out_size, modes + 1);
}

// Round 12
// 2180.859 us; speedup vs baseline: 1.6531x; 1.0114x over previous
//
#include <hip/hip_runtime.h>
#include <hip/hip_bf16.h>

typedef __hip_bfloat16 bf16;
typedef unsigned short u16;
typedef unsigned int u32;

#define D1c 48
#define H1c 40
#define W1c 48
#define NHALF 92160L
#define D2c 96
#define H2c 80
#define W2c 96
#define NFULL 737280L
#define S1 368
#define S2 128
#define RG 512

#define NX1 (NHALF * S1)
#define NX2 (NFULL * S2)
#define NCTX16 (NHALF * 16)
#define N3H (NHALF * 3)
#define N3F (NFULL * 3)
#define GUARD 1024

typedef __attribute__((ext_vector_type(8))) short s8v;
typedef __attribute__((ext_vector_type(4))) float f4v;

__device__ __forceinline__ float bf2f(bf16 v){ return __bfloat162float(v); }
__device__ __forceinline__ float sf(float v){ return (v == v && fabsf(v) < 1e30f) ? v : 0.f; }
__device__ __forceinline__ bf16 f2bf(float v){ return __float2bfloat16(sf(v)); }
__device__ __forceinline__ u16 f2bfu(float v){ bf16 b = f2bf(v); return *(u16*)&b; }
__device__ __forceinline__ long cl(long i, long n){ i = i < 0 ? 0 : i; return i >= n ? n - 1 : i; }
// mode-dispatched input load: 0 = bf16, 1 = f32
__device__ __forceinline__ float gld(const void* p, long i, int mode){
    return mode ? sf(((const float*)p)[i]) : sf(bf2f(((const bf16*)p)[i]));
}

// ---------------- dtype detection: one block per input ---------------------
__global__ void k_detect(const void* p, long nelem, int* flag) {
    long N = nelem < 4096 ? nelem : 4096;
    int tid = threadIdx.x;
    int nb = 0, nf = 0;
    for (long i = tid; i < N; i += 256) {
        float v = bf2f(((const bf16*)p)[i]);
        if (v == v && fabsf(v) <= 1e4f) nb++;
    }
    long M = N / 2;
    for (long i = tid; i < M; i += 256) {
        float v = ((const float*)p)[i];
        if (v == v && fabsf(v) <= 1e4f) nf += 2;
    }
    __shared__ int sb[256], sq[256];
    sb[tid] = nb; sq[tid] = nf;
    __syncthreads();
    for (int t = 128; t; t >>= 1) {
        if (tid < t) { sb[tid] += sb[tid + t]; sq[tid] += sq[tid + t]; }
        __syncthreads();
    }
    if (tid == 0) *flag = (sb[0] >= sq[0]) ? 0 : 1;
}

// ---------------- fills -----------------------------------------------------
__global__ void k_fill(u16* __restrict__ p, long n, u16 val) {
    long i = (long)blockIdx.x * 256 + threadIdx.x;
    long stride = (long)gridDim.x * 256;
    for (; i < n; i += stride) p[i] = val;
}
__global__ void k_fill_tail(void* out, long vf, long out_n, const int* __restrict__ modep) {
    int mode = *modep;
    long n = out_n - vf;
    if (n <= 0) return;
    long i = (long)blockIdx.x * 256 + threadIdx.x;
    long stride = (long)gridDim.x * 256;
    if (mode) { float* p = (float*)out + vf; for (; i < n; i += stride) p[i] = 0.f; }
    else      { u16*   p = (u16*)out + vf;   for (; i < n; i += stride) p[i] = 0; }
}

// ------- weight transpose: (co,ci,tap) -> (tap,ci,co) f32 (small convs) ----
__global__ void k_wt(const void* __restrict__ w, float* __restrict__ wt,
                     int Cin, int Cout, const int* __restrict__ modep) {
    int mode = *modep;
    long n = (long)Cin * Cout * 27;
    long i = (long)blockIdx.x * 256 + threadIdx.x;
    if (i >= n) return;
    int tap = (int)(i % 27); long r = i / 27;
    int ci = (int)(r % Cin); int co = (int)(r / Cin);
    wt[cl(((long)tap * Cin + ci) * Cout + co, n)] = gld(w, cl(i, n), mode);
}

// ------- MFMA weight repack: (co,ci,tap) -> [tap][chunk][co][32] bf16 ------
// zero-padded for ci >= Cin (Cin tails)
__global__ void k_wtb(const void* __restrict__ w, bf16* __restrict__ wtb,
                      int Cin, int Cout, int nchunk, const int* __restrict__ modep) {
    int mode = *modep;
    long n = 27L * nchunk * Cout * 32;
    long i = (long)blockIdx.x * 256 + threadIdx.x;
    if (i >= n) return;
    int kk = (int)(i & 31);
    long r = i >> 5;
    int co = (int)(r % Cout); r /= Cout;
    int ch = (int)(r % nchunk); int tap = (int)(r / nchunk);
    int ci = ch * 32 + kk;
    float v = (ci < Cin) ? gld(w, ((long)co * Cin + ci) * 27 + tap, mode) : 0.f;
    wtb[i] = f2bf(v);
}

// ------- channel-first [C][N] -> channel-last columns, LDS-transposed ------
template<int C>
__global__ __launch_bounds__(256) void k_tcl_t(const void* __restrict__ in,
                                               u16* __restrict__ out, long nout,
                                               int col0, long N, int stride,
                                               const int* __restrict__ modep) {
    __shared__ u16 lds[256 * C];
    const int mode = *modep;
    const int tid = threadIdx.x;
    const long n0 = (long)blockIdx.x * 256;
    #pragma unroll
    for (int c = 0; c < C; ++c)
        lds[tid * C + c] = f2bfu(gld(in, (long)c * N + n0 + tid, mode));
    __syncthreads();
    #pragma unroll
    for (int k = 0; k < C; ++k) {
        const int e = tid + k * 256;
        const int row = e / C, col = e - row * C;
        out[cl((n0 + row) * (long)stride + col0 + col, nout)] = lds[e];
    }
}

// ------- channel-first [C][N] -> dense channel-last f32 [N][C] -------------
__global__ void k_tclf(const void* __restrict__ in, float* __restrict__ out,
                       int C, long N, const int* __restrict__ modep) {
    int mode = *modep;
    long n = (long)blockIdx.x * 256 + threadIdx.x;
    if (n >= N) return;
    for (int c = 0; c < C; ++c)
        out[n * C + c] = gld(in, (long)c * N + n, mode);
}

// ------- antialiased x0.5 downsample taps ----------------------------------
__device__ __forceinline__ void down_taps(int i, int n_in, int j[4], float w[4]) {
    float s = 0.f;
    for (int k = 0; k < 4; ++k) {
        int jj = 2 * i - 1 + k;
        bool valid = (jj >= 0 && jj < n_in);
        j[k] = valid ? jj : 0;
        float b = (k == 0 || k == 3) ? 1.f : 3.f;
        w[k] = valid ? b : 0.f;
        s += w[k];
    }
    float inv = 1.f / fmaxf(s, 1e-6f);
    for (int k = 0; k < 4; ++k) w[k] *= inv;
}

// disp = resize(disp_up,0.5)*0.5 -> disph f32 + xin1 cols 221..223
__global__ void k_down(const void* __restrict__ dispup, float* __restrict__ disph,
                       bf16* __restrict__ xin1, const int* __restrict__ modep) {
    int mode = *modep;
    long p = (long)blockIdx.x * 256 + threadIdx.x;
    if (p >= NHALF) return;
    int x = (int)(p % W1c), y = (int)((p / W1c) % H1c), z = (int)(p / (W1c * H1c));
    int jz[4], jy[4], jx[4]; float wz[4], wy[4], wx[4];
    down_taps(z, D2c, jz, wz); down_taps(y, H2c, jy, wy); down_taps(x, W2c, jx, wx);
    for (int c = 0; c < 3; ++c) {
        float acc = 0.f;
        for (int a = 0; a < 4; ++a) {
            if (wz[a] == 0.f) continue;
            for (int b = 0; b < 4; ++b) {
                if (wy[b] == 0.f) continue;
                float wzy = wz[a] * wy[b];
                long base = (long)c * NFULL + ((long)jz[a] * H2c + jy[b]) * W2c;
                for (int d = 0; d < 4; ++d) {
                    if (wx[d] == 0.f) continue;
                    acc += wzy * wx[d] * gld(dispup, cl(base + jx[d], 3 * NFULL), mode);
                }
            }
        }
        acc = sf(acc * 0.5f);
        disph[cl(p * 3 + c, N3H)] = acc;
        xin1[cl(p * (long)S1 + 221 + c, NX1)] = f2bf(acc);
    }
}

// ------- trilinear warp, channel-first INPUT volume, zero pad --------------
// LDS-transposed write phase (round-10). Requires N % 256 == 0.
template<int C>
__global__ __launch_bounds__(256) void k_warp_cf(
        const void* __restrict__ vol, long nvol,
        const float* __restrict__ coords, long ncoords,
        u16* __restrict__ dst, long ndst, int dstride, int col0,
        int D, int H, int W, const int* __restrict__ modep) {
    __shared__ u16 lw[256 * C];
    int mode = *modep;
    const long p0 = (long)blockIdx.x * 256;
    const long p = p0 + threadIdx.x;
    int x = (int)(p % W), y = (int)((p / W) % H), z = (int)(p / ((long)W * H));
    float cz = z + sf(coords[cl(p * 3, ncoords)]);
    float cy = y + sf(coords[cl(p * 3 + 1, ncoords)]);
    float cx = x + sf(coords[cl(p * 3 + 2, ncoords)]);
    const long N = (long)D * H * W;
    float acc[C];
    for (int c = 0; c < C; ++c) acc[c] = 0.f;
    float z0f = floorf(cz), y0f = floorf(cy), x0f = floorf(cx);
    int z0 = (int)z0f, y0 = (int)y0f, x0 = (int)x0f;
    float fz = cz - z0f, fy = cy - y0f, fx = cx - x0f;
    for (int dz = 0; dz < 2; ++dz) {
        int zi = z0 + dz; if (zi < 0 || zi >= D) continue;
        float wz = dz ? fz : 1.f - fz;
        for (int dy = 0; dy < 2; ++dy) {
            int yi = y0 + dy; if (yi < 0 || yi >= H) continue;
            float wzy = wz * (dy ? fy : 1.f - fy);
            for (int dx = 0; dx < 2; ++dx) {
                int xi = x0 + dx; if (xi < 0 || xi >= W) continue;
                float w = wzy * (dx ? fx : 1.f - fx);
                long idx = (long)(zi * H + yi) * W + xi;
                for (int c = 0; c < C; ++c) acc[c] += w * gld(vol, cl((long)c * N + idx, nvol), mode);
            }
        }
    }
    #pragma unroll
    for (int c = 0; c < C; ++c) lw[threadIdx.x * C + c] = f2bfu(acc[c]);
    __syncthreads();
    #pragma unroll
    for (int k = 0; k < C; ++k) {
        const int e = threadIdx.x + k * 256;
        const int row = e / C, col = e - row * C;
        dst[cl((p0 + row) * (long)dstride + col0 + col, ndst)] = lw[e];
    }
}

// ------- trilinear warp, dense channel-last f32 source (C=16) --------------
__global__ __launch_bounds__(256) void k_warp_cl16(const float* __restrict__ vol,
                                                   const float* __restrict__ coords,
                                                   u16* __restrict__ dst) {
    __shared__ u16 lw[256 * 16];
    const long p0 = (long)blockIdx.x * 256;
    const long p = p0 + threadIdx.x;
    int x = (int)(p % W2c), y = (int)((p / W2c) % H2c), z = (int)(p / (W2c * H2c));
    float cz = z + sf(coords[p * 3]);
    float cy = y + sf(coords[p * 3 + 1]);
    float cx = x + sf(coords[p * 3 + 2]);
    float acc[16];
    #pragma unroll
    for (int c = 0; c < 16; ++c) acc[c] = 0.f;
    float z0f = floorf(cz), y0f = floorf(cy), x0f = floorf(cx);
    int z0 = (int)z0f, y0 = (int)y0f, x0 = (int)x0f;
    float fz = cz - z0f, fy = cy - y0f, fx = cx - x0f;
    for (int dz = 0; dz < 2; ++dz) {
        int zi = z0 + dz; if (zi < 0 || zi >= D2c) continue;
        float wz = dz ? fz : 1.f - fz;
        for (int dy = 0; dy < 2; ++dy) {
            int yi = y0 + dy; if (yi < 0 || yi >= H2c) continue;
            float wzy = wz * (dy ? fy : 1.f - fy);
            for (int dx = 0; dx < 2; ++dx) {
                int xi = x0 + dx; if (xi < 0 || xi >= W2c) continue;
                float w = wzy * (dx ? fx : 1.f - fx);
                const float4* q = (const float4*)(vol + ((long)(zi * H2c + yi) * W2c + xi) * 16);
                float4 a0 = q[0], a1 = q[1], a2 = q[2], a3 = q[3];
                acc[0]  += w * a0.x; acc[1]  += w * a0.y; acc[2]  += w * a0.z; acc[3]  += w * a0.w;
                acc[4]  += w * a1.x; acc[5]  += w * a1.y; acc[6]  += w * a1.z; acc[7]  += w * a1.w;
                acc[8]  += w * a2.x; acc[9]  += w * a2.y; acc[10] += w * a2.z; acc[11] += w * a2.w;
                acc[12] += w * a3.x; acc[13] += w * a3.y; acc[14] += w * a3.z; acc[15] += w * a3.w;
            }
        }
    }
    #pragma unroll
    for (int c = 0; c < 16; ++c) lw[threadIdx.x * 16 + c] = f2bfu(acc[c]);
    __syncthreads();
    #pragma unroll
    for (int k = 0; k < 16; ++k) {
        const int e = threadIdx.x + k * 256;
        const int row = e >> 4, col = e & 15;
        dst[(p0 + row) * (long)S2 + 43 + col] = lw[e];
    }
}

// ------- two-stage deterministic reduction (sum, sumsq) --------------------
__global__ void k_reduce_cl(const void* __restrict__ base, long nbase, long rows,
                            int stride, int col0, int cn, double* __restrict__ part,
                            const int* __restrict__ modep) {
    int mode = *modep;
    long total = rows * cn;
    double s = 0.0, q = 0.0;
    long i = (long)blockIdx.x * 256 + threadIdx.x;
    long gs = (long)gridDim.x * 256;
    for (; i < total; i += gs) {
        long r = i / cn; int c = (int)(i - r * cn);
        float f = gld(base, cl(r * (long)stride + col0 + c, nbase), mode);
        s += f; q += (double)f * f;
    }
    __shared__ double ls[256], lq[256];
    ls[threadIdx.x] = s; lq[threadIdx.x] = q;
    __syncthreads();
    for (int t = 128; t; t >>= 1) {
        if (threadIdx.x < t) { ls[threadIdx.x] += ls[threadIdx.x + t]; lq[threadIdx.x] += lq[threadIdx.x + t]; }
        __syncthreads();
    }
    if (threadIdx.x == 0) { part[cl(blockIdx.x * 2, RG * 2)] = ls[0]; part[cl(blockIdx.x * 2 + 1, RG * 2)] = lq[0]; }
}

__global__ void k_stats2(const double* __restrict__ pa, const double* __restrict__ pb,
                         double n, double C, double* __restrict__ outm) {
    __shared__ double ls[256], lq[256];
    double s = 0.0, q = 0.0;
    for (int i = threadIdx.x; i < RG; i += 256) { s += pa[i * 2]; q += pa[i * 2 + 1]; }
    ls[threadIdx.x] = s; lq[threadIdx.x] = q;
    __syncthreads();
    for (int t = 128; t; t >>= 1) {
        if (threadIdx.x < t) { ls[threadIdx.x] += ls[threadIdx.x + t]; lq[threadIdx.x] += lq[threadIdx.x + t]; }
        __syncthreads();
    }
    double sa = ls[0], qa = lq[0];
    __syncthreads();
    s = 0.0; q = 0.0;
    for (int i = threadIdx.x; i < RG; i += 256) { s += pb[i * 2]; q += pb[i * 2 + 1]; }
    ls[threadIdx.x] = s; lq[threadIdx.x] = q;
    __syncthreads();
    for (int t = 128; t; t >>= 1) {
        if (threadIdx.x < t) { ls[threadIdx.x] += ls[threadIdx.x + t]; lq[threadIdx.x] += lq[threadIdx.x + t]; }
        __syncthreads();
    }
    if (threadIdx.x == 0) {
        double sb = ls[0], qb = lq[0];
        double va = (qa - sa * sa / n) / (n - 1.0);
        double vb = (qb - sb * sb / n) / (n - 1.0);
        va = va > 0.0 ? va : 0.0;
        vb = vb > 0.0 ? vb : 0.0;
        double sd = 0.5 * (sqrt(va) + sqrt(vb));
        sd = sd < 1e-6 ? 1e-6 : (sd > 1e9 ? 1e9 : sd);
        outm[0] = 0.5 * (sa / n + sb / n);
        outm[1] = 1.0 / (sd * sd * C);
    }
}

// ------- cost volume 1 (md=2, C=32), LDS-tiled -> xin1 cols 0..124 ---------
__global__ __launch_bounds__(128, 2) void k_cv1_t(bf16* __restrict__ xin1,
                                                  const double* __restrict__ red) {
    __shared__ bf16 lds[8][8][12][32];   // [plane z0-2..z0+5][row y0-2..y0+5][x0-2..x0+9][ch]
    const int tid = threadIdx.x;
    const int xyt = (int)(blockIdx.x % 60u);     // 6 x-tiles * 10 y-tiles
    const int zg  = (int)(blockIdx.x / 60u);     // 12 z-groups
    const int x0 = (xyt % 6) * 8;
    const int y0 = (xyt / 6) * 4;
    const int z0 = zg * 4;
    const u16* src16 = (const u16*)xin1;

    for (int f = tid; f < 8 * 8 * 12; f += 128) {
        int xx = f % 12, rest = f / 12;
        int yy = rest % 8, pl = rest / 8;
        int z2 = z0 - 2 + pl, y2 = y0 - 2 + yy, x2 = x0 - 2 + xx;
        u32 pk[16];
        #pragma unroll
        for (int c = 0; c < 16; ++c) pk[c] = 0;
        if ((unsigned)z2 < (unsigned)D1c && (unsigned)y2 < (unsigned)H1c && (unsigned)x2 < (unsigned)W1c) {
            long rb = (((long)z2 * H1c + y2) * W1c + x2) * S1 + 157;
            #pragma unroll
            for (int c = 0; c < 16; ++c)
                pk[c] = (u32)src16[rb + 2 * c] | ((u32)src16[rb + 2 * c + 1] << 16);
        }
        #pragma unroll
        for (int qq = 0; qq < 4; ++qq) {
            uint4 q = { pk[qq * 4], pk[qq * 4 + 1], pk[qq * 4 + 2], pk[qq * 4 + 3] };
            *(uint4*)&lds[pl][yy][xx][qq * 8] = q;
        }
    }
    __syncthreads();

    const float m = sf((float)red[0]), mult = sf((float)red[1]);
    const int tx = tid & 7, ty = (tid >> 3) & 3, tz = tid >> 5;
    const int x = x0 + tx, y = y0 + ty, z = z0 + tz;
    const long p = ((long)z * H1c + y) * W1c + x;

    float fm[32], S = 0.f;
    #pragma unroll
    for (int c = 0; c < 32; ++c) { fm[c] = sf(bf2f(xin1[p * (long)S1 + 125 + c])) - m; S += fm[c]; }

    #pragma unroll 1
    for (int dz = 0; dz < 5; ++dz) {
        const int z2 = z + dz - 2;
        u16 hg[25];
        #pragma unroll
        for (int oo = 0; oo < 25; ++oo) {
            const int dy = oo / 5, dx = oo % 5;
            const int y2 = y + dy - 2, x2 = x + dx - 2;
            float cost = 0.f;
            if ((unsigned)z2 < (unsigned)D1c && (unsigned)y2 < (unsigned)H1c && (unsigned)x2 < (unsigned)W1c) {
                union { uint4 u[4]; bf16 h[32]; } wv;
                #pragma unroll
                for (int qq = 0; qq < 4; ++qq)
                    wv.u[qq] = *(const uint4*)&lds[tz + dz][ty + dy][tx + dx][qq * 8];
                float dot = 0.f;
                #pragma unroll
                for (int c = 0; c < 32; ++c) dot += fm[c] * sf(bf2f(wv.h[c]));
                dot -= m * S;
                cost = dot * mult;
                cost = cost >= 0.f ? cost : 0.05f * cost;
            }
            hg[oo] = f2bfu(cost);
        }
        u16* dstp = (u16*)(xin1 + p * (long)S1) + dz * 25;
        #pragma unroll
        for (int oo = 0; oo < 25; ++oo) dstp[oo] = hg[oo];
    }
}

// ------- cost volume 2 (md=1, C=16), LDS-tiled -> xin2 cols 0..26 ----------
__global__ __launch_bounds__(256, 2) void k_cv2_t(bf16* __restrict__ xin2,
                                                  const double* __restrict__ red) {
    __shared__ bf16 lds[6][18][18][16];
    const int tid = threadIdx.x;
    const int xyt = (int)(blockIdx.x % 30u);     // 6 x-tiles * 5 y-tiles
    const int zg  = (int)(blockIdx.x / 30u);     // 24 z-groups
    const int x0 = (xyt % 6) * 16;
    const int y0 = (xyt / 6) * 16;
    const int z0 = zg * 4;
    const u16* src16 = (const u16*)xin2;

    for (int f = tid; f < 6 * 324; f += 256) {
        int pl = f / 324, r = f - pl * 324;
        int yy = r / 18, xx = r - yy * 18;
        int z2 = z0 - 1 + pl, y2 = y0 - 1 + yy, x2 = x0 - 1 + xx;
        u32 pk[8];
        #pragma unroll
        for (int c = 0; c < 8; ++c) pk[c] = 0;
        if ((unsigned)z2 < (unsigned)D2c && (unsigned)y2 < (unsigned)H2c && (unsigned)x2 < (unsigned)W2c) {
            long rb = (((long)z2 * H2c + y2) * W2c + x2) * S2 + 43;
            #pragma unroll
            for (int c = 0; c < 8; ++c)
                pk[c] = (u32)src16[rb + 2 * c] | ((u32)src16[rb + 2 * c + 1] << 16);
        }
        uint4 q0 = { pk[0], pk[1], pk[2], pk[3] };
        uint4 q1 = { pk[4], pk[5], pk[6], pk[7] };
        *(uint4*)&lds[pl][yy][xx][0] = q0;
        *(uint4*)&lds[pl][yy][xx][8] = q1;
    }
    __syncthreads();

    const float m = sf((float)red[2]), mult = sf((float)red[3]);
    const int tx = tid & 15, ty = tid >> 4;
    const int x = x0 + tx, y = y0 + ty;

    #pragma unroll 1
    for (int zz = 0; zz < 4; ++zz) {
        const int z = z0 + zz;
        const long p = ((long)z * H2c + y) * W2c + x;
        float fm[16], S = 0.f;
        #pragma unroll
        for (int c = 0; c < 16; ++c) {
            fm[c] = sf(bf2f(xin2[p * (long)S2 + 27 + c])) - m;
            S += fm[c];
        }
        union { u16 h[28]; uint4 q[3]; u32 w[14]; } r;
        #pragma unroll
        for (int o = 0; o < 27; ++o) {
            const int dz = o / 9, dy = (o / 3) % 3, dx = o % 3;
            const int z2 = z + dz - 1, y2 = y + dy - 1, x2 = x + dx - 1;
            float cost = 0.f;
            if ((unsigned)z2 < (unsigned)D2c && (unsigned)y2 < (unsigned)H2c && (unsigned)x2 < (unsigned)W2c) {
                union { uint4 u[2]; bf16 h[16]; } wv;
                wv.u[0] = *(const uint4*)&lds[zz + dz][ty + dy][tx + dx][0];
                wv.u[1] = *(const uint4*)&lds[zz + dz][ty + dy][tx + dx][8];
                float dot = 0.f;
                #pragma unroll
                for (int c = 0; c < 16; ++c) dot += fm[c] * sf(bf2f(wv.h[c]));
                dot -= m * S;
                cost = dot * mult;
                cost = cost >= 0.f ? cost : 0.05f * cost;
            }
            r.h[o] = f2bfu(cost);
        }
        r.h[27] = 0;
        u16* dstp = (u16*)(xin2 + p * (long)S2);
        *(uint4*)dstp        = r.q[0];
        *(uint4*)(dstp + 8)  = r.q[1];
        *(uint4*)(dstp + 16) = r.q[2];
        *(u32*)(dstp + 24)   = r.w[12];
        dstp[26] = r.h[26];
    }
}

// ------- MFMA implicit-GEMM 3x3x3 conv, channel-last, LDS-staged -----------
// Round-12: async stage via global_load_lds (width 16). Round-11 removed all
// bank conflicts yet saved only 8us -> conflicts weren't the critical path;
// the stage (div/mod VALU + register round-trip + explicit ds_write for
// ~2600 quarters/ch) serialized against consume was. global_load_lds deletes
// the round-trip and ds_writes and queues loads deeply. LDS dest is linear
// (lane-contiguous quarters, wave-uniform base + lane*16); the round-11 bank
// swizzle survives by PRE-SWIZZLING the global source quarter
// qs = (q&3) ^ ((vx>>1)&3) (m173 pattern; same involution; consume's aoff
// swizzled reads unchanged -> conflicts stay 0). All addrs 16B-aligned
// (SS*2 in {736,256}, both multiples of 16).
template<int NT, int NCH, int COUT, int M, int SS, int DD, int HH, int WW>
__global__ __launch_bounds__(256, 3) void k_conv_mfma(
        const bf16* __restrict__ src,
        const bf16* __restrict__ wtb, const void* __restrict__ bias,
        bf16* __restrict__ dst, int dstride, int dcol0,
        float slope, const int* __restrict__ bmodep) {
    const int bmode = *bmodep;
    const int tid = threadIdx.x;
    const int wave = tid >> 6, lane = tid & 63;
    const int quad = lane >> 4, nlo = lane & 15;
    constexpr long HW = (long)HH * WW;
    constexpr int PL = M + 2;            // staged planes
    constexpr int NXB = WW / 16;
    constexpr int NYB = HH / 4;          // 4 rows per block (one per wave)
    constexpr int NXY = NXB * NYB;
    __shared__ bf16 lds[PL][6][18][32];  // M=4: 41472 B, M=2: 27648 B
    bf16* lb = &lds[0][0][0][0];

    // bijective chunked swizzle (gridDim.x % 8 == 0 by construction)
    const u32 per = gridDim.x >> 3;
    const u32 bid = (blockIdx.x & 7u) * per + (blockIdx.x >> 3);
    const int xyb = (int)(bid % (u32)NXY);
    const int zg  = (int)(bid / (u32)NXY);
    const int x0 = (xyb % NXB) * 16;
    const int y0 = (xyb / NXB) * 4;
    const int z0 = zg * M;

    f4v acc[M][NT];
    #pragma unroll
    for (int m = 0; m < M; ++m) {
        #pragma unroll
        for (int nt = 0; nt < NT; ++nt) {
            float bv = gld(bias, nt * 16 + nlo, bmode);
            acc[m][nt][0] = bv; acc[m][nt][1] = bv; acc[m][nt][2] = bv; acc[m][nt][3] = bv;
        }
    }

    const u32 selLo = (x0 == 0       && nlo == 0)  ? 0u : 0xFFFFFFFFu;
    const u32 selHi = (x0 == WW - 16 && nlo == 15) ? 0u : 0xFFFFFFFFu;

    u32 zm[PL];
    #pragma unroll
    for (int p = 0; p < PL; ++p) {
        const int z2 = z0 - 1 + p;
        zm[p] = ((unsigned)z2 < (unsigned)DD) ? 0xFFFFFFFFu : 0u;
    }
    u32 ym[3];
    #pragma unroll
    for (int dyi = 0; dyi < 3; ++dyi) {
        const int y2 = y0 + wave + dyi - 1;
        ym[dyi] = ((unsigned)y2 < (unsigned)HH) ? 0xFFFFFFFFu : 0u;
    }
    // per-dxi swizzled read offsets within a (p,rr) row-block (bf16 units)
    int aoff[3];
    #pragma unroll
    for (int dxi = 0; dxi < 3; ++dxi) {
        const int vx = nlo + dxi;
        aoff[dxi] = vx * 32 + (quad ^ ((vx >> 1) & 3)) * 8;
    }

    constexpr int NQ = PL * 6 * 18 * 4;      // 16B quarters to stage per ch
    constexpr int KQ = (NQ + 255) / 256;

    const bf16* bp = wtb + (long)nlo * 32 + quad * 8;

    #pragma unroll 1
    for (int ch = 0; ch < NCH; ++ch) {
        __syncthreads();                     // previous consume done
        #pragma unroll
        for (int k = 0; k < KQ; ++k) {
            const int q = tid + k * 256;
            if (q < NQ) {
                const int f = q >> 2;
                const int vx = f % 18;
                const int rest = f / 18;
                const int r = rest % 6;
                const int lp = rest / 6;
                const int qs = (q & 3) ^ ((vx >> 1) & 3);   // pre-swizzled src
                int zc = z0 - 1 + lp; zc = zc < 0 ? 0 : (zc >= DD ? DD - 1 : zc);
                int yc = y0 - 1 + r;  yc = yc < 0 ? 0 : (yc >= HH ? HH - 1 : yc);
                int xc = x0 - 1 + vx; xc = xc < 0 ? 0 : (xc >= WW ? WW - 1 : xc);
                const bf16* gp = src + ((long)zc * HW + (long)yc * WW + xc) * (long)SS + ch * 32 + qs * 8;
                __builtin_amdgcn_global_load_lds(
                    (const __attribute__((address_space(1))) void*)gp,
                    (__attribute__((address_space(3))) void*)(lb + (long)q * 8),
                    16, 0, 0);
            }
        }
        __syncthreads();                     // stage visible to all waves

        #pragma unroll 1
        for (int dyi = 0; dyi < 3; ++dyi) {
            if (!ym[dyi]) continue;          // wave-uniform; no barriers inside
            const int rr = wave + dyi;
            #pragma unroll
            for (int dxi = 0; dxi < 3; ++dxi) {
                union U { uint4 u; s8v v; } b[3][NT];
                #pragma unroll
                for (int dz = 0; dz < 3; ++dz)
                    #pragma unroll
                    for (int nt = 0; nt < NT; ++nt)
                        b[dz][nt].u = *(const uint4*)(bp +
                            (((long)(dz * 9 + dyi * 3 + dxi) * NCH + ch) * COUT) * 32 + nt * 512);
                const u32 sx = (dxi == 0) ? selLo : (dxi == 2 ? selHi : 0xFFFFFFFFu);
                #pragma unroll
                for (int p = 0; p < PL; ++p) {
                    union U2 { uint4 u; s8v v; } a;
                    a.u = *(const uint4*)(lb + ((p * 6 + rr) * 18) * 32 + aoff[dxi]);
                    const u32 mm = zm[p] & sx;
                    a.u.x &= mm; a.u.y &= mm; a.u.z &= mm; a.u.w &= mm;
                    #pragma unroll
                    for (int dz = 0; dz < 3; ++dz) {
                        const int m = p - dz;
                        if (m < 0 || m >= M) continue;   // compile-time prune
                        #pragma unroll
                        for (int nt = 0; nt < NT; ++nt)
                            acc[m][nt] = __builtin_amdgcn_mfma_f32_16x16x32_bf16(a.v, b[dz][nt].v, acc[m][nt], 0, 0, 0);
                    }
                }
            }
        }
    }

    const int yw = y0 + wave;
    #pragma unroll
    for (int m = 0; m < M; ++m) {
        const long vbase = (long)(z0 + m) * HW + (long)yw * WW + x0 + quad * 4;
        #pragma unroll
        for (int nt = 0; nt < NT; ++nt) {
            #pragma unroll
            for (int reg = 0; reg < 4; ++reg) {
                float v = acc[m][nt][reg];
                v = v >= 0.f ? v : v * slope;
                dst[(vbase + reg) * (long)dstride + dcol0 + nt * 16 + nlo] = f2bf(v);
            }
        }
    }
}

// ------- tiled small conv: Cin=16 -> Cout=3, linear, f32 out ---------------
template<int ZS>
__global__ __launch_bounds__(256, 2) void k_conv_small_t(
        const bf16* __restrict__ src, int sstride, int scol0,
        const float* __restrict__ wt, const void* __restrict__ bias,
        float* __restrict__ dst, int D, int H, int W,
        const int* __restrict__ bmodep) {
    const int bmode = *bmodep;
    __shared__ bf16 lds[ZS + 2][18][18][16];   // ZS=4: 62208 B
    const int tid = threadIdx.x;
    const int gx = W >> 4;                      // W % 16 == 0
    const int gy = (H + 15) >> 4;
    const int xyt = (int)(blockIdx.x % (u32)(gx * gy));
    const int zg  = (int)(blockIdx.x / (u32)(gx * gy));
    const int x0 = (xyt % gx) << 4;
    const int y0 = (xyt / gx) << 4;
    const int z0 = zg * ZS;

    // ---- stage (ZS+2) planes of 18x18 fragments (zeros outside volume) ----
    const int NFRAG = (ZS + 2) * 324;
    for (int f = tid; f < NFRAG; f += 256) {
        int pl = f / 324, r = f - pl * 324;
        int yy = r / 18, xx = r - yy * 18;
        int z2 = z0 - 1 + pl, y2 = y0 - 1 + yy, x2 = x0 - 1 + xx;
        uint4 lo = {0, 0, 0, 0}, hi = {0, 0, 0, 0};
        if ((unsigned)z2 < (unsigned)D && (unsigned)y2 < (unsigned)H && (unsigned)x2 < (unsigned)W) {
            const bf16* p = src + ((long)(z2 * H + y2) * W + x2) * (long)sstride + scol0;
            lo = *(const uint4*)p;
            hi = *(const uint4*)(p + 8);
        }
        *(uint4*)&lds[pl][yy][xx][0] = lo;
        *(uint4*)&lds[pl][yy][xx][8] = hi;
    }
    __syncthreads();

    const int ty = tid >> 4, tx = tid & 15;
    const bool live = (y0 + ty) < H;

    float a0[ZS], a1[ZS], a2[ZS];
    {
        float b0 = gld(bias, 0, bmode), b1 = gld(bias, 1, bmode), b2 = gld(bias, 2, bmode);
        #pragma unroll
        for (int zz = 0; zz < ZS; ++zz) { a0[zz] = b0; a1[zz] = b1; a2[zz] = b2; }
    }

    #pragma unroll 1
    for (int tap = 0; tap < 27; ++tap) {
        const int dz = tap / 9, dy = (tap / 3) % 3, dx = tap % 3;
        const float* w = wt + tap * 48;          // uniform -> scalar loads
        float wv[48];
        #pragma unroll
        for (int k = 0; k < 48; ++k) wv[k] = w[k];
        #pragma unroll
        for (int zz = 0; zz < ZS; ++zz) {
            union { uint4 u[2]; bf16 h[16]; } fr;
            fr.u[0] = *(const uint4*)&lds[zz + dz][ty + dy][tx + dx][0];
            fr.u[1] = *(const uint4*)&lds[zz + dz][ty + dy][tx + dx][8];
            #pragma unroll
            for (int c = 0; c < 16; ++c) {
                float f = bf2f(fr.h[c]);
                a0[zz] += f * wv[c * 3];
                a1[zz] += f * wv[c * 3 + 1];
                a2[zz] += f * wv[c * 3 + 2];
            }
        }
    }

    if (!live) return;
    #pragma unroll
    for (int zz = 0; zz < ZS; ++zz) {
        long p = ((long)(z0 + zz) * H + (y0 + ty)) * W + (x0 + tx);
        dst[p * 3]     = sf(a0[zz]);
        dst[p * 3 + 1] = sf(a1[zz]);
        dst[p * 3 + 2] = sf(a2[zz]);
    }
}

// ------- x2 upsample taps ---------------------------------------------------
__device__ __forceinline__ void up_taps(int i, int n, int& j0, int& j1, float& w0, float& w1) {
    if (i & 1) { j0 = i >> 1; j1 = j0 + 1; w0 = 0.75f; w1 = 0.25f; if (j1 >= n) { j1 = j0; w0 = 1.f; w1 = 0.f; } }
    else { j1 = i >> 1; j0 = j1 - 1; w0 = 0.25f; w1 = 0.75f; if (j0 < 0) { j0 = j1; w0 = 0.f; w1 = 1.f; } }
}

// ctx16 [NHALF][16] -> xin2 cols 59..74 (LDS-transposed coalesced writes)
__global__ __launch_bounds__(256) void k_up_ctx(const bf16* __restrict__ in,
                                                u16* __restrict__ xin2) {
    __shared__ u16 lw[256 * 16];
    const long p0 = (long)blockIdx.x * 256;
    const long p = p0 + threadIdx.x;
    int x = (int)(p % W2c), y = (int)((p / W2c) % H2c), z = (int)(p / (W2c * H2c));
    int jz0, jz1, jy0, jy1, jx0, jx1; float wz0, wz1, wy0, wy1, wx0, wx1;
    up_taps(z, D1c, jz0, jz1, wz0, wz1);
    up_taps(y, H1c, jy0, jy1, wy0, wy1);
    up_taps(x, W1c, jx0, jx1, wx0, wx1);
    float acc[16];
    for (int c = 0; c < 16; ++c) acc[c] = 0.f;
    int jzs[2] = { jz0, jz1 }; float wzs[2] = { wz0, wz1 };
    int jys[2] = { jy0, jy1 }; float wys[2] = { wy0, wy1 };
    int jxs[2] = { jx0, jx1 }; float wxs[2] = { wx0, wx1 };
    for (int a = 0; a < 2; ++a) {
        if (wzs[a] == 0.f) continue;
        for (int b = 0; b < 2; ++b) {
            if (wys[b] == 0.f) continue;
            float wzy = wzs[a] * wys[b];
            for (int d = 0; d < 2; ++d) {
                if (wxs[d] == 0.f) continue;
                float w = wzy * wxs[d];
                long rb = ((long)(jzs[a] * H1c + jys[b]) * W1c + jxs[d]) * 16;
                for (int c = 0; c < 16; ++c) acc[c] += w * bf2f(in[cl(rb + c, NCTX16)]);
            }
        }
    }
    #pragma unroll
    for (int c = 0; c < 16; ++c) lw[threadIdx.x * 16 + c] = f2bfu(acc[c]);
    __syncthreads();
    #pragma unroll
    for (int k = 0; k < 16; ++k) {
        const int e = threadIdx.x + k * 256;
        const int row = e >> 4, col = e & 15;
        xin2[(p0 + row) * (long)S2 + 59 + col] = lw[e];
    }
}

// fused: velup = 2*up(vel1); du2 = warp(disp_up, velup) + velup; xin2 75..77
__global__ void k_warp_dispup(const void* __restrict__ dispup, const float* __restrict__ vel1,
                              float* __restrict__ du2, bf16* __restrict__ xin2,
                              const int* __restrict__ modep) {
    int mode = *modep;
    long p = (long)blockIdx.x * 256 + threadIdx.x;
    if (p >= NFULL) return;
    int x = (int)(p % W2c), y = (int)((p / W2c) % H2c), z = (int)(p / (W2c * H2c));
    int jz0, jz1, jy0, jy1, jx0, jx1; float wz0, wz1, wy0, wy1, wx0, wx1;
    up_taps(z, D1c, jz0, jz1, wz0, wz1);
    up_taps(y, H1c, jy0, jy1, wy0, wy1);
    up_taps(x, W1c, jx0, jx1, wx0, wx1);
    int jzs[2] = { jz0, jz1 }; float wzs[2] = { wz0, wz1 };
    int jys[2] = { jy0, jy1 }; float wys[2] = { wy0, wy1 };
    int jxs[2] = { jx0, jx1 }; float wxs[2] = { wx0, wx1 };
    float vu[3] = { 0.f, 0.f, 0.f };
    for (int a = 0; a < 2; ++a) {
        if (wzs[a] == 0.f) continue;
        for (int b = 0; b < 2; ++b) {
            if (wys[b] == 0.f) continue;
            float wzy = wzs[a] * wys[b];
            for (int d = 0; d < 2; ++d) {
                if (wxs[d] == 0.f) continue;
                float w = wzy * wxs[d];
                long rb = ((long)(jzs[a] * H1c + jys[b]) * W1c + jxs[d]) * 3;
                for (int c = 0; c < 3; ++c) vu[c] += w * sf(vel1[cl(rb + c, N3H)]);
            }
        }
    }
    for (int c = 0; c < 3; ++c) vu[c] = sf(vu[c] * 2.f);
    float cz = z + vu[0], cy = y + vu[1], cx = x + vu[2];
    float acc[3] = { 0.f, 0.f, 0.f };
    float z0f = floorf(cz), y0f = floorf(cy), x0f = floorf(cx);
    int z0 = (int)z0f, y0 = (int)y0f, x0 = (int)x0f;
    float fz = cz - z0f, fy = cy - y0f, fx = cx - x0f;
    for (int dz = 0; dz < 2; ++dz) {
        int zi = z0 + dz; if (zi < 0 || zi >= D2c) continue;
        float wz = dz ? fz : 1.f - fz;
        for (int dy = 0; dy < 2; ++dy) {
            int yi = y0 + dy; if (yi < 0 || yi >= H2c) continue;
            float wzy = wz * (dy ? fy : 1.f - fy);
            for (int dx = 0; dx < 2; ++dx) {
                int xi = x0 + dx; if (xi < 0 || xi >= W2c) continue;
                float w = wzy * (dx ? fx : 1.f - fx);
                long idx = (long)(zi * H2c + yi) * W2c + xi;
                for (int c = 0; c < 3; ++c) acc[c] += w * gld(dispup, cl((long)c * NFULL + idx, 3 * NFULL), mode);
            }
        }
    }
    for (int c = 0; c < 3; ++c) {
        float v = sf(acc[c] + vu[c]);
        du2[cl(p * 3 + c, N3F)] = v;
        xin2[cl(p * (long)S2 + 75 + c, NX2)] = f2bf(v);
    }
}

// robust t decode (handles bf16-stored or f32-stored scalar)
__device__ __forceinline__ float decode_t(const u16* tp) {
    u16 b0 = tp[0], b1 = tp[1];
    union { u32 i; float f; } a, b;
    a.i = ((u32)b0) << 16;
    b.i = ((u32)b1 << 16) | b0;
    float ta = a.f, tb = b.f;
    bool okA = (ta == ta) && ta >= 0.f && ta < 0.75f;
    bool okB = (tb == tb) && tb >= 0.f && tb < 0.75f;
    return okB ? tb : (okA ? ta : 0.f);
}

// vf = (warp(du2, vu2) + vu2 - disp_up) / (1 - t); out mode-dispatched
__global__ void k_final(const float* __restrict__ du2, const float* __restrict__ vu2,
                        const void* __restrict__ dispup, const u16* __restrict__ tptr,
                        void* __restrict__ out, long out_n, const int* __restrict__ modep) {
    int mode = *modep;
    long p = (long)blockIdx.x * 256 + threadIdx.x;
    if (p >= NFULL) return;
    float t = decode_t(tptr);
    float den = 1.f - t;
    if (fabsf(den) < 1e-6f) den = 1e-6f;
    float inv = 1.f / den;
    int x = (int)(p % W2c), y = (int)((p / W2c) % H2c), z = (int)(p / (W2c * H2c));
    float cz = z + sf(vu2[cl(p * 3, N3F)]);
    float cy = y + sf(vu2[cl(p * 3 + 1, N3F)]);
    float cx = x + sf(vu2[cl(p * 3 + 2, N3F)]);
    float acc[3] = { 0.f, 0.f, 0.f };
    float z0f = floorf(cz), y0f = floorf(cy), x0f = floorf(cx);
    int z0 = (int)z0f, y0 = (int)y0f, x0 = (int)x0f;
    float fz = cz - z0f, fy = cy - y0f, fx = cx - x0f;
    for (int dz = 0; dz < 2; ++dz) {
        int zi = z0 + dz; if (zi < 0 || zi >= D2c) continue;
        float wz = dz ? fz : 1.f - fz;
        for (int dy = 0; dy < 2; ++dy) {
            int yi = y0 + dy; if (yi < 0 || yi >= H2c) continue;
            float wzy = wz * (dy ? fy : 1.f - fy);
            for (int dx = 0; dx < 2; ++dx) {
                int xi = x0 + dx; if (xi < 0 || xi >= W2c) continue;
                float w = wzy * (dx ? fx : 1.f - fx);
                long rb = ((long)(zi * H2c + yi) * W2c + xi) * 3;
                for (int c = 0; c < 3; ++c) acc[c] += w * sf(du2[cl(rb + c, N3F)]);
            }
        }
    }
    for (int c = 0; c < 3; ++c) {
        float v = (acc[c] + sf(vu2[cl(p * 3 + c, N3F)]) - gld(dispup, cl((long)c * NFULL + p, 3 * NFULL), mode)) * inv;
        long oi = cl((long)c * NFULL + p, out_n);
        if (mode) ((float*)out)[oi] = sf(v);
        else      ((bf16*)out)[oi] = f2bf(v);
    }
}

static inline int cdiv(long a, long b) { return (int)((a + b - 1) / b); }

extern "C" void kernel_launch(void* const* d_in, const int* in_sizes, int n_in,
                              void* d_out, int out_size, void* d_ws, size_t ws_size,
                              hipStream_t stream) {
    const u16* t_in = (const u16*)d_in[0];
    const void* disp_up = d_in[1];
    const void* fx  = d_in[2];
    const void* fy  = d_in[3];
    const void* fxu = d_in[4];
    const void* fyu = d_in[5];
    const void* ctx = d_in[6];

    const size_t XIN1_B = (size_t)NX1 * 2;
    const size_t XIN2_B = (size_t)NX2 * 2;
    const size_t base_need = XIN1_B + XIN2_B + 2 * (size_t)GUARD;
    const size_t base_pad = (base_need + 255) & ~(size_t)255;
    const size_t vf_elems = 3UL * NFULL;

    // wtb sizes (bf16 elements): 27 * nchunk * Cout * 32
    const long WTB0 = 387072;  // 224->64, 7ch
    const long WTB1 = 373248;  // 288->48, 9ch
    const long WTB2 = 304128;  // 336->32, 11ch
    const long WTB3 = 165888;  // 368->16, 12ch
    const long WTB5 = 82944;   // 78->32, 3ch
    const long WTB6 = 55296;   // 110->16, 4ch
    const long WTB_TOT = WTB0 + WTB1 + WTB2 + WTB3 + WTB5 + WTB6; // 1,368,576

    size_t scro[11];
    {
        size_t o = 0;
        auto al = [&](size_t bytes) { size_t r = o; o = (o + bytes + 255) & ~(size_t)255; return r; };
        scro[0] = al((size_t)WTB_TOT * 2);      // WTB (bf16, mfma layout)
        scro[1] = al(2UL * 1296 * 4);           // WT f32 (two small convs)
        scro[2] = al((size_t)NCTX16 * 2);       // CTX16
        scro[3] = al((size_t)N3H * 4);          // VEL1
        scro[4] = al((size_t)N3H * 4);          // DISPH
        scro[5] = al((size_t)N3F * 4);          // DU2
        scro[6] = al((size_t)N3F * 4);          // VU2
        scro[7] = al(4UL * RG * 2 * 8);         // partials
        scro[8] = al(16 * 8);                   // RED
        scro[9] = al(32 * 4);                   // MODES
        scro[10] = o;
    }
    const size_t scratch_need = scro[10];
    const size_t tail_avail = ((size_t)out_size > vf_elems) ? ((size_t)out_size - vf_elems) * 2 : 0;

    char* scr = nullptr;
    if (ws_size >= base_pad + scratch_need) {
        scr = (char*)d_ws + base_pad;
    } else if (ws_size >= base_need && tail_avail >= scratch_need) {
        scr = (char*)d_out + vf_elems * 2;
    }
    if (scr == nullptr) {
        k_fill<<<2048, 256, 0, stream>>>((u16*)d_out, (long)out_size, 0x49A0);
        return;
    }

    char* ws = (char*)d_ws;
    bf16*  xin1  = (bf16*)(ws + GUARD);
    bf16*  xin2  = (bf16*)(ws + GUARD + XIN1_B);
    bf16*  wtball = (bf16*)(scr + scro[0]);
    float* wtf   = (float*)(scr + scro[1]);
    bf16*  ctx16 = (bf16*)(scr + scro[2]);
    float* vel1  = (float*)(scr + scro[3]);
    float* disph = (float*)(scr + scro[4]);
    float* du2   = (float*)(scr + scro[5]);
    float* vu2   = (float*)(scr + scro[6]);
    double* part = (double*)(scr + scro[7]);
    double* red  = (double*)(scr + scro[8]);
    int*   modes = (int*)(scr + scro[9]);
    double* pA = part;
    double* pB = part + RG * 2;
    double* pC = part + RG * 4;
    double* pD = part + RG * 6;

    bf16* wtb0 = wtball;
    bf16* wtb1 = wtb0 + WTB0;
    bf16* wtb2 = wtb1 + WTB1;
    bf16* wtb3 = wtb2 + WTB2;
    bf16* wtb5 = wtb3 + WTB3;
    bf16* wtb6 = wtb5 + WTB5;
    float* wt4 = wtf;
    float* wt7 = wtf + 1296;

    // fxu channel-last f32 copy reuses xin1's memory (dead after fl1 conv3):
    // NFULL*16*4 = 47.2MB <= XIN1_B = 67.8MB
    float* fxucl = (float*)xin1;

    // zero-init xin2 + scratch. xin2 must be finite everywhere (fl2 convs
    // read K-pad cols with zero weights; NaN*0 = NaN). xin1 needs no fill:
    // every byte of cols 0..223 is produced before its first read.
    k_fill<<<4096, 256, 0, stream>>>((u16*)xin2, NX2, 0);
    k_fill<<<4096, 256, 0, stream>>>((u16*)scr, (long)(scratch_need / 2), 0);

    // dtype detection for all tensor inputs
    for (int i = 1; i < 23 && i < n_in; ++i) {
        k_detect<<<1, 256, 0, stream>>>(d_in[i], (long)in_sizes[i], modes + i);
    }

    // MFMA weight repack (bf16, zero-padded K tails)
    k_wtb<<<cdiv(WTB0, 256), 256, 0, stream>>>(d_in[7],  wtb0, 224, 64, 7,  modes + 7);
    k_wtb<<<cdiv(WTB1, 256), 256, 0, stream>>>(d_in[9],  wtb1, 288, 48, 9,  modes + 9);
    k_wtb<<<cdiv(WTB2, 256), 256, 0, stream>>>(d_in[11], wtb2, 336, 32, 11, modes + 11);
    k_wtb<<<cdiv(WTB3, 256), 256, 0, stream>>>(d_in[13], wtb3, 368, 16, 12, modes + 13);
    k_wtb<<<cdiv(WTB5, 256), 256, 0, stream>>>(d_in[17], wtb5, 78,  32, 3,  modes + 17);
    k_wtb<<<cdiv(WTB6, 256), 256, 0, stream>>>(d_in[19], wtb6, 110, 16, 4,  modes + 19);
    // f32 weights for the two small convs
    k_wt<<<cdiv(1296, 256), 256, 0, stream>>>(d_in[15], wt4, 16, 3, modes + 15);
    k_wt<<<cdiv(1296, 256), 256, 0, stream>>>(d_in[21], wt7, 16, 3, modes + 21);

    // channel-last transposes with coalesced (LDS-staged) writes
    k_tcl_t<32><<<360, 256, 0, stream>>>(fy,  (u16*)xin1, NX1, 125, NHALF, S1, modes + 3);
    k_tcl_t<32><<<360, 256, 0, stream>>>(ctx, (u16*)xin1, NX1, 189, NHALF, S1, modes + 6);
    k_tcl_t<16><<<2880, 256, 0, stream>>>(fyu, (u16*)xin2, NX2, 27, NFULL, S2, modes + 5);

    k_down<<<cdiv(NHALF, 256), 256, 0, stream>>>(disp_up, disph, xin1, modes + 1);

    k_warp_cf<32><<<360, 256, 0, stream>>>(fx, 32L * NHALF, disph, N3H, (u16*)xin1, NX1, S1, 157, D1c, H1c, W1c, modes + 2);
    k_reduce_cl<<<RG, 256, 0, stream>>>(xin1, NX1, NHALF, S1, 157, 32, pA, modes + 31);
    k_reduce_cl<<<RG, 256, 0, stream>>>(fy, 32L * NHALF, 32L * NHALF, 1, 0, 1, pB, modes + 3);
    k_stats2<<<1, 256, 0, stream>>>(pA, pB, (double)(32L * NHALF), 32.0, red);

    // LDS-tiled cost volume 1: grid = 60 xy-tiles (8x4) x 12 zgroups = 720
    k_cv1_t<<<720, 128, 0, stream>>>(xin1, red);

    // fl1 dense block — LDS-staged MFMA conv (4 rows x M=2 z-planes / block)
    k_conv_mfma<4, 7, 64, 2, S1, D1c, H1c, W1c><<<720, 256, 0, stream>>>(xin1, wtb0, d_in[8],  xin1, S1, 224, 0.02f, modes + 8);
    k_conv_mfma<3, 9, 48, 2, S1, D1c, H1c, W1c><<<720, 256, 0, stream>>>(xin1, wtb1, d_in[10], xin1, S1, 288, 0.02f, modes + 10);
    k_conv_mfma<2, 11, 32, 2, S1, D1c, H1c, W1c><<<720, 256, 0, stream>>>(xin1, wtb2, d_in[12], xin1, S1, 336, 0.02f, modes + 12);
    k_conv_mfma<1, 12, 16, 2, S1, D1c, H1c, W1c><<<720, 256, 0, stream>>>(xin1, wtb3, d_in[14], ctx16, 16, 0, 0.02f, modes + 14);
    // tiled small conv (NHALF): grid = 3x3 xy-tiles x 12 zgroups = 108
    k_conv_small_t<4><<<108, 256, 0, stream>>>(ctx16, 16, 0, wt4, d_in[16], vel1, D1c, H1c, W1c, modes + 16);

    // xin1 is now dead -> transpose fxu into its memory as [NFULL][16] f32
    k_tclf<<<cdiv(NFULL, 256), 256, 0, stream>>>(fxu, fxucl, 16, NFULL, modes + 4);

    k_up_ctx<<<2880, 256, 0, stream>>>(ctx16, (u16*)xin2);
    k_warp_dispup<<<cdiv(NFULL, 256), 256, 0, stream>>>(disp_up, vel1, du2, xin2, modes + 1);

    // vectorized warp from the dense channel-last f32 copy
    k_warp_cl16<<<2880, 256, 0, stream>>>(fxucl, du2, (u16*)xin2);
    k_reduce_cl<<<RG, 256, 0, stream>>>(xin2, NX2, NFULL, S2, 43, 16, pC, modes + 31);
    k_reduce_cl<<<RG, 256, 0, stream>>>(fyu, 16L * NFULL, 16L * NFULL, 1, 0, 1, pD, modes + 5);
    k_stats2<<<1, 256, 0, stream>>>(pC, pD, (double)(16L * NFULL), 16.0, red + 2);

    // LDS-tiled cost volume 2: grid = 30 xy-tiles (16x16) x 24 zgroups = 720
    k_cv2_t<<<720, 256, 0, stream>>>(xin2, red);

    // fl2 block — LDS-staged MFMA conv (4 rows x M=4 z-planes / block)
    k_conv_mfma<2, 3, 32, 4, S2, D2c, H2c, W2c><<<2880, 256, 0, stream>>>(xin2, wtb5, d_in[18], xin2, S2, 78,  0.02f, modes + 18);
    k_conv_mfma<1, 4, 16, 4, S2, D2c, H2c, W2c><<<2880, 256, 0, stream>>>(xin2, wtb6, d_in[20], xin2, S2, 110, 0.02f, modes + 20);
    // tiled small conv (NFULL): grid = 6x5 xy-tiles x 24 zgroups = 720
    k_conv_small_t<4><<<720, 256, 0, stream>>>(xin2, S2, 110, wt7, d_in[22], vu2, D2c, H2c, W2c, modes + 22);

    // out dtype follows disp_up's detected mode
    k_final<<<cdiv(NFULL, 256), 256, 0, stream>>>(du2, vu2, disp_up, t_in, d_out, (long)out_size, modes + 1);
    k_fill_tail<<<2048, 256, 0, stream>>>(d_out, (long)vf_elems, (long)out_size, modes + 1);
}